// Round 1
// baseline (12318.604 us; speedup 1.0000x reference)
//
#include <hip/hip_runtime.h>
#include <hip/hip_bf16.h>

#define T_LEN 1024
#define D_DIM 1024
#define V_DIM 17
#define H_NUM 16
#define DH_DIM 64
#define F_DIM 4096
#define R_LORA 32
#define N_LAYERS 2
#define N_STEPS 2
#define MASK_ID 16
#define LORA_SCALE 2.0f

// ---------------- init soft: all rows = onehot(MASK_ID) ----------------
__global__ void init_soft_kernel(float* __restrict__ soft) {
    int idx = blockIdx.x * blockDim.x + threadIdx.x;
    if (idx < T_LEN * V_DIM) {
        soft[idx] = ((idx % V_DIM) == MASK_ID) ? 1.0f : 0.0f;
    }
}

// ---------------- embed: x = soft @ E  [T,V]@[V,D] ----------------
__global__ __launch_bounds__(256) void embed_kernel(const float* __restrict__ soft,
                                                    const float* __restrict__ E,
                                                    float* __restrict__ x) {
    int t = blockIdx.x;
    __shared__ float srow[V_DIM];
    if (threadIdx.x < V_DIM) srow[threadIdx.x] = soft[t * V_DIM + threadIdx.x];
    __syncthreads();
    for (int d = threadIdx.x; d < D_DIM; d += 256) {
        float acc = 0.f;
        #pragma unroll
        for (int v = 0; v < V_DIM; v++) acc += srow[v] * E[v * D_DIM + d];
        x[(size_t)t * D_DIM + d] = acc;
    }
}

// ---------------- rmsnorm: out = x * rsqrt(mean(x^2)+eps) * w ----------------
__global__ __launch_bounds__(256) void rms_kernel(const float* __restrict__ x,
                                                  const float* __restrict__ w,
                                                  float* __restrict__ out) {
    int t = blockIdx.x;
    const float* xr = x + (size_t)t * D_DIM;
    float ss = 0.f;
    for (int d = threadIdx.x; d < D_DIM; d += 256) { float v = xr[d]; ss += v * v; }
    __shared__ float red[4];
    int lane = threadIdx.x & 63, wave = threadIdx.x >> 6;
    for (int off = 32; off > 0; off >>= 1) ss += __shfl_xor(ss, off);
    if (lane == 0) red[wave] = ss;
    __syncthreads();
    ss = red[0] + red[1] + red[2] + red[3];
    float r = 1.0f / sqrtf(ss * (1.0f / D_DIM) + 1e-6f);
    for (int d = threadIdx.x; d < D_DIM; d += 256) out[(size_t)t * D_DIM + d] = xr[d] * r * w[d];
}

// ---------------- generic fp32 GEMM: C = alpha*(A@B) (+ C if accumulate) ----------------
// A: [M,K] row-major, B: [K,N] row-major, C: [M,N]
__global__ __launch_bounds__(256) void gemm_kernel(const float* __restrict__ A,
                                                   const float* __restrict__ B,
                                                   float* __restrict__ C,
                                                   int M, int N, int K,
                                                   float alpha, int accumulate) {
    const int BM = 64, BN = 64, BK = 16;
    __shared__ float As[BK][BM];
    __shared__ float Bs[BK][BN];
    int tid = threadIdx.x;
    int tx = tid % 16, ty = tid / 16;
    int row0 = blockIdx.y * BM, col0 = blockIdx.x * BN;
    float acc[4][4] = {};
    for (int k0 = 0; k0 < K; k0 += BK) {
        #pragma unroll
        for (int i = 0; i < 4; i++) {
            int e = tid * 4 + i;
            int m = e / BK, kk = e % BK;
            int gr = row0 + m, gk = k0 + kk;
            As[kk][m] = (gr < M && gk < K) ? A[(size_t)gr * K + gk] : 0.f;
        }
        #pragma unroll
        for (int i = 0; i < 4; i++) {
            int e = tid * 4 + i;
            int kk = e / BN, n = e % BN;
            int gk = k0 + kk, gc = col0 + n;
            Bs[kk][n] = (gk < K && gc < N) ? B[(size_t)gk * N + gc] : 0.f;
        }
        __syncthreads();
        #pragma unroll
        for (int kk = 0; kk < BK; kk++) {
            float a[4], b[4];
            #pragma unroll
            for (int i = 0; i < 4; i++) a[i] = As[kk][ty * 4 + i];
            #pragma unroll
            for (int j = 0; j < 4; j++) b[j] = Bs[kk][tx * 4 + j];
            #pragma unroll
            for (int i = 0; i < 4; i++)
                #pragma unroll
                for (int j = 0; j < 4; j++)
                    acc[i][j] += a[i] * b[j];
        }
        __syncthreads();
    }
    #pragma unroll
    for (int i = 0; i < 4; i++) {
        int r = row0 + ty * 4 + i;
        if (r >= M) continue;
        #pragma unroll
        for (int j = 0; j < 4; j++) {
            int c = col0 + tx * 4 + j;
            if (c >= N) continue;
            size_t idx = (size_t)r * N + c;
            float val = alpha * acc[i][j];
            if (accumulate) val += C[idx];
            C[idx] = val;
        }
    }
}

// ---------------- attention: one block per (query row, head) ----------------
__global__ __launch_bounds__(256) void attn_kernel(const float* __restrict__ q,
                                                   const float* __restrict__ k,
                                                   const float* __restrict__ v,
                                                   float* __restrict__ ctx) {
    int qi = blockIdx.x;
    int hh = blockIdx.y;
    __shared__ float sc[T_LEN];
    __shared__ float qrow[DH_DIM];
    __shared__ float red[8];
    __shared__ float part[4][DH_DIM];
    int tid = threadIdx.x;
    int lane = tid & 63, wave = tid >> 6;

    const float* qp = q + (size_t)qi * D_DIM + hh * DH_DIM;
    if (tid < DH_DIM) qrow[tid] = qp[tid];
    __syncthreads();

    const float scale = 0.125f;  // 1/sqrt(64)
    // phase 1: scores for j <= qi (masked j underflow to 0 in reference; skip)
    for (int j = wave; j <= qi; j += 4) {
        const float* kp = k + (size_t)j * D_DIM + hh * DH_DIM;
        float p = qrow[lane] * kp[lane];
        for (int off = 32; off > 0; off >>= 1) p += __shfl_xor(p, off);
        if (lane == 0) sc[j] = p * scale;
    }
    __syncthreads();

    int n = qi + 1;
    // phase 2: softmax over sc[0..n)
    float m = -1e30f;
    for (int j = tid; j < n; j += 256) m = fmaxf(m, sc[j]);
    for (int off = 32; off > 0; off >>= 1) m = fmaxf(m, __shfl_xor(m, off));
    if (lane == 0) red[wave] = m;
    __syncthreads();
    m = fmaxf(fmaxf(red[0], red[1]), fmaxf(red[2], red[3]));
    float s = 0.f;
    for (int j = tid; j < n; j += 256) { float e = expf(sc[j] - m); sc[j] = e; s += e; }
    for (int off = 32; off > 0; off >>= 1) s += __shfl_xor(s, off);
    if (lane == 0) red[4 + wave] = s;
    __syncthreads();
    s = red[4] + red[5] + red[6] + red[7];
    float inv = 1.0f / s;

    // phase 3: ctx[dh] = sum_j att[j] * v[j][dh]
    float acc = 0.f;
    for (int j = wave; j < n; j += 4) {
        acc += sc[j] * v[(size_t)j * D_DIM + hh * DH_DIM + lane];
    }
    part[wave][lane] = acc;
    __syncthreads();
    if (tid < DH_DIM) {
        float r = (part[0][tid] + part[1][tid] + part[2][tid] + part[3][tid]) * inv;
        ctx[(size_t)qi * D_DIM + hh * DH_DIM + tid] = r;
    }
}

// ---------------- silu(g)*u elementwise ----------------
__global__ void silu_mul_kernel(const float* __restrict__ g, const float* __restrict__ u,
                                float* __restrict__ out, int nelem) {
    int i = blockIdx.x * blockDim.x + threadIdx.x;
    if (i < nelem) {
        float gv = g[i];
        float sg = 1.0f / (1.0f + expf(-gv));
        out[i] = gv * sg * u[i];
    }
}

// ---------------- head: rms(x,lnf) @ E^T -> softmax -> update soft ----------------
__global__ __launch_bounds__(256) void head_kernel(const float* __restrict__ x,
                                                   const float* __restrict__ lnf,
                                                   const float* __restrict__ E,
                                                   const int* __restrict__ tok,
                                                   float* __restrict__ soft) {
    int t = blockIdx.x;
    int tid = threadIdx.x;
    __shared__ float y[D_DIM];
    __shared__ float red[4];
    __shared__ float logits[V_DIM];
    const float* xr = x + (size_t)t * D_DIM;
    float ss = 0.f;
    for (int d = tid; d < D_DIM; d += 256) { float v = xr[d]; ss += v * v; }
    int lane = tid & 63, wave = tid >> 6;
    for (int off = 32; off > 0; off >>= 1) ss += __shfl_xor(ss, off);
    if (lane == 0) red[wave] = ss;
    __syncthreads();
    ss = red[0] + red[1] + red[2] + red[3];
    float r = 1.0f / sqrtf(ss * (1.0f / D_DIM) + 1e-6f);
    for (int d = tid; d < D_DIM; d += 256) y[d] = xr[d] * r * lnf[d];
    __syncthreads();
    for (int vv = wave; vv < V_DIM; vv += 4) {
        float p = 0.f;
        for (int d = lane; d < D_DIM; d += 64) p += y[d] * E[vv * D_DIM + d];
        for (int off = 32; off > 0; off >>= 1) p += __shfl_xor(p, off);
        if (lane == 0) logits[vv] = p;
    }
    __syncthreads();
    if (tid == 0) {
        int tk = tok[t];
        if (tk != MASK_ID) {
            for (int vv = 0; vv < V_DIM; vv++) soft[t * V_DIM + vv] = (vv == tk) ? 1.f : 0.f;
        } else {
            float mx = -1e30f;
            for (int vv = 0; vv < V_DIM; vv++) mx = fmaxf(mx, logits[vv]);
            float sm = 0.f;
            float e[V_DIM];
            for (int vv = 0; vv < V_DIM; vv++) { e[vv] = expf(logits[vv] - mx); sm += e[vv]; }
            float invs = 1.0f / sm;
            for (int vv = 0; vv < V_DIM; vv++) soft[t * V_DIM + vv] = e[vv] * invs;
        }
    }
}

// ---------------- argmax over V ----------------
__global__ void argmax_kernel(const float* __restrict__ soft, int* __restrict__ out) {
    int t = blockIdx.x * blockDim.x + threadIdx.x;
    if (t < T_LEN) {
        const float* s = soft + t * V_DIM;
        int best = 0;
        float bv = s[0];
        #pragma unroll
        for (int vv = 1; vv < V_DIM; vv++) {
            float v = s[vv];
            if (v > bv) { bv = v; best = vv; }
        }
        out[t] = best;
    }
}

static inline void launch_gemm(const float* A, const float* B, float* C,
                               int M, int N, int K, float alpha, int accumulate,
                               hipStream_t stream) {
    dim3 grid((N + 63) / 64, (M + 63) / 64);
    gemm_kernel<<<grid, 256, 0, stream>>>(A, B, C, M, N, K, alpha, accumulate);
}

extern "C" void kernel_launch(void* const* d_in, const int* in_sizes, int n_in,
                              void* d_out, int out_size, void* d_ws, size_t ws_size,
                              hipStream_t stream) {
    const int* packed = (const int*)d_in[0];
    const float* E  = (const float*)d_in[6];
    const float* Wq = (const float*)d_in[7];
    const float* Aq = (const float*)d_in[8];
    const float* Bq = (const float*)d_in[9];
    const float* Wk = (const float*)d_in[10];
    const float* Ak = (const float*)d_in[11];
    const float* Bk = (const float*)d_in[12];
    const float* Wv = (const float*)d_in[13];
    const float* Av = (const float*)d_in[14];
    const float* Bv = (const float*)d_in[15];
    const float* Wo = (const float*)d_in[16];
    const float* Ao = (const float*)d_in[17];
    const float* Bo = (const float*)d_in[18];
    const float* Wg = (const float*)d_in[19];
    const float* Ag = (const float*)d_in[20];
    const float* Bg = (const float*)d_in[21];
    const float* Wu = (const float*)d_in[22];
    const float* Au = (const float*)d_in[23];
    const float* Bu = (const float*)d_in[24];
    const float* Wd = (const float*)d_in[25];
    const float* Ad = (const float*)d_in[26];
    const float* Bd = (const float*)d_in[27];
    const float* ln1 = (const float*)d_in[28];
    const float* ln2 = (const float*)d_in[29];
    const float* lnf = (const float*)d_in[30];

    float* ws = (float*)d_ws;
    size_t off = 0;
    float* soft = ws + off; off += (size_t)T_LEN * V_DIM;      // 17408
    float* x    = ws + off; off += (size_t)T_LEN * D_DIM;
    float* h    = ws + off; off += (size_t)T_LEN * D_DIM;
    float* qb   = ws + off; off += (size_t)T_LEN * D_DIM;
    float* kb   = ws + off; off += (size_t)T_LEN * D_DIM;
    float* vb   = ws + off; off += (size_t)T_LEN * D_DIM;
    float* cb   = ws + off; off += (size_t)T_LEN * D_DIM;
    float* gb   = ws + off; off += (size_t)T_LEN * F_DIM;
    float* ub   = ws + off; off += (size_t)T_LEN * F_DIM;
    float* tmp  = ws + off; off += (size_t)T_LEN * R_LORA;

    init_soft_kernel<<<(T_LEN * V_DIM + 255) / 256, 256, 0, stream>>>(soft);

    for (int step = 0; step < N_STEPS; step++) {
        embed_kernel<<<T_LEN, 256, 0, stream>>>(soft, E, x);
        for (int l = 0; l < N_LAYERS; l++) {
            const float* Wq_l = Wq + (size_t)l * D_DIM * D_DIM;
            const float* Aq_l = Aq + (size_t)l * D_DIM * R_LORA;
            const float* Bq_l = Bq + (size_t)l * R_LORA * D_DIM;
            const float* Wk_l = Wk + (size_t)l * D_DIM * D_DIM;
            const float* Ak_l = Ak + (size_t)l * D_DIM * R_LORA;
            const float* Bk_l = Bk + (size_t)l * R_LORA * D_DIM;
            const float* Wv_l = Wv + (size_t)l * D_DIM * D_DIM;
            const float* Av_l = Av + (size_t)l * D_DIM * R_LORA;
            const float* Bv_l = Bv + (size_t)l * R_LORA * D_DIM;
            const float* Wo_l = Wo + (size_t)l * D_DIM * D_DIM;
            const float* Ao_l = Ao + (size_t)l * D_DIM * R_LORA;
            const float* Bo_l = Bo + (size_t)l * R_LORA * D_DIM;
            const float* Wg_l = Wg + (size_t)l * D_DIM * F_DIM;
            const float* Ag_l = Ag + (size_t)l * D_DIM * R_LORA;
            const float* Bg_l = Bg + (size_t)l * R_LORA * F_DIM;
            const float* Wu_l = Wu + (size_t)l * D_DIM * F_DIM;
            const float* Au_l = Au + (size_t)l * D_DIM * R_LORA;
            const float* Bu_l = Bu + (size_t)l * R_LORA * F_DIM;
            const float* Wd_l = Wd + (size_t)l * F_DIM * D_DIM;
            const float* Ad_l = Ad + (size_t)l * F_DIM * R_LORA;
            const float* Bd_l = Bd + (size_t)l * R_LORA * D_DIM;
            const float* ln1_l = ln1 + (size_t)l * D_DIM;
            const float* ln2_l = ln2 + (size_t)l * D_DIM;

            // h = rms(x, ln1)
            rms_kernel<<<T_LEN, 256, 0, stream>>>(x, ln1_l, h);

            // q = h@Wq + 2*(h@Aq)@Bq
            launch_gemm(h, Aq_l, tmp, T_LEN, R_LORA, D_DIM, 1.0f, 0, stream);
            launch_gemm(h, Wq_l, qb, T_LEN, D_DIM, D_DIM, 1.0f, 0, stream);
            launch_gemm(tmp, Bq_l, qb, T_LEN, D_DIM, R_LORA, LORA_SCALE, 1, stream);
            // k
            launch_gemm(h, Ak_l, tmp, T_LEN, R_LORA, D_DIM, 1.0f, 0, stream);
            launch_gemm(h, Wk_l, kb, T_LEN, D_DIM, D_DIM, 1.0f, 0, stream);
            launch_gemm(tmp, Bk_l, kb, T_LEN, D_DIM, R_LORA, LORA_SCALE, 1, stream);
            // v
            launch_gemm(h, Av_l, tmp, T_LEN, R_LORA, D_DIM, 1.0f, 0, stream);
            launch_gemm(h, Wv_l, vb, T_LEN, D_DIM, D_DIM, 1.0f, 0, stream);
            launch_gemm(tmp, Bv_l, vb, T_LEN, D_DIM, R_LORA, LORA_SCALE, 1, stream);

            // attention
            attn_kernel<<<dim3(T_LEN, H_NUM), 256, 0, stream>>>(qb, kb, vb, cb);

            // x = x + ctx@Wo + 2*(ctx@Ao)@Bo
            launch_gemm(cb, Ao_l, tmp, T_LEN, R_LORA, D_DIM, 1.0f, 0, stream);
            launch_gemm(cb, Wo_l, x, T_LEN, D_DIM, D_DIM, 1.0f, 1, stream);
            launch_gemm(tmp, Bo_l, x, T_LEN, D_DIM, R_LORA, LORA_SCALE, 1, stream);

            // h = rms(x, ln2)
            rms_kernel<<<T_LEN, 256, 0, stream>>>(x, ln2_l, h);

            // g = h@Wg + 2*(h@Ag)@Bg ; u = h@Wu + 2*(h@Au)@Bu
            launch_gemm(h, Ag_l, tmp, T_LEN, R_LORA, D_DIM, 1.0f, 0, stream);
            launch_gemm(h, Wg_l, gb, T_LEN, F_DIM, D_DIM, 1.0f, 0, stream);
            launch_gemm(tmp, Bg_l, gb, T_LEN, F_DIM, R_LORA, LORA_SCALE, 1, stream);
            launch_gemm(h, Au_l, tmp, T_LEN, R_LORA, D_DIM, 1.0f, 0, stream);
            launch_gemm(h, Wu_l, ub, T_LEN, F_DIM, D_DIM, 1.0f, 0, stream);
            launch_gemm(tmp, Bu_l, ub, T_LEN, F_DIM, R_LORA, LORA_SCALE, 1, stream);

            // ff = silu(g)*u  (into gb)
            silu_mul_kernel<<<(T_LEN * F_DIM + 255) / 256, 256, 0, stream>>>(gb, ub, gb, T_LEN * F_DIM);

            // x = x + ff@Wd + 2*(ff@Ad)@Bd
            launch_gemm(gb, Ad_l, tmp, T_LEN, R_LORA, F_DIM, 1.0f, 0, stream);
            launch_gemm(gb, Wd_l, x, T_LEN, D_DIM, F_DIM, 1.0f, 1, stream);
            launch_gemm(tmp, Bd_l, x, T_LEN, D_DIM, R_LORA, LORA_SCALE, 1, stream);
        }
        head_kernel<<<T_LEN, 256, 0, stream>>>(x, lnf, E, packed, soft);
    }

    argmax_kernel<<<(T_LEN + 255) / 256, 256, 0, stream>>>(soft, (int*)d_out);
}

// Round 2
// 2014.181 us; speedup vs baseline: 6.1159x; 6.1159x over previous
//
#include <hip/hip_runtime.h>
#include <hip/hip_bf16.h>

#define T_LEN 1024
#define D_DIM 1024
#define V_DIM 17
#define H_NUM 16
#define DH_DIM 64
#define F_DIM 4096
#define R_LORA 32
#define N_LAYERS 2
#define N_STEPS 2
#define MASK_ID 16
#define LORA_SCALE 2.0f

typedef __attribute__((ext_vector_type(8))) short bfx8;   // 8 bf16 in 4 VGPRs (guide §3)
typedef __attribute__((ext_vector_type(4))) float f32x4;

typedef unsigned short ushort_t;
typedef unsigned int uint_t;

__device__ __forceinline__ ushort_t f2bf(float v) {
    __hip_bfloat16 h = __float2bfloat16(v);
    return __builtin_bit_cast(unsigned short, h);
}
__device__ __forceinline__ float bf2f(ushort_t u) {
    return __uint_as_float(((uint_t)u) << 16);
}
__device__ __forceinline__ void split4_store(float y0, float y1, float y2, float y3,
                                             ushort_t* __restrict__ hi, ushort_t* __restrict__ lo,
                                             size_t idx) {
    ushort_t h0 = f2bf(y0), h1 = f2bf(y1), h2 = f2bf(y2), h3 = f2bf(y3);
    ushort_t l0 = f2bf(y0 - bf2f(h0));
    ushort_t l1 = f2bf(y1 - bf2f(h1));
    ushort_t l2 = f2bf(y2 - bf2f(h2));
    ushort_t l3 = f2bf(y3 - bf2f(h3));
    uint2 hv, lv;
    hv.x = (uint_t)h0 | ((uint_t)h1 << 16);
    hv.y = (uint_t)h2 | ((uint_t)h3 << 16);
    lv.x = (uint_t)l0 | ((uint_t)l1 << 16);
    lv.y = (uint_t)l2 | ((uint_t)l3 << 16);
    *(uint2*)(hi + idx) = hv;
    *(uint2*)(lo + idx) = lv;
}

// ---------------- init soft: all rows = onehot(MASK_ID) ----------------
__global__ void init_soft_kernel(float* __restrict__ soft) {
    int idx = blockIdx.x * blockDim.x + threadIdx.x;
    if (idx < T_LEN * V_DIM) {
        soft[idx] = ((idx % V_DIM) == MASK_ID) ? 1.0f : 0.0f;
    }
}

// ---------------- embed: x = soft @ E  [T,V]@[V,D] ----------------
__global__ __launch_bounds__(256) void embed_kernel(const float* __restrict__ soft,
                                                    const float* __restrict__ E,
                                                    float* __restrict__ x) {
    int t = blockIdx.x;
    __shared__ float srow[V_DIM];
    if (threadIdx.x < V_DIM) srow[threadIdx.x] = soft[t * V_DIM + threadIdx.x];
    __syncthreads();
    for (int d = threadIdx.x; d < D_DIM; d += 256) {
        float acc = 0.f;
        #pragma unroll
        for (int v = 0; v < V_DIM; v++) acc += srow[v] * E[v * D_DIM + d];
        x[(size_t)t * D_DIM + d] = acc;
    }
}

// ---------------- fold: out^T(hi/lo) = split(W + 2*A@B), out is [N,K] ----------------
__global__ __launch_bounds__(256) void fold_kernel(
    const float* __restrict__ W,   // [K,N]
    const float* __restrict__ A,   // [K,R]
    const float* __restrict__ Bm,  // [R,N]
    ushort_t* __restrict__ oHi,    // [N,K]
    ushort_t* __restrict__ oLo,    // [N,K]
    int K, int N)
{
    __shared__ uint_t tile[64][65];
    const int tid = threadIdx.x;
    const int n0 = blockIdx.x * 64, k0 = blockIdx.y * 64;
    {
        const int nl = tid & 63, kq = tid >> 6;
        float breg[R_LORA];
        #pragma unroll
        for (int r = 0; r < R_LORA; r++) breg[r] = Bm[(size_t)r * N + n0 + nl];
        for (int i = 0; i < 16; i++) {
            const int kl = kq * 16 + i;
            const size_t kgl = (size_t)(k0 + kl);
            const float* arow = A + kgl * R_LORA;
            float acc = 0.f;
            #pragma unroll
            for (int r = 0; r < R_LORA; r++) acc = fmaf(arow[r], breg[r], acc);
            float val = W[kgl * N + n0 + nl] + LORA_SCALE * acc;
            ushort_t h = f2bf(val);
            ushort_t l = f2bf(val - bf2f(h));
            tile[kl][nl] = ((uint_t)h << 16) | (uint_t)l;
        }
    }
    __syncthreads();
    {
        const int kl = tid & 63, nb = tid >> 6;
        for (int i = 0; i < 16; i++) {
            const int nl = nb * 16 + i;
            uint_t pk = tile[kl][nl];
            size_t idx = (size_t)(n0 + nl) * K + k0 + kl;
            oHi[idx] = (ushort_t)(pk >> 16);
            oLo[idx] = (ushort_t)(pk & 0xffffu);
        }
    }
}

// ---------------- rms + bf16-split: h = rms(x,w) -> (hi,lo) ----------------
__global__ __launch_bounds__(256) void rms_split_kernel(
    const float* __restrict__ x, const float* __restrict__ w,
    ushort_t* __restrict__ hi, ushort_t* __restrict__ lo)
{
    const int t = blockIdx.x, tid = threadIdx.x;
    const float* xr = x + (size_t)t * D_DIM;
    float4 xv = *(const float4*)(xr + tid * 4);
    float ss = xv.x * xv.x + xv.y * xv.y + xv.z * xv.z + xv.w * xv.w;
    __shared__ float red[4];
    const int lane = tid & 63, wv = tid >> 6;
    #pragma unroll
    for (int off = 32; off > 0; off >>= 1) ss += __shfl_xor(ss, off);
    if (lane == 0) red[wv] = ss;
    __syncthreads();
    ss = red[0] + red[1] + red[2] + red[3];
    const float r = 1.0f / sqrtf(ss * (1.0f / D_DIM) + 1e-6f);
    const float4 wv4 = *(const float4*)(w + tid * 4);
    size_t base = (size_t)t * D_DIM + tid * 4;
    split4_store(xv.x * r * wv4.x, xv.y * r * wv4.y, xv.z * r * wv4.z, xv.w * r * wv4.w,
                 hi, lo, base);
}

// ---------------- MFMA split-bf16 GEMM: C = A@B (+C), A=[M,K] hi/lo, B=[N,K] hi/lo ----------------
#define GLDK 36
__global__ __launch_bounds__(256) void gemm_mfma_kernel(
    const ushort_t* __restrict__ Ahi, const ushort_t* __restrict__ Alo,
    const ushort_t* __restrict__ Bhi, const ushort_t* __restrict__ Blo,
    float* __restrict__ C, int M, int N, int K, int accum)
{
    __shared__ ushort_t As[2][64][GLDK];
    __shared__ ushort_t Bs[2][64][GLDK];
    const int tid = threadIdx.x;
    const int lane = tid & 63;
    const int wave = tid >> 6;
    const int m0 = blockIdx.y * 64, n0 = blockIdx.x * 64;
    const int wm = (wave >> 1) * 32, wn = (wave & 1) * 32;
    const int l15 = lane & 15, lg = lane >> 4;
    const int srow = tid >> 2;
    const int skq = (tid & 3) * 8;

    f32x4 acc[2][2];
    #pragma unroll
    for (int i = 0; i < 2; i++)
        #pragma unroll
        for (int j = 0; j < 2; j++) acc[i][j] = f32x4{0.f, 0.f, 0.f, 0.f};

    const size_t aBase = (size_t)(m0 + srow) * K + skq;
    const size_t bBase = (size_t)(n0 + srow) * K + skq;

    for (int k0 = 0; k0 < K; k0 += 32) {
        uint4 va = *(const uint4*)(Ahi + aBase + k0);
        uint4 vb = *(const uint4*)(Alo + aBase + k0);
        uint4 vc = *(const uint4*)(Bhi + bBase + k0);
        uint4 vd = *(const uint4*)(Blo + bBase + k0);
        {
            uint_t* p = (uint_t*)&As[0][srow][skq];
            p[0] = va.x; p[1] = va.y; p[2] = va.z; p[3] = va.w;
            uint_t* q = (uint_t*)&As[1][srow][skq];
            q[0] = vb.x; q[1] = vb.y; q[2] = vb.z; q[3] = vb.w;
            uint_t* r = (uint_t*)&Bs[0][srow][skq];
            r[0] = vc.x; r[1] = vc.y; r[2] = vc.z; r[3] = vc.w;
            uint_t* s = (uint_t*)&Bs[1][srow][skq];
            s[0] = vd.x; s[1] = vd.y; s[2] = vd.z; s[3] = vd.w;
        }
        __syncthreads();
        bfx8 ah[2], al[2], bh[2], bl[2];
        #pragma unroll
        for (int mi = 0; mi < 2; mi++) {
            union { bfx8 v; uint_t u[4]; } f0, f1;
            const uint_t* p0 = (const uint_t*)&As[0][wm + mi * 16 + l15][lg * 8];
            const uint_t* p1 = (const uint_t*)&As[1][wm + mi * 16 + l15][lg * 8];
            f0.u[0] = p0[0]; f0.u[1] = p0[1]; f0.u[2] = p0[2]; f0.u[3] = p0[3];
            f1.u[0] = p1[0]; f1.u[1] = p1[1]; f1.u[2] = p1[2]; f1.u[3] = p1[3];
            ah[mi] = f0.v; al[mi] = f1.v;
        }
        #pragma unroll
        for (int ni = 0; ni < 2; ni++) {
            union { bfx8 v; uint_t u[4]; } f0, f1;
            const uint_t* p0 = (const uint_t*)&Bs[0][wn + ni * 16 + l15][lg * 8];
            const uint_t* p1 = (const uint_t*)&Bs[1][wn + ni * 16 + l15][lg * 8];
            f0.u[0] = p0[0]; f0.u[1] = p0[1]; f0.u[2] = p0[2]; f0.u[3] = p0[3];
            f1.u[0] = p1[0]; f1.u[1] = p1[1]; f1.u[2] = p1[2]; f1.u[3] = p1[3];
            bh[ni] = f0.v; bl[ni] = f1.v;
        }
        #pragma unroll
        for (int mi = 0; mi < 2; mi++)
            #pragma unroll
            for (int ni = 0; ni < 2; ni++) {
                acc[mi][ni] = __builtin_amdgcn_mfma_f32_16x16x32_bf16(ah[mi], bh[ni], acc[mi][ni], 0, 0, 0);
                acc[mi][ni] = __builtin_amdgcn_mfma_f32_16x16x32_bf16(ah[mi], bl[ni], acc[mi][ni], 0, 0, 0);
                acc[mi][ni] = __builtin_amdgcn_mfma_f32_16x16x32_bf16(al[mi], bh[ni], acc[mi][ni], 0, 0, 0);
            }
        __syncthreads();
    }
    #pragma unroll
    for (int mi = 0; mi < 2; mi++)
        #pragma unroll
        for (int ni = 0; ni < 2; ni++) {
            int col = n0 + wn + ni * 16 + l15;
            #pragma unroll
            for (int i = 0; i < 4; i++) {
                int row = m0 + wm + mi * 16 + lg * 4 + i;
                size_t idx = (size_t)row * N + col;
                float v = acc[mi][ni][i];
                if (accum) v += C[idx];
                C[idx] = v;
            }
        }
}

// ---------------- flash attention: block per (q-tile 64, head); fp32 ----------------
__global__ __launch_bounds__(256, 1) void attn_flash_kernel(
    const float* __restrict__ qg, const float* __restrict__ kg,
    const float* __restrict__ vg, ushort_t* __restrict__ chi, ushort_t* __restrict__ clo)
{
    __shared__ float kbuf[64][64];
    __shared__ float vbuf[64][64];
    __shared__ float qs[64][68];
    __shared__ float msm[4][64];
    __shared__ float lsm[4][64];

    const int qt = blockIdx.x, hh = blockIdx.y;
    const int tid = threadIdx.x;
    const int w = tid >> 6, lane = tid & 63;
    const int q0 = qt * 64;
    const int hcol = hh * DH_DIM;
    const int srow = tid >> 2, sc0 = (tid & 3) * 16;

    {   // stage Q tile
        const float* src = qg + (size_t)(q0 + srow) * D_DIM + hcol + sc0;
        #pragma unroll
        for (int i = 0; i < 4; i++)
            *(float4*)&qs[srow][sc0 + i * 4] = *(const float4*)(src + i * 4);
    }
    __syncthreads();
    float qreg[64];
    #pragma unroll
    for (int d4 = 0; d4 < 16; d4++) {
        float4 t = *(const float4*)&qs[lane][d4 * 4];
        qreg[d4 * 4 + 0] = t.x; qreg[d4 * 4 + 1] = t.y;
        qreg[d4 * 4 + 2] = t.z; qreg[d4 * 4 + 3] = t.w;
    }

    float accv[64];
    #pragma unroll
    for (int d = 0; d < 64; d++) accv[d] = 0.f;
    float mrun = -3.0e38f, lrun = 0.f;
    const int qglob = q0 + lane;
    const int kk0 = w * 16;

    for (int kt = 0; kt <= qt; kt++) {
        __syncthreads();
        {
            const int krow0 = kt * 64;
            const float* ks = kg + (size_t)(krow0 + srow) * D_DIM + hcol + sc0;
            const float* vs = vg + (size_t)(krow0 + srow) * D_DIM + hcol + sc0;
            #pragma unroll
            for (int i = 0; i < 4; i++) {
                *(float4*)&kbuf[srow][sc0 + i * 4] = *(const float4*)(ks + i * 4);
                *(float4*)&vbuf[srow][sc0 + i * 4] = *(const float4*)(vs + i * 4);
            }
        }
        __syncthreads();
        float p16[16];
        float tmax = -3.0e38f;
        const bool diag = (kt == qt);
        #pragma unroll
        for (int kk = 0; kk < 16; kk++) {
            const int kl = kk0 + kk;
            float s = 0.f;
            #pragma unroll
            for (int d4 = 0; d4 < 16; d4++) {
                float4 kv = *(const float4*)&kbuf[kl][d4 * 4];
                s = fmaf(qreg[d4 * 4 + 0], kv.x, s);
                s = fmaf(qreg[d4 * 4 + 1], kv.y, s);
                s = fmaf(qreg[d4 * 4 + 2], kv.z, s);
                s = fmaf(qreg[d4 * 4 + 3], kv.w, s);
            }
            s *= 0.125f;
            if (diag && (kt * 64 + kl > qglob)) s = -3.0e38f;
            p16[kk] = s;
            tmax = fmaxf(tmax, s);
        }
        if (tmax > -1.0e37f) {  // skip fully-masked chunks (avoids exp(0)=1 on -inf - -inf)
            float newm = fmaxf(mrun, tmax);
            float scale = expf(mrun - newm);
            lrun *= scale;
            #pragma unroll
            for (int d = 0; d < 64; d++) accv[d] *= scale;
            float psum = 0.f;
            #pragma unroll
            for (int kk = 0; kk < 16; kk++) {
                float e = expf(p16[kk] - newm);
                p16[kk] = e; psum += e;
            }
            lrun += psum; mrun = newm;
            #pragma unroll
            for (int kk = 0; kk < 16; kk++) {
                const int kl = kk0 + kk;
                const float pw = p16[kk];
                #pragma unroll
                for (int d4 = 0; d4 < 16; d4++) {
                    float4 vv = *(const float4*)&vbuf[kl][d4 * 4];
                    accv[d4 * 4 + 0] = fmaf(pw, vv.x, accv[d4 * 4 + 0]);
                    accv[d4 * 4 + 1] = fmaf(pw, vv.y, accv[d4 * 4 + 1]);
                    accv[d4 * 4 + 2] = fmaf(pw, vv.z, accv[d4 * 4 + 2]);
                    accv[d4 * 4 + 3] = fmaf(pw, vv.w, accv[d4 * 4 + 3]);
                }
            }
        }
    }

    msm[w][lane] = mrun;
    lsm[w][lane] = lrun;
    // merge 4 wave-partials; reuse kbuf/vbuf as [4][32][64] transposed acc storage
    for (int half = 0; half < 2; half++) {
        __syncthreads();
        {
            float* mb = (w & 1) ? &vbuf[0][0] : &kbuf[0][0];
            float* dst = mb + (w >> 1) * 2048;
            #pragma unroll
            for (int i = 0; i < 32; i++)
                dst[i * 64 + lane] = accv[half * 32 + i];
        }
        __syncthreads();
        {
            const int qq = tid & 63, db = tid >> 6;
            float mm0 = msm[0][qq], mm1 = msm[1][qq], mm2 = msm[2][qq], mm3 = msm[3][qq];
            float M = fmaxf(fmaxf(mm0, mm1), fmaxf(mm2, mm3));
            float e0 = expf(mm0 - M), e1 = expf(mm1 - M), e2 = expf(mm2 - M), e3 = expf(mm3 - M);
            float L = lsm[0][qq] * e0 + lsm[1][qq] * e1 + lsm[2][qq] * e2 + lsm[3][qq] * e3;
            float invL = 1.0f / L;
            const float* b0 = &kbuf[0][0];
            const float* b1 = &vbuf[0][0];
            const float* b2 = &kbuf[0][0] + 2048;
            const float* b3 = &vbuf[0][0] + 2048;
            #pragma unroll
            for (int i = 0; i < 8; i++) {
                int dl = db * 8 + i;
                float vsum = b0[dl * 64 + qq] * e0 + b1[dl * 64 + qq] * e1 +
                             b2[dl * 64 + qq] * e2 + b3[dl * 64 + qq] * e3;
                qs[qq][half * 32 + dl] = vsum * invL;
            }
        }
    }
    __syncthreads();
    {
        size_t base = (size_t)(q0 + srow) * D_DIM + hcol + sc0;
        ushort_t hb[16], lb[16];
        #pragma unroll
        for (int i = 0; i < 16; i++) {
            float v = qs[srow][sc0 + i];
            ushort_t h = f2bf(v);
            hb[i] = h;
            lb[i] = f2bf(v - bf2f(h));
        }
        uint4 hv0, hv1, lv0, lv1;
        hv0.x = hb[0] | ((uint_t)hb[1] << 16);  hv0.y = hb[2] | ((uint_t)hb[3] << 16);
        hv0.z = hb[4] | ((uint_t)hb[5] << 16);  hv0.w = hb[6] | ((uint_t)hb[7] << 16);
        hv1.x = hb[8] | ((uint_t)hb[9] << 16);  hv1.y = hb[10] | ((uint_t)hb[11] << 16);
        hv1.z = hb[12] | ((uint_t)hb[13] << 16); hv1.w = hb[14] | ((uint_t)hb[15] << 16);
        lv0.x = lb[0] | ((uint_t)lb[1] << 16);  lv0.y = lb[2] | ((uint_t)lb[3] << 16);
        lv0.z = lb[4] | ((uint_t)lb[5] << 16);  lv0.w = lb[6] | ((uint_t)lb[7] << 16);
        lv1.x = lb[8] | ((uint_t)lb[9] << 16);  lv1.y = lb[10] | ((uint_t)lb[11] << 16);
        lv1.z = lb[12] | ((uint_t)lb[13] << 16); lv1.w = lb[14] | ((uint_t)lb[15] << 16);
        *(uint4*)(chi + base) = hv0;
        *(uint4*)(chi + base + 8) = hv1;
        *(uint4*)(clo + base) = lv0;
        *(uint4*)(clo + base + 8) = lv1;
    }
}

// ---------------- silu(g)*u -> split ----------------
__global__ void silu_split_kernel(const float* __restrict__ g, const float* __restrict__ u,
                                  ushort_t* __restrict__ hi, ushort_t* __restrict__ lo, int n4) {
    int i = blockIdx.x * blockDim.x + threadIdx.x;
    if (i < n4) {
        float4 gv = *(const float4*)(g + (size_t)i * 4);
        float4 uv = *(const float4*)(u + (size_t)i * 4);
        float y0 = gv.x / (1.f + expf(-gv.x)) * uv.x;
        float y1 = gv.y / (1.f + expf(-gv.y)) * uv.y;
        float y2 = gv.z / (1.f + expf(-gv.z)) * uv.z;
        float y3 = gv.w / (1.f + expf(-gv.w)) * uv.w;
        split4_store(y0, y1, y2, y3, hi, lo, (size_t)i * 4);
    }
}

// ---------------- head: rms(x,lnf) @ E^T -> softmax -> update soft ----------------
__global__ __launch_bounds__(256) void head_kernel(const float* __restrict__ x,
                                                   const float* __restrict__ lnf,
                                                   const float* __restrict__ E,
                                                   const int* __restrict__ tok,
                                                   float* __restrict__ soft) {
    int t = blockIdx.x;
    int tid = threadIdx.x;
    __shared__ float y[D_DIM];
    __shared__ float red[4];
    __shared__ float logits[V_DIM];
    const float* xr = x + (size_t)t * D_DIM;
    float ss = 0.f;
    for (int d = tid; d < D_DIM; d += 256) { float v = xr[d]; ss += v * v; }
    int lane = tid & 63, wave = tid >> 6;
    for (int off = 32; off > 0; off >>= 1) ss += __shfl_xor(ss, off);
    if (lane == 0) red[wave] = ss;
    __syncthreads();
    ss = red[0] + red[1] + red[2] + red[3];
    float r = 1.0f / sqrtf(ss * (1.0f / D_DIM) + 1e-6f);
    for (int d = tid; d < D_DIM; d += 256) y[d] = xr[d] * r * lnf[d];
    __syncthreads();
    for (int vv = wave; vv < V_DIM; vv += 4) {
        float p = 0.f;
        for (int d = lane; d < D_DIM; d += 64) p += y[d] * E[vv * D_DIM + d];
        for (int off = 32; off > 0; off >>= 1) p += __shfl_xor(p, off);
        if (lane == 0) logits[vv] = p;
    }
    __syncthreads();
    if (tid == 0) {
        int tk = tok[t];
        if (tk != MASK_ID) {
            for (int vv = 0; vv < V_DIM; vv++) soft[t * V_DIM + vv] = (vv == tk) ? 1.f : 0.f;
        } else {
            float mx = -1e30f;
            for (int vv = 0; vv < V_DIM; vv++) mx = fmaxf(mx, logits[vv]);
            float sm = 0.f;
            float e[V_DIM];
            for (int vv = 0; vv < V_DIM; vv++) { e[vv] = expf(logits[vv] - mx); sm += e[vv]; }
            float invs = 1.0f / sm;
            for (int vv = 0; vv < V_DIM; vv++) soft[t * V_DIM + vv] = e[vv] * invs;
        }
    }
}

// ---------------- argmax over V ----------------
__global__ void argmax_kernel(const float* __restrict__ soft, int* __restrict__ out) {
    int t = blockIdx.x * blockDim.x + threadIdx.x;
    if (t < T_LEN) {
        const float* s = soft + t * V_DIM;
        int best = 0;
        float bv = s[0];
        #pragma unroll
        for (int vv = 1; vv < V_DIM; vv++) {
            float v = s[vv];
            if (v > bv) { bv = v; best = vv; }
        }
        out[t] = best;
    }
}

// ================= round-1 fallback kernels (fp32, if ws too small) =================
__global__ __launch_bounds__(256) void rms_kernel(const float* __restrict__ x,
                                                  const float* __restrict__ w,
                                                  float* __restrict__ out) {
    int t = blockIdx.x;
    const float* xr = x + (size_t)t * D_DIM;
    float ss = 0.f;
    for (int d = threadIdx.x; d < D_DIM; d += 256) { float v = xr[d]; ss += v * v; }
    __shared__ float red[4];
    int lane = threadIdx.x & 63, wave = threadIdx.x >> 6;
    for (int off = 32; off > 0; off >>= 1) ss += __shfl_xor(ss, off);
    if (lane == 0) red[wave] = ss;
    __syncthreads();
    ss = red[0] + red[1] + red[2] + red[3];
    float r = 1.0f / sqrtf(ss * (1.0f / D_DIM) + 1e-6f);
    for (int d = threadIdx.x; d < D_DIM; d += 256) out[(size_t)t * D_DIM + d] = xr[d] * r * w[d];
}

__global__ __launch_bounds__(256) void gemm_kernel(const float* __restrict__ A,
                                                   const float* __restrict__ B,
                                                   float* __restrict__ C,
                                                   int M, int N, int K,
                                                   float alpha, int accumulate) {
    const int BM = 64, BN = 64, BK = 16;
    __shared__ float As[BK][BM];
    __shared__ float Bsh[BK][BN];
    int tid = threadIdx.x;
    int tx = tid % 16, ty = tid / 16;
    int row0 = blockIdx.y * BM, col0 = blockIdx.x * BN;
    float acc[4][4] = {};
    for (int k0 = 0; k0 < K; k0 += BK) {
        #pragma unroll
        for (int i = 0; i < 4; i++) {
            int e = tid * 4 + i;
            int m = e / BK, kk = e % BK;
            int gr = row0 + m, gk = k0 + kk;
            As[kk][m] = (gr < M && gk < K) ? A[(size_t)gr * K + gk] : 0.f;
        }
        #pragma unroll
        for (int i = 0; i < 4; i++) {
            int e = tid * 4 + i;
            int kk = e / BN, n = e % BN;
            int gk = k0 + kk, gc = col0 + n;
            Bsh[kk][n] = (gk < K && gc < N) ? B[(size_t)gk * N + gc] : 0.f;
        }
        __syncthreads();
        #pragma unroll
        for (int kk = 0; kk < BK; kk++) {
            float a[4], b[4];
            #pragma unroll
            for (int i = 0; i < 4; i++) a[i] = As[kk][ty * 4 + i];
            #pragma unroll
            for (int j = 0; j < 4; j++) b[j] = Bsh[kk][tx * 4 + j];
            #pragma unroll
            for (int i = 0; i < 4; i++)
                #pragma unroll
                for (int j = 0; j < 4; j++)
                    acc[i][j] += a[i] * b[j];
        }
        __syncthreads();
    }
    #pragma unroll
    for (int i = 0; i < 4; i++) {
        int r = row0 + ty * 4 + i;
        if (r >= M) continue;
        #pragma unroll
        for (int j = 0; j < 4; j++) {
            int c = col0 + tx * 4 + j;
            if (c >= N) continue;
            size_t idx = (size_t)r * N + c;
            float val = alpha * acc[i][j];
            if (accumulate) val += C[idx];
            C[idx] = val;
        }
    }
}

__global__ __launch_bounds__(256) void attn_kernel(const float* __restrict__ q,
                                                   const float* __restrict__ k,
                                                   const float* __restrict__ v,
                                                   float* __restrict__ ctx) {
    int qi = blockIdx.x;
    int hh = blockIdx.y;
    __shared__ float sc[T_LEN];
    __shared__ float qrow[DH_DIM];
    __shared__ float red[8];
    __shared__ float part[4][DH_DIM];
    int tid = threadIdx.x;
    int lane = tid & 63, wave = tid >> 6;
    const float* qp = q + (size_t)qi * D_DIM + hh * DH_DIM;
    if (tid < DH_DIM) qrow[tid] = qp[tid];
    __syncthreads();
    const float scale = 0.125f;
    for (int j = wave; j <= qi; j += 4) {
        const float* kp = k + (size_t)j * D_DIM + hh * DH_DIM;
        float p = qrow[lane] * kp[lane];
        for (int off = 32; off > 0; off >>= 1) p += __shfl_xor(p, off);
        if (lane == 0) sc[j] = p * scale;
    }
    __syncthreads();
    int n = qi + 1;
    float m = -1e30f;
    for (int j = tid; j < n; j += 256) m = fmaxf(m, sc[j]);
    for (int off = 32; off > 0; off >>= 1) m = fmaxf(m, __shfl_xor(m, off));
    if (lane == 0) red[wave] = m;
    __syncthreads();
    m = fmaxf(fmaxf(red[0], red[1]), fmaxf(red[2], red[3]));
    float s = 0.f;
    for (int j = tid; j < n; j += 256) { float e = expf(sc[j] - m); sc[j] = e; s += e; }
    for (int off = 32; off > 0; off >>= 1) s += __shfl_xor(s, off);
    if (lane == 0) red[4 + wave] = s;
    __syncthreads();
    s = red[4] + red[5] + red[6] + red[7];
    float inv = 1.0f / s;
    float acc = 0.f;
    for (int j = wave; j < n; j += 4) {
        acc += sc[j] * v[(size_t)j * D_DIM + hh * DH_DIM + lane];
    }
    part[wave][lane] = acc;
    __syncthreads();
    if (tid < DH_DIM) {
        float r = (part[0][tid] + part[1][tid] + part[2][tid] + part[3][tid]) * inv;
        ctx[(size_t)qi * D_DIM + hh * DH_DIM + tid] = r;
    }
}

__global__ void silu_mul_kernel(const float* __restrict__ g, const float* __restrict__ u,
                                float* __restrict__ out, int nelem) {
    int i = blockIdx.x * blockDim.x + threadIdx.x;
    if (i < nelem) {
        float gv = g[i];
        float sg = 1.0f / (1.0f + expf(-gv));
        out[i] = gv * sg * u[i];
    }
}

static inline void launch_gemm(const float* A, const float* B, float* C,
                               int M, int N, int K, float alpha, int accumulate,
                               hipStream_t stream) {
    dim3 grid((N + 63) / 64, (M + 63) / 64);
    gemm_kernel<<<grid, 256, 0, stream>>>(A, B, C, M, N, K, alpha, accumulate);
}

// =====================================================================================
extern "C" void kernel_launch(void* const* d_in, const int* in_sizes, int n_in,
                              void* d_out, int out_size, void* d_ws, size_t ws_size,
                              hipStream_t stream) {
    const int* packed = (const int*)d_in[0];
    const float* E  = (const float*)d_in[6];
    const float* Wsrc[7] = {(const float*)d_in[7],  (const float*)d_in[10], (const float*)d_in[13],
                            (const float*)d_in[16], (const float*)d_in[19], (const float*)d_in[22],
                            (const float*)d_in[25]};
    const float* Asrc[7] = {(const float*)d_in[8],  (const float*)d_in[11], (const float*)d_in[14],
                            (const float*)d_in[17], (const float*)d_in[20], (const float*)d_in[23],
                            (const float*)d_in[26]};
    const float* Bsrc[7] = {(const float*)d_in[9],  (const float*)d_in[12], (const float*)d_in[15],
                            (const float*)d_in[18], (const float*)d_in[21], (const float*)d_in[24],
                            (const float*)d_in[27]};
    const float* ln1 = (const float*)d_in[28];
    const float* ln2 = (const float*)d_in[29];
    const float* lnf = (const float*)d_in[30];

    const size_t DD = (size_t)D_DIM * D_DIM;     // 1M
    const size_t DF = (size_t)D_DIM * F_DIM;     // 4M
    const size_t wsizes[7] = {DD, DD, DD, DD, DF, DF, DF};
    const int Kdim[7] = {D_DIM, D_DIM, D_DIM, D_DIM, D_DIM, D_DIM, F_DIM};
    const int Ndim[7] = {D_DIM, D_DIM, D_DIM, D_DIM, F_DIM, F_DIM, D_DIM};

    // fast-path workspace requirement
    size_t u16_elems = 0;
    for (int p = 0; p < 7; p++) u16_elems += 2ull * N_LAYERS * wsizes[p];  // hi+lo per layer
    u16_elems += 2ull * DD;            // h hi/lo
    u16_elems += 2ull * DD;            // ctx hi/lo
    u16_elems += 2ull * DF;            // ff hi/lo
    size_t f32_elems = (size_t)T_LEN * V_DIM + DD /*x*/ + 3 * DD /*q,k,v*/ + 2 * DF /*g,u*/;
    size_t need = u16_elems * 2 + f32_elems * 4 + 256;

    if (ws_size >= need) {
        // -------- fast path --------
        ushort_t* ub = (ushort_t*)d_ws;
        size_t uo = 0;
        ushort_t *Whi[7], *Wlo[7];
        for (int p = 0; p < 7; p++) {
            Whi[p] = ub + uo; uo += (size_t)N_LAYERS * wsizes[p];
            Wlo[p] = ub + uo; uo += (size_t)N_LAYERS * wsizes[p];
        }
        ushort_t* h_hi = ub + uo; uo += DD;
        ushort_t* h_lo = ub + uo; uo += DD;
        ushort_t* c_hi = ub + uo; uo += DD;
        ushort_t* c_lo = ub + uo; uo += DD;
        ushort_t* f_hi = ub + uo; uo += DF;
        ushort_t* f_lo = ub + uo; uo += DF;
        float* fb = (float*)(ub + uo);
        size_t fo = 0;
        float* soft = fb + fo; fo += (size_t)T_LEN * V_DIM;
        float* x    = fb + fo; fo += DD;
        float* qb   = fb + fo; fo += DD;
        float* kb   = fb + fo; fo += DD;
        float* vb   = fb + fo; fo += DD;
        float* gbuf = fb + fo; fo += DF;
        float* ubuf = fb + fo; fo += DF;

        // fold weights: W' = W + 2*A@B, transposed + split
        for (int p = 0; p < 7; p++)
            for (int l = 0; l < N_LAYERS; l++) {
                dim3 grid(Ndim[p] / 64, Kdim[p] / 64);
                fold_kernel<<<grid, 256, 0, stream>>>(
                    Wsrc[p] + (size_t)l * Kdim[p] * Ndim[p],
                    Asrc[p] + (size_t)l * Kdim[p] * R_LORA,
                    Bsrc[p] + (size_t)l * R_LORA * Ndim[p],
                    Whi[p] + (size_t)l * wsizes[p],
                    Wlo[p] + (size_t)l * wsizes[p],
                    Kdim[p], Ndim[p]);
            }

        init_soft_kernel<<<(T_LEN * V_DIM + 255) / 256, 256, 0, stream>>>(soft);

        for (int step = 0; step < N_STEPS; step++) {
            embed_kernel<<<T_LEN, 256, 0, stream>>>(soft, E, x);
            for (int l = 0; l < N_LAYERS; l++) {
                rms_split_kernel<<<T_LEN, 256, 0, stream>>>(x, ln1 + (size_t)l * D_DIM, h_hi, h_lo);
                gemm_mfma_kernel<<<dim3(16, 16), 256, 0, stream>>>(
                    h_hi, h_lo, Whi[0] + (size_t)l * DD, Wlo[0] + (size_t)l * DD,
                    qb, T_LEN, D_DIM, D_DIM, 0);
                gemm_mfma_kernel<<<dim3(16, 16), 256, 0, stream>>>(
                    h_hi, h_lo, Whi[1] + (size_t)l * DD, Wlo[1] + (size_t)l * DD,
                    kb, T_LEN, D_DIM, D_DIM, 0);
                gemm_mfma_kernel<<<dim3(16, 16), 256, 0, stream>>>(
                    h_hi, h_lo, Whi[2] + (size_t)l * DD, Wlo[2] + (size_t)l * DD,
                    vb, T_LEN, D_DIM, D_DIM, 0);
                attn_flash_kernel<<<dim3(T_LEN / 64, H_NUM), 256, 0, stream>>>(qb, kb, vb, c_hi, c_lo);
                gemm_mfma_kernel<<<dim3(16, 16), 256, 0, stream>>>(
                    c_hi, c_lo, Whi[3] + (size_t)l * DD, Wlo[3] + (size_t)l * DD,
                    x, T_LEN, D_DIM, D_DIM, 1);
                rms_split_kernel<<<T_LEN, 256, 0, stream>>>(x, ln2 + (size_t)l * D_DIM, h_hi, h_lo);
                gemm_mfma_kernel<<<dim3(64, 16), 256, 0, stream>>>(
                    h_hi, h_lo, Whi[4] + (size_t)l * DF, Wlo[4] + (size_t)l * DF,
                    gbuf, T_LEN, F_DIM, D_DIM, 0);
                gemm_mfma_kernel<<<dim3(64, 16), 256, 0, stream>>>(
                    h_hi, h_lo, Whi[5] + (size_t)l * DF, Wlo[5] + (size_t)l * DF,
                    ubuf, T_LEN, F_DIM, D_DIM, 0);
                silu_split_kernel<<<(T_LEN * F_DIM / 4 + 255) / 256, 256, 0, stream>>>(
                    gbuf, ubuf, f_hi, f_lo, T_LEN * F_DIM / 4);
                gemm_mfma_kernel<<<dim3(16, 16), 256, 0, stream>>>(
                    f_hi, f_lo, Whi[6] + (size_t)l * DF, Wlo[6] + (size_t)l * DF,
                    x, T_LEN, D_DIM, F_DIM, 1);
            }
            head_kernel<<<T_LEN, 256, 0, stream>>>(x, lnf, E, packed, soft);
        }
        argmax_kernel<<<(T_LEN + 255) / 256, 256, 0, stream>>>(soft, (int*)d_out);
        return;
    }

    // -------- fallback: round-1 fp32 path --------
    float* ws = (float*)d_ws;
    size_t off = 0;
    float* soft = ws + off; off += (size_t)T_LEN * V_DIM;
    float* x    = ws + off; off += (size_t)T_LEN * D_DIM;
    float* h    = ws + off; off += (size_t)T_LEN * D_DIM;
    float* qb   = ws + off; off += (size_t)T_LEN * D_DIM;
    float* kb   = ws + off; off += (size_t)T_LEN * D_DIM;
    float* vb   = ws + off; off += (size_t)T_LEN * D_DIM;
    float* cb   = ws + off; off += (size_t)T_LEN * D_DIM;
    float* gb   = ws + off; off += (size_t)T_LEN * F_DIM;
    float* ubf  = ws + off; off += (size_t)T_LEN * F_DIM;
    float* tmp  = ws + off; off += (size_t)T_LEN * R_LORA;

    init_soft_kernel<<<(T_LEN * V_DIM + 255) / 256, 256, 0, stream>>>(soft);
    for (int step = 0; step < N_STEPS; step++) {
        embed_kernel<<<T_LEN, 256, 0, stream>>>(soft, E, x);
        for (int l = 0; l < N_LAYERS; l++) {
            const float* ln1_l = ln1 + (size_t)l * D_DIM;
            const float* ln2_l = ln2 + (size_t)l * D_DIM;
            rms_kernel<<<T_LEN, 256, 0, stream>>>(x, ln1_l, h);
            launch_gemm(h, Asrc[0] + (size_t)l * D_DIM * R_LORA, tmp, T_LEN, R_LORA, D_DIM, 1.0f, 0, stream);
            launch_gemm(h, Wsrc[0] + (size_t)l * DD, qb, T_LEN, D_DIM, D_DIM, 1.0f, 0, stream);
            launch_gemm(tmp, Bsrc[0] + (size_t)l * R_LORA * D_DIM, qb, T_LEN, D_DIM, R_LORA, LORA_SCALE, 1, stream);
            launch_gemm(h, Asrc[1] + (size_t)l * D_DIM * R_LORA, tmp, T_LEN, R_LORA, D_DIM, 1.0f, 0, stream);
            launch_gemm(h, Wsrc[1] + (size_t)l * DD, kb, T_LEN, D_DIM, D_DIM, 1.0f, 0, stream);
            launch_gemm(tmp, Bsrc[1] + (size_t)l * R_LORA * D_DIM, kb, T_LEN, D_DIM, R_LORA, LORA_SCALE, 1, stream);
            launch_gemm(h, Asrc[2] + (size_t)l * D_DIM * R_LORA, tmp, T_LEN, R_LORA, D_DIM, 1.0f, 0, stream);
            launch_gemm(h, Wsrc[2] + (size_t)l * DD, vb, T_LEN, D_DIM, D_DIM, 1.0f, 0, stream);
            launch_gemm(tmp, Bsrc[2] + (size_t)l * R_LORA * D_DIM, vb, T_LEN, D_DIM, R_LORA, LORA_SCALE, 1, stream);
            attn_kernel<<<dim3(T_LEN, H_NUM), 256, 0, stream>>>(qb, kb, vb, cb);
            launch_gemm(cb, Asrc[3] + (size_t)l * D_DIM * R_LORA, tmp, T_LEN, R_LORA, D_DIM, 1.0f, 0, stream);
            launch_gemm(cb, Wsrc[3] + (size_t)l * DD, x, T_LEN, D_DIM, D_DIM, 1.0f, 1, stream);
            launch_gemm(tmp, Bsrc[3] + (size_t)l * R_LORA * D_DIM, x, T_LEN, D_DIM, R_LORA, LORA_SCALE, 1, stream);
            rms_kernel<<<T_LEN, 256, 0, stream>>>(x, ln2_l, h);
            launch_gemm(h, Asrc[4] + (size_t)l * D_DIM * R_LORA, tmp, T_LEN, R_LORA, D_DIM, 1.0f, 0, stream);
            launch_gemm(h, Wsrc[4] + (size_t)l * DF, gb, T_LEN, F_DIM, D_DIM, 1.0f, 0, stream);
            launch_gemm(tmp, Bsrc[4] + (size_t)l * R_LORA * F_DIM, gb, T_LEN, F_DIM, R_LORA, LORA_SCALE, 1, stream);
            launch_gemm(h, Asrc[5] + (size_t)l * D_DIM * R_LORA, tmp, T_LEN, R_LORA, D_DIM, 1.0f, 0, stream);
            launch_gemm(h, Wsrc[5] + (size_t)l * DF, ubf, T_LEN, F_DIM, D_DIM, 1.0f, 0, stream);
            launch_gemm(tmp, Bsrc[5] + (size_t)l * R_LORA * F_DIM, ubf, T_LEN, F_DIM, R_LORA, LORA_SCALE, 1, stream);
            silu_mul_kernel<<<(T_LEN * F_DIM + 255) / 256, 256, 0, stream>>>(gb, ubf, gb, T_LEN * F_DIM);
            launch_gemm(gb, Asrc[6] + (size_t)l * F_DIM * R_LORA, tmp, T_LEN, R_LORA, F_DIM, 1.0f, 0, stream);
            launch_gemm(gb, Wsrc[6] + (size_t)l * DF, x, T_LEN, D_DIM, F_DIM, 1.0f, 1, stream);
            launch_gemm(tmp, Bsrc[6] + (size_t)l * R_LORA * D_DIM, x, T_LEN, D_DIM, R_LORA, LORA_SCALE, 1, stream);
        }
        head_kernel<<<T_LEN, 256, 0, stream>>>(x, lnf, E, packed, soft);
    }
    argmax_kernel<<<(T_LEN + 255) / 256, 256, 0, stream>>>(soft, (int*)d_out);
}

// Round 3
// 1288.337 us; speedup vs baseline: 9.5616x; 1.5634x over previous
//
#include <hip/hip_runtime.h>
#include <hip/hip_bf16.h>

#define T_LEN 1024
#define D_DIM 1024
#define V_DIM 17
#define H_NUM 16
#define DH_DIM 64
#define F_DIM 4096
#define R_LORA 32
#define N_LAYERS 2
#define N_STEPS 2
#define MASK_ID 16
#define LORA_SCALE 2.0f

typedef __attribute__((ext_vector_type(8))) short bfx8;   // 8 bf16 in 4 VGPRs
typedef __attribute__((ext_vector_type(4))) float f32x4;

typedef unsigned short ushort_t;
typedef unsigned int uint_t;

__device__ __forceinline__ ushort_t f2bf(float v) {
    __hip_bfloat16 h = __float2bfloat16(v);
    return __builtin_bit_cast(unsigned short, h);
}
__device__ __forceinline__ float bf2f(ushort_t u) {
    return __uint_as_float(((uint_t)u) << 16);
}
__device__ __forceinline__ void split4_store(float y0, float y1, float y2, float y3,
                                             ushort_t* __restrict__ hi, ushort_t* __restrict__ lo,
                                             size_t idx) {
    ushort_t h0 = f2bf(y0), h1 = f2bf(y1), h2 = f2bf(y2), h3 = f2bf(y3);
    ushort_t l0 = f2bf(y0 - bf2f(h0));
    ushort_t l1 = f2bf(y1 - bf2f(h1));
    ushort_t l2 = f2bf(y2 - bf2f(h2));
    ushort_t l3 = f2bf(y3 - bf2f(h3));
    uint2 hv, lv;
    hv.x = (uint_t)h0 | ((uint_t)h1 << 16);
    hv.y = (uint_t)h2 | ((uint_t)h3 << 16);
    lv.x = (uint_t)l0 | ((uint_t)l1 << 16);
    lv.y = (uint_t)l2 | ((uint_t)l3 << 16);
    *(uint2*)(hi + idx) = hv;
    *(uint2*)(lo + idx) = lv;
}

// ---------------- init soft ----------------
__global__ void init_soft_kernel(float* __restrict__ soft) {
    int idx = blockIdx.x * blockDim.x + threadIdx.x;
    if (idx < T_LEN * V_DIM) {
        soft[idx] = ((idx % V_DIM) == MASK_ID) ? 1.0f : 0.0f;
    }
}

// ---------------- embed: x = soft @ E ----------------
__global__ __launch_bounds__(256) void embed_kernel(const float* __restrict__ soft,
                                                    const float* __restrict__ E,
                                                    float* __restrict__ x) {
    int t = blockIdx.x;
    __shared__ float srow[V_DIM];
    if (threadIdx.x < V_DIM) srow[threadIdx.x] = soft[t * V_DIM + threadIdx.x];
    __syncthreads();
    for (int d = threadIdx.x; d < D_DIM; d += 256) {
        float acc = 0.f;
        #pragma unroll
        for (int v = 0; v < V_DIM; v++) acc += srow[v] * E[v * D_DIM + d];
        x[(size_t)t * D_DIM + d] = acc;
    }
}

// ---------------- fold (batched over layers via z): out^T = split(W + 2*A@B) ----------------
__global__ __launch_bounds__(256) void fold_kernel(
    const float* __restrict__ W,   // [L,K,N]
    const float* __restrict__ A,   // [L,K,R]
    const float* __restrict__ Bm,  // [L,R,N]
    ushort_t* __restrict__ oHi,    // [L,N,K]
    ushort_t* __restrict__ oLo,
    int K, int N)
{
    const int l = blockIdx.z;
    W   += (size_t)l * K * N;
    A   += (size_t)l * K * R_LORA;
    Bm  += (size_t)l * R_LORA * N;
    oHi += (size_t)l * K * N;
    oLo += (size_t)l * K * N;
    __shared__ uint_t tile[64][65];
    const int tid = threadIdx.x;
    const int n0 = blockIdx.x * 64, k0 = blockIdx.y * 64;
    {
        const int nl = tid & 63, kq = tid >> 6;
        float breg[R_LORA];
        #pragma unroll
        for (int r = 0; r < R_LORA; r++) breg[r] = Bm[(size_t)r * N + n0 + nl];
        for (int i = 0; i < 16; i++) {
            const int kl = kq * 16 + i;
            const size_t kgl = (size_t)(k0 + kl);
            const float* arow = A + kgl * R_LORA;
            float acc = 0.f;
            #pragma unroll
            for (int r = 0; r < R_LORA; r++) acc = fmaf(arow[r], breg[r], acc);
            float val = W[kgl * N + n0 + nl] + LORA_SCALE * acc;
            ushort_t h = f2bf(val);
            ushort_t l2 = f2bf(val - bf2f(h));
            tile[kl][nl] = ((uint_t)h << 16) | (uint_t)l2;
        }
    }
    __syncthreads();
    {
        const int kl = tid & 63, nb = tid >> 6;
        for (int i = 0; i < 16; i++) {
            const int nl = nb * 16 + i;
            uint_t pk = tile[kl][nl];
            size_t idx = (size_t)(n0 + nl) * K + k0 + kl;
            oHi[idx] = (ushort_t)(pk >> 16);
            oLo[idx] = (ushort_t)(pk & 0xffffu);
        }
    }
}

// ---------------- rms + bf16-split ----------------
__global__ __launch_bounds__(256) void rms_split_kernel(
    const float* __restrict__ x, const float* __restrict__ w,
    ushort_t* __restrict__ hi, ushort_t* __restrict__ lo)
{
    const int t = blockIdx.x, tid = threadIdx.x;
    const float* xr = x + (size_t)t * D_DIM;
    float4 xv = *(const float4*)(xr + tid * 4);
    float ss = xv.x * xv.x + xv.y * xv.y + xv.z * xv.z + xv.w * xv.w;
    __shared__ float red[4];
    const int lane = tid & 63, wv = tid >> 6;
    #pragma unroll
    for (int off = 32; off > 0; off >>= 1) ss += __shfl_xor(ss, off);
    if (lane == 0) red[wv] = ss;
    __syncthreads();
    ss = red[0] + red[1] + red[2] + red[3];
    const float r = 1.0f / sqrtf(ss * (1.0f / D_DIM) + 1e-6f);
    const float4 wv4 = *(const float4*)(w + tid * 4);
    size_t base = (size_t)t * D_DIM + tid * 4;
    split4_store(xv.x * r * wv4.x, xv.y * r * wv4.y, xv.z * r * wv4.z, xv.w * r * wv4.w,
                 hi, lo, base);
}

// ---------------- MFMA split-bf16 GEMM with jobs (grid.z) ----------------
struct GemmJob {
    const ushort_t* Bh;
    const ushort_t* Bl;
    float* Cf;        // if non-null: f32 plain store
    ushort_t* Ch;     // else split store
    ushort_t* Cl;
    int k0, k1;
};

#define GLDK 36
__global__ __launch_bounds__(256) void gemm_mfma2_kernel(
    const ushort_t* __restrict__ Ahi, const ushort_t* __restrict__ Alo,
    int K, int N, GemmJob j0, GemmJob j1, GemmJob j2, GemmJob j3)
{
    GemmJob jb = (blockIdx.z == 0) ? j0 : (blockIdx.z == 1) ? j1 : (blockIdx.z == 2) ? j2 : j3;
    __shared__ ushort_t As[2][64][GLDK];
    __shared__ ushort_t Bs[2][64][GLDK];
    const int tid = threadIdx.x;
    const int lane = tid & 63;
    const int wave = tid >> 6;
    const int m0 = blockIdx.y * 64, n0 = blockIdx.x * 64;
    const int wm = (wave >> 1) * 32, wn = (wave & 1) * 32;
    const int l15 = lane & 15, lg = lane >> 4;
    const int srow = tid >> 2;
    const int skq = (tid & 3) * 8;

    f32x4 acc[2][2];
    #pragma unroll
    for (int i = 0; i < 2; i++)
        #pragma unroll
        for (int j = 0; j < 2; j++) acc[i][j] = f32x4{0.f, 0.f, 0.f, 0.f};

    const size_t aBase = (size_t)(m0 + srow) * K + skq;
    const size_t bBase = (size_t)(n0 + srow) * K + skq;

    for (int k0 = jb.k0; k0 < jb.k1; k0 += 32) {
        uint4 va = *(const uint4*)(Ahi + aBase + k0);
        uint4 vb = *(const uint4*)(Alo + aBase + k0);
        uint4 vc = *(const uint4*)(jb.Bh + bBase + k0);
        uint4 vd = *(const uint4*)(jb.Bl + bBase + k0);
        {
            uint_t* p = (uint_t*)&As[0][srow][skq];
            p[0] = va.x; p[1] = va.y; p[2] = va.z; p[3] = va.w;
            uint_t* q = (uint_t*)&As[1][srow][skq];
            q[0] = vb.x; q[1] = vb.y; q[2] = vb.z; q[3] = vb.w;
            uint_t* r = (uint_t*)&Bs[0][srow][skq];
            r[0] = vc.x; r[1] = vc.y; r[2] = vc.z; r[3] = vc.w;
            uint_t* s = (uint_t*)&Bs[1][srow][skq];
            s[0] = vd.x; s[1] = vd.y; s[2] = vd.z; s[3] = vd.w;
        }
        __syncthreads();
        bfx8 ah[2], al[2], bh[2], bl[2];
        #pragma unroll
        for (int mi = 0; mi < 2; mi++) {
            ah[mi] = *(const bfx8*)&As[0][wm + mi * 16 + l15][lg * 8];
            al[mi] = *(const bfx8*)&As[1][wm + mi * 16 + l15][lg * 8];
        }
        #pragma unroll
        for (int ni = 0; ni < 2; ni++) {
            bh[ni] = *(const bfx8*)&Bs[0][wn + ni * 16 + l15][lg * 8];
            bl[ni] = *(const bfx8*)&Bs[1][wn + ni * 16 + l15][lg * 8];
        }
        #pragma unroll
        for (int mi = 0; mi < 2; mi++)
            #pragma unroll
            for (int ni = 0; ni < 2; ni++) {
                acc[mi][ni] = __builtin_amdgcn_mfma_f32_16x16x32_bf16(ah[mi], bh[ni], acc[mi][ni], 0, 0, 0);
                acc[mi][ni] = __builtin_amdgcn_mfma_f32_16x16x32_bf16(ah[mi], bl[ni], acc[mi][ni], 0, 0, 0);
                acc[mi][ni] = __builtin_amdgcn_mfma_f32_16x16x32_bf16(al[mi], bh[ni], acc[mi][ni], 0, 0, 0);
            }
        __syncthreads();
    }
    if (jb.Cf) {
        #pragma unroll
        for (int mi = 0; mi < 2; mi++)
            #pragma unroll
            for (int ni = 0; ni < 2; ni++) {
                int col = n0 + wn + ni * 16 + l15;
                #pragma unroll
                for (int i = 0; i < 4; i++) {
                    int row = m0 + wm + mi * 16 + lg * 4 + i;
                    jb.Cf[(size_t)row * N + col] = acc[mi][ni][i];
                }
            }
    } else {
        #pragma unroll
        for (int mi = 0; mi < 2; mi++)
            #pragma unroll
            for (int ni = 0; ni < 2; ni++) {
                int col = n0 + wn + ni * 16 + l15;
                #pragma unroll
                for (int i = 0; i < 4; i++) {
                    int row = m0 + wm + mi * 16 + lg * 4 + i;
                    size_t idx = (size_t)row * N + col;
                    float v = acc[mi][ni][i];
                    ushort_t h = f2bf(v);
                    jb.Ch[idx] = h;
                    jb.Cl[idx] = f2bf(v - bf2f(h));
                }
            }
    }
}

// ---------------- add2 / add4: x += sum(partials) ----------------
__global__ void add2_kernel(float* __restrict__ x, const float* __restrict__ p0,
                            const float* __restrict__ p1, int n4) {
    int i = blockIdx.x * blockDim.x + threadIdx.x;
    if (i < n4) {
        float4 xv = *(const float4*)(x + (size_t)i * 4);
        float4 a = *(const float4*)(p0 + (size_t)i * 4);
        float4 b = *(const float4*)(p1 + (size_t)i * 4);
        xv.x += a.x + b.x; xv.y += a.y + b.y; xv.z += a.z + b.z; xv.w += a.w + b.w;
        *(float4*)(x + (size_t)i * 4) = xv;
    }
}
__global__ void add4_kernel(float* __restrict__ x, const float* __restrict__ p0,
                            const float* __restrict__ p1, const float* __restrict__ p2,
                            const float* __restrict__ p3, int n4) {
    int i = blockIdx.x * blockDim.x + threadIdx.x;
    if (i < n4) {
        float4 xv = *(const float4*)(x + (size_t)i * 4);
        float4 a = *(const float4*)(p0 + (size_t)i * 4);
        float4 b = *(const float4*)(p1 + (size_t)i * 4);
        float4 c = *(const float4*)(p2 + (size_t)i * 4);
        float4 d = *(const float4*)(p3 + (size_t)i * 4);
        xv.x += a.x + b.x + c.x + d.x;
        xv.y += a.y + b.y + c.y + d.y;
        xv.z += a.z + b.z + c.z + d.z;
        xv.w += a.w + b.w + c.w + d.w;
        *(float4*)(x + (size_t)i * 4) = xv;
    }
}

// ---------------- MFMA flash attention ----------------
// block = (q-tile of 64 rows, head). 4 waves, each owns a 16-q-row strip.
// Inputs q/k/v as bf16 hi/lo splits [T][D]. Output ctx split [T][D].
#define KS_PAD 72
#define P_PAD 72
__global__ __launch_bounds__(256, 1) void attn_mfma_kernel(
    const ushort_t* __restrict__ qh, const ushort_t* __restrict__ ql,
    const ushort_t* __restrict__ kh, const ushort_t* __restrict__ kl,
    const ushort_t* __restrict__ vh, const ushort_t* __restrict__ vl,
    ushort_t* __restrict__ chi, ushort_t* __restrict__ clo)
{
    __shared__ ushort_t Ksh[64][KS_PAD];
    __shared__ ushort_t Ksl[64][KS_PAD];
    __shared__ ushort_t VTh[64][KS_PAD];   // transposed V: [d][k]
    __shared__ ushort_t VTl[64][KS_PAD];
    __shared__ ushort_t Ph[4][16][P_PAD];  // per-wave P strips
    __shared__ ushort_t Pl[4][16][P_PAD];

    const int qt = blockIdx.x, hh = blockIdx.y;
    const int tid = threadIdx.x, w = tid >> 6, lane = tid & 63;
    const int l15 = lane & 15, lg = lane >> 4;
    const int q0 = qt * 64;
    const int hcol = hh * DH_DIM;

    // Q A-fragments in registers
    bfx8 qa_h[2], qa_l[2];
    {
        size_t qrow = (size_t)(q0 + w * 16 + l15) * D_DIM + hcol;
        #pragma unroll
        for (int ks = 0; ks < 2; ks++) {
            qa_h[ks] = *(const bfx8*)(qh + qrow + ks * 32 + lg * 8);
            qa_l[ks] = *(const bfx8*)(ql + qrow + ks * 32 + lg * 8);
        }
    }

    f32x4 o[4];
    #pragma unroll
    for (int ni = 0; ni < 4; ni++) o[ni] = f32x4{0.f, 0.f, 0.f, 0.f};
    float mrun[4], lrun[4];
    #pragma unroll
    for (int i = 0; i < 4; i++) { mrun[i] = -3.0e38f; lrun[i] = 0.f; }

    const int srow = tid >> 2;            // K staging: 64 rows, 4 threads/row
    const int sseg = (tid & 3) * 16;
    const int vp = tid & 31;              // V staging: k-pair index
    const int vd0 = (tid >> 5) * 8;       // 8 d values per thread

    for (int kt = 0; kt <= qt; kt++) {
        __syncthreads();
        {   // stage K tile [64 k][64 d]
            size_t src = (size_t)(kt * 64 + srow) * D_DIM + hcol + sseg;
            *(uint4*)&Ksh[srow][sseg]     = *(const uint4*)(kh + src);
            *(uint4*)&Ksh[srow][sseg + 8] = *(const uint4*)(kh + src + 8);
            *(uint4*)&Ksl[srow][sseg]     = *(const uint4*)(kl + src);
            *(uint4*)&Ksl[srow][sseg + 8] = *(const uint4*)(kl + src + 8);
        }
        {   // stage V transposed: VT[d][k], pack k-pair into one u32 write
            size_t s0 = (size_t)(kt * 64 + 2 * vp) * D_DIM + hcol + vd0;
            uint4 h0 = *(const uint4*)(vh + s0);
            uint4 h1 = *(const uint4*)(vh + s0 + D_DIM);
            uint4 l0 = *(const uint4*)(vl + s0);
            uint4 l1 = *(const uint4*)(vl + s0 + D_DIM);
            const ushort_t* a = (const ushort_t*)&h0;
            const ushort_t* b = (const ushort_t*)&h1;
            const ushort_t* c = (const ushort_t*)&l0;
            const ushort_t* d = (const ushort_t*)&l1;
            #pragma unroll
            for (int j = 0; j < 8; j++) {
                *(uint_t*)&VTh[vd0 + j][2 * vp] = (uint_t)a[j] | ((uint_t)b[j] << 16);
                *(uint_t*)&VTl[vd0 + j][2 * vp] = (uint_t)c[j] | ((uint_t)d[j] << 16);
            }
        }
        __syncthreads();

        // ---- QK^T: S strip [16 q][64 k] ----
        f32x4 s[4];
        #pragma unroll
        for (int ni = 0; ni < 4; ni++) s[ni] = f32x4{0.f, 0.f, 0.f, 0.f};
        #pragma unroll
        for (int ks = 0; ks < 2; ks++) {
            #pragma unroll
            for (int ni = 0; ni < 4; ni++) {
                bfx8 bh = *(const bfx8*)&Ksh[ni * 16 + l15][ks * 32 + lg * 8];
                bfx8 bl = *(const bfx8*)&Ksl[ni * 16 + l15][ks * 32 + lg * 8];
                s[ni] = __builtin_amdgcn_mfma_f32_16x16x32_bf16(qa_h[ks], bh, s[ni], 0, 0, 0);
                s[ni] = __builtin_amdgcn_mfma_f32_16x16x32_bf16(qa_h[ks], bl, s[ni], 0, 0, 0);
                s[ni] = __builtin_amdgcn_mfma_f32_16x16x32_bf16(qa_l[ks], bh, s[ni], 0, 0, 0);
            }
        }

        // ---- scale + causal mask + row max ----
        const int kbase = kt * 64;
        float rmax[4];
        #pragma unroll
        for (int i = 0; i < 4; i++) rmax[i] = -3.0e38f;
        #pragma unroll
        for (int ni = 0; ni < 4; ni++) {
            int kc = kbase + ni * 16 + l15;
            #pragma unroll
            for (int i = 0; i < 4; i++) {
                int qrow = q0 + w * 16 + lg * 4 + i;
                float v = s[ni][i] * 0.125f;
                v = (kc <= qrow) ? v : -3.0e38f;
                s[ni][i] = v;
                rmax[i] = fmaxf(rmax[i], v);
            }
        }
        #pragma unroll
        for (int off = 1; off < 16; off <<= 1) {
            #pragma unroll
            for (int i = 0; i < 4; i++) rmax[i] = fmaxf(rmax[i], __shfl_xor(rmax[i], off));
        }
        // ---- online softmax update ----
        float psum[4];
        #pragma unroll
        for (int i = 0; i < 4; i++) {
            float nm = fmaxf(mrun[i], rmax[i]);
            float sc = __expf(mrun[i] - nm);
            lrun[i] *= sc;
            #pragma unroll
            for (int ni = 0; ni < 4; ni++) o[ni][i] *= sc;
            mrun[i] = nm;
            psum[i] = 0.f;
        }
        #pragma unroll
        for (int ni = 0; ni < 4; ni++) {
            #pragma unroll
            for (int i = 0; i < 4; i++) {
                float e = __expf(s[ni][i] - mrun[i]);
                s[ni][i] = e;
                psum[i] += e;
            }
        }
        #pragma unroll
        for (int off = 1; off < 16; off <<= 1) {
            #pragma unroll
            for (int i = 0; i < 4; i++) psum[i] += __shfl_xor(psum[i], off);
        }
        #pragma unroll
        for (int i = 0; i < 4; i++) lrun[i] += psum[i];

        // ---- P -> split bf16 -> per-wave LDS ----
        #pragma unroll
        for (int ni = 0; ni < 4; ni++) {
            #pragma unroll
            for (int i = 0; i < 4; i++) {
                float e = s[ni][i];
                ushort_t hp = f2bf(e);
                Ph[w][lg * 4 + i][ni * 16 + l15] = hp;
                Pl[w][lg * 4 + i][ni * 16 + l15] = f2bf(e - bf2f(hp));
            }
        }
        // ---- PV: o += P @ V ----
        #pragma unroll
        for (int ks = 0; ks < 2; ks++) {
            bfx8 ah = *(const bfx8*)&Ph[w][l15][ks * 32 + lg * 8];
            bfx8 al = *(const bfx8*)&Pl[w][l15][ks * 32 + lg * 8];
            #pragma unroll
            for (int ni = 0; ni < 4; ni++) {
                bfx8 bh = *(const bfx8*)&VTh[ni * 16 + l15][ks * 32 + lg * 8];
                bfx8 bl = *(const bfx8*)&VTl[ni * 16 + l15][ks * 32 + lg * 8];
                o[ni] = __builtin_amdgcn_mfma_f32_16x16x32_bf16(ah, bh, o[ni], 0, 0, 0);
                o[ni] = __builtin_amdgcn_mfma_f32_16x16x32_bf16(ah, bl, o[ni], 0, 0, 0);
                o[ni] = __builtin_amdgcn_mfma_f32_16x16x32_bf16(al, bh, o[ni], 0, 0, 0);
            }
        }
    }

    // epilogue: normalize + split store
    #pragma unroll
    for (int i = 0; i < 4; i++) {
        float inv = 1.0f / lrun[i];
        #pragma unroll
        for (int ni = 0; ni < 4; ni++) o[ni][i] *= inv;
    }
    #pragma unroll
    for (int ni = 0; ni < 4; ni++) {
        int col = hcol + ni * 16 + l15;
        #pragma unroll
        for (int i = 0; i < 4; i++) {
            int row = q0 + w * 16 + lg * 4 + i;
            size_t idx = (size_t)row * D_DIM + col;
            float v = o[ni][i];
            ushort_t hp = f2bf(v);
            chi[idx] = hp;
            clo[idx] = f2bf(v - bf2f(hp));
        }
    }
}

// ---------------- silu(g)*u -> split ----------------
__global__ void silu_split_kernel(const float* __restrict__ g, const float* __restrict__ u,
                                  ushort_t* __restrict__ hi, ushort_t* __restrict__ lo, int n4) {
    int i = blockIdx.x * blockDim.x + threadIdx.x;
    if (i < n4) {
        float4 gv = *(const float4*)(g + (size_t)i * 4);
        float4 uv = *(const float4*)(u + (size_t)i * 4);
        float y0 = gv.x / (1.f + expf(-gv.x)) * uv.x;
        float y1 = gv.y / (1.f + expf(-gv.y)) * uv.y;
        float y2 = gv.z / (1.f + expf(-gv.z)) * uv.z;
        float y3 = gv.w / (1.f + expf(-gv.w)) * uv.w;
        split4_store(y0, y1, y2, y3, hi, lo, (size_t)i * 4);
    }
}

// ---------------- head ----------------
__global__ __launch_bounds__(256) void head_kernel(const float* __restrict__ x,
                                                   const float* __restrict__ lnf,
                                                   const float* __restrict__ E,
                                                   const int* __restrict__ tok,
                                                   float* __restrict__ soft) {
    int t = blockIdx.x;
    int tid = threadIdx.x;
    __shared__ float y[D_DIM];
    __shared__ float red[4];
    __shared__ float logits[V_DIM];
    const float* xr = x + (size_t)t * D_DIM;
    float ss = 0.f;
    for (int d = tid; d < D_DIM; d += 256) { float v = xr[d]; ss += v * v; }
    int lane = tid & 63, wave = tid >> 6;
    for (int off = 32; off > 0; off >>= 1) ss += __shfl_xor(ss, off);
    if (lane == 0) red[wave] = ss;
    __syncthreads();
    ss = red[0] + red[1] + red[2] + red[3];
    float r = 1.0f / sqrtf(ss * (1.0f / D_DIM) + 1e-6f);
    for (int d = tid; d < D_DIM; d += 256) y[d] = xr[d] * r * lnf[d];
    __syncthreads();
    for (int vv = wave; vv < V_DIM; vv += 4) {
        float p = 0.f;
        for (int d = lane; d < D_DIM; d += 64) p += y[d] * E[vv * D_DIM + d];
        for (int off = 32; off > 0; off >>= 1) p += __shfl_xor(p, off);
        if (lane == 0) logits[vv] = p;
    }
    __syncthreads();
    if (tid == 0) {
        int tk = tok[t];
        if (tk != MASK_ID) {
            for (int vv = 0; vv < V_DIM; vv++) soft[t * V_DIM + vv] = (vv == tk) ? 1.f : 0.f;
        } else {
            float mx = -1e30f;
            for (int vv = 0; vv < V_DIM; vv++) mx = fmaxf(mx, logits[vv]);
            float sm = 0.f;
            float e[V_DIM];
            for (int vv = 0; vv < V_DIM; vv++) { e[vv] = expf(logits[vv] - mx); sm += e[vv]; }
            float invs = 1.0f / sm;
            for (int vv = 0; vv < V_DIM; vv++) soft[t * V_DIM + vv] = e[vv] * invs;
        }
    }
}

// ---------------- argmax ----------------
__global__ void argmax_kernel(const float* __restrict__ soft, int* __restrict__ out) {
    int t = blockIdx.x * blockDim.x + threadIdx.x;
    if (t < T_LEN) {
        const float* s = soft + t * V_DIM;
        int best = 0;
        float bv = s[0];
        #pragma unroll
        for (int vv = 1; vv < V_DIM; vv++) {
            float v = s[vv];
            if (v > bv) { bv = v; best = vv; }
        }
        out[t] = best;
    }
}

// ================= fallback kernels (fp32, if ws too small) =================
__global__ __launch_bounds__(256) void rms_kernel(const float* __restrict__ x,
                                                  const float* __restrict__ w,
                                                  float* __restrict__ out) {
    int t = blockIdx.x;
    const float* xr = x + (size_t)t * D_DIM;
    float ss = 0.f;
    for (int d = threadIdx.x; d < D_DIM; d += 256) { float v = xr[d]; ss += v * v; }
    __shared__ float red[4];
    int lane = threadIdx.x & 63, wave = threadIdx.x >> 6;
    for (int off = 32; off > 0; off >>= 1) ss += __shfl_xor(ss, off);
    if (lane == 0) red[wave] = ss;
    __syncthreads();
    ss = red[0] + red[1] + red[2] + red[3];
    float r = 1.0f / sqrtf(ss * (1.0f / D_DIM) + 1e-6f);
    for (int d = threadIdx.x; d < D_DIM; d += 256) out[(size_t)t * D_DIM + d] = xr[d] * r * w[d];
}

__global__ __launch_bounds__(256) void gemm_kernel(const float* __restrict__ A,
                                                   const float* __restrict__ B,
                                                   float* __restrict__ C,
                                                   int M, int N, int K,
                                                   float alpha, int accumulate) {
    const int BM = 64, BN = 64, BK = 16;
    __shared__ float As[BK][BM];
    __shared__ float Bsh[BK][BN];
    int tid = threadIdx.x;
    int tx = tid % 16, ty = tid / 16;
    int row0 = blockIdx.y * BM, col0 = blockIdx.x * BN;
    float acc[4][4] = {};
    for (int k0 = 0; k0 < K; k0 += BK) {
        #pragma unroll
        for (int i = 0; i < 4; i++) {
            int e = tid * 4 + i;
            int m = e / BK, kk = e % BK;
            int gr = row0 + m, gk = k0 + kk;
            As[kk][m] = (gr < M && gk < K) ? A[(size_t)gr * K + gk] : 0.f;
        }
        #pragma unroll
        for (int i = 0; i < 4; i++) {
            int e = tid * 4 + i;
            int kk = e / BN, n = e % BN;
            int gk = k0 + kk, gc = col0 + n;
            Bsh[kk][n] = (gk < K && gc < N) ? B[(size_t)gk * N + gc] : 0.f;
        }
        __syncthreads();
        #pragma unroll
        for (int kk = 0; kk < BK; kk++) {
            float a[4], b[4];
            #pragma unroll
            for (int i = 0; i < 4; i++) a[i] = As[kk][ty * 4 + i];
            #pragma unroll
            for (int j = 0; j < 4; j++) b[j] = Bsh[kk][tx * 4 + j];
            #pragma unroll
            for (int i = 0; i < 4; i++)
                #pragma unroll
                for (int j = 0; j < 4; j++)
                    acc[i][j] += a[i] * b[j];
        }
        __syncthreads();
    }
    #pragma unroll
    for (int i = 0; i < 4; i++) {
        int r = row0 + ty * 4 + i;
        if (r >= M) continue;
        #pragma unroll
        for (int j = 0; j < 4; j++) {
            int c = col0 + tx * 4 + j;
            if (c >= N) continue;
            size_t idx = (size_t)r * N + c;
            float val = alpha * acc[i][j];
            if (accumulate) val += C[idx];
            C[idx] = val;
        }
    }
}

__global__ __launch_bounds__(256) void attn_kernel(const float* __restrict__ q,
                                                   const float* __restrict__ k,
                                                   const float* __restrict__ v,
                                                   float* __restrict__ ctx) {
    int qi = blockIdx.x;
    int hh = blockIdx.y;
    __shared__ float sc[T_LEN];
    __shared__ float qrow[DH_DIM];
    __shared__ float red[8];
    __shared__ float part[4][DH_DIM];
    int tid = threadIdx.x;
    int lane = tid & 63, wave = tid >> 6;
    const float* qp = q + (size_t)qi * D_DIM + hh * DH_DIM;
    if (tid < DH_DIM) qrow[tid] = qp[tid];
    __syncthreads();
    const float scale = 0.125f;
    for (int j = wave; j <= qi; j += 4) {
        const float* kp = k + (size_t)j * D_DIM + hh * DH_DIM;
        float p = qrow[lane] * kp[lane];
        for (int off = 32; off > 0; off >>= 1) p += __shfl_xor(p, off);
        if (lane == 0) sc[j] = p * scale;
    }
    __syncthreads();
    int n = qi + 1;
    float m = -1e30f;
    for (int j = tid; j < n; j += 256) m = fmaxf(m, sc[j]);
    for (int off = 32; off > 0; off >>= 1) m = fmaxf(m, __shfl_xor(m, off));
    if (lane == 0) red[wave] = m;
    __syncthreads();
    m = fmaxf(fmaxf(red[0], red[1]), fmaxf(red[2], red[3]));
    float s = 0.f;
    for (int j = tid; j < n; j += 256) { float e = expf(sc[j] - m); sc[j] = e; s += e; }
    for (int off = 32; off > 0; off >>= 1) s += __shfl_xor(s, off);
    if (lane == 0) red[4 + wave] = s;
    __syncthreads();
    s = red[4] + red[5] + red[6] + red[7];
    float inv = 1.0f / s;
    float acc = 0.f;
    for (int j = wave; j < n; j += 4) {
        acc += sc[j] * v[(size_t)j * D_DIM + hh * DH_DIM + lane];
    }
    part[wave][lane] = acc;
    __syncthreads();
    if (tid < DH_DIM) {
        float r = (part[0][tid] + part[1][tid] + part[2][tid] + part[3][tid]) * inv;
        ctx[(size_t)qi * D_DIM + hh * DH_DIM + tid] = r;
    }
}

__global__ void silu_mul_kernel(const float* __restrict__ g, const float* __restrict__ u,
                                float* __restrict__ out, int nelem) {
    int i = blockIdx.x * blockDim.x + threadIdx.x;
    if (i < nelem) {
        float gv = g[i];
        float sg = 1.0f / (1.0f + expf(-gv));
        out[i] = gv * sg * u[i];
    }
}

static inline void launch_gemm(const float* A, const float* B, float* C,
                               int M, int N, int K, float alpha, int accumulate,
                               hipStream_t stream) {
    dim3 grid((N + 63) / 64, (M + 63) / 64);
    gemm_kernel<<<grid, 256, 0, stream>>>(A, B, C, M, N, K, alpha, accumulate);
}

// =====================================================================================
extern "C" void kernel_launch(void* const* d_in, const int* in_sizes, int n_in,
                              void* d_out, int out_size, void* d_ws, size_t ws_size,
                              hipStream_t stream) {
    const int* packed = (const int*)d_in[0];
    const float* E  = (const float*)d_in[6];
    const float* Wsrc[7] = {(const float*)d_in[7],  (const float*)d_in[10], (const float*)d_in[13],
                            (const float*)d_in[16], (const float*)d_in[19], (const float*)d_in[22],
                            (const float*)d_in[25]};
    const float* Asrc[7] = {(const float*)d_in[8],  (const float*)d_in[11], (const float*)d_in[14],
                            (const float*)d_in[17], (const float*)d_in[20], (const float*)d_in[23],
                            (const float*)d_in[26]};
    const float* Bsrc[7] = {(const float*)d_in[9],  (const float*)d_in[12], (const float*)d_in[15],
                            (const float*)d_in[18], (const float*)d_in[21], (const float*)d_in[24],
                            (const float*)d_in[27]};
    const float* ln1 = (const float*)d_in[28];
    const float* ln2 = (const float*)d_in[29];
    const float* lnf = (const float*)d_in[30];

    const size_t DD = (size_t)D_DIM * D_DIM;     // 1M
    const size_t DF = (size_t)D_DIM * F_DIM;     // 4M
    const size_t wsizes[7] = {DD, DD, DD, DD, DF, DF, DF};
    const int Kdim[7] = {D_DIM, D_DIM, D_DIM, D_DIM, D_DIM, D_DIM, F_DIM};
    const int Ndim[7] = {D_DIM, D_DIM, D_DIM, D_DIM, F_DIM, F_DIM, D_DIM};

    // fast-path workspace requirement
    size_t u16_elems = 0;
    for (int p = 0; p < 7; p++) u16_elems += 2ull * N_LAYERS * wsizes[p];  // folded hi/lo
    u16_elems += 2ull * DD;            // h hi/lo
    u16_elems += 2ull * DD;            // ctx hi/lo
    u16_elems += 2ull * DF;            // ff hi/lo
    u16_elems += 6ull * DD;            // q,k,v hi/lo
    size_t f32_elems = (size_t)T_LEN * V_DIM + DD /*x*/ + 2 * DF /*g,u (p0..3 alias)*/;
    size_t need = u16_elems * 2 + f32_elems * 4 + 256;

    if (ws_size >= need) {
        // -------- fast path --------
        ushort_t* ub = (ushort_t*)d_ws;
        size_t uo = 0;
        ushort_t *Whi[7], *Wlo[7];
        for (int p = 0; p < 7; p++) {
            Whi[p] = ub + uo; uo += (size_t)N_LAYERS * wsizes[p];
            Wlo[p] = ub + uo; uo += (size_t)N_LAYERS * wsizes[p];
        }
        ushort_t* h_hi = ub + uo; uo += DD;
        ushort_t* h_lo = ub + uo; uo += DD;
        ushort_t* c_hi = ub + uo; uo += DD;
        ushort_t* c_lo = ub + uo; uo += DD;
        ushort_t* f_hi = ub + uo; uo += DF;
        ushort_t* f_lo = ub + uo; uo += DF;
        ushort_t* qbh = ub + uo; uo += DD;
        ushort_t* qbl = ub + uo; uo += DD;
        ushort_t* kbh = ub + uo; uo += DD;
        ushort_t* kbl = ub + uo; uo += DD;
        ushort_t* vbh = ub + uo; uo += DD;
        ushort_t* vbl = ub + uo; uo += DD;
        float* fb = (float*)(ub + uo);
        size_t fo = 0;
        float* soft = fb + fo; fo += (size_t)T_LEN * V_DIM;
        float* x    = fb + fo; fo += DD;
        float* gbuf = fb + fo; fo += DF;
        float* ubuf = fb + fo; fo += DF;
        // split-K partial buffers alias gbuf (different live ranges)
        float* p0 = gbuf;
        float* p1 = gbuf + DD;
        float* p2 = gbuf + 2 * DD;
        float* p3 = gbuf + 3 * DD;

        // fold weights (batched over layers)
        for (int p = 0; p < 7; p++) {
            dim3 grid(Ndim[p] / 64, Kdim[p] / 64, N_LAYERS);
            fold_kernel<<<grid, 256, 0, stream>>>(Wsrc[p], Asrc[p], Bsrc[p],
                                                  Whi[p], Wlo[p], Kdim[p], Ndim[p]);
        }

        init_soft_kernel<<<(T_LEN * V_DIM + 255) / 256, 256, 0, stream>>>(soft);

        const int n4 = (int)(DD / 4);
        for (int step = 0; step < N_STEPS; step++) {
            embed_kernel<<<T_LEN, 256, 0, stream>>>(soft, E, x);
            for (int l = 0; l < N_LAYERS; l++) {
                rms_split_kernel<<<T_LEN, 256, 0, stream>>>(x, ln1 + (size_t)l * D_DIM, h_hi, h_lo);
                {   // fused QKV
                    GemmJob jq = {Whi[0] + l * DD, Wlo[0] + l * DD, nullptr, qbh, qbl, 0, D_DIM};
                    GemmJob jk = {Whi[1] + l * DD, Wlo[1] + l * DD, nullptr, kbh, kbl, 0, D_DIM};
                    GemmJob jv = {Whi[2] + l * DD, Wlo[2] + l * DD, nullptr, vbh, vbl, 0, D_DIM};
                    gemm_mfma2_kernel<<<dim3(16, 16, 3), 256, 0, stream>>>(
                        h_hi, h_lo, D_DIM, D_DIM, jq, jk, jv, jq);
                }
                attn_mfma_kernel<<<dim3(T_LEN / 64, H_NUM), 256, 0, stream>>>(
                    qbh, qbl, kbh, kbl, vbh, vbl, c_hi, c_lo);
                {   // o-proj split-K x2
                    GemmJob ja = {Whi[3] + l * DD, Wlo[3] + l * DD, p0, nullptr, nullptr, 0, 512};
                    GemmJob jb = {Whi[3] + l * DD, Wlo[3] + l * DD, p1, nullptr, nullptr, 512, 1024};
                    gemm_mfma2_kernel<<<dim3(16, 16, 2), 256, 0, stream>>>(
                        c_hi, c_lo, D_DIM, D_DIM, ja, jb, ja, ja);
                    add2_kernel<<<(n4 + 255) / 256, 256, 0, stream>>>(x, p0, p1, n4);
                }
                rms_split_kernel<<<T_LEN, 256, 0, stream>>>(x, ln2 + (size_t)l * D_DIM, h_hi, h_lo);
                {   // fused G,U
                    GemmJob jg = {Whi[4] + l * DF, Wlo[4] + l * DF, gbuf, nullptr, nullptr, 0, D_DIM};
                    GemmJob ju = {Whi[5] + l * DF, Wlo[5] + l * DF, ubuf, nullptr, nullptr, 0, D_DIM};
                    gemm_mfma2_kernel<<<dim3(64, 16, 2), 256, 0, stream>>>(
                        h_hi, h_lo, D_DIM, F_DIM, jg, ju, jg, jg);
                }
                silu_split_kernel<<<(T_LEN * F_DIM / 4 + 255) / 256, 256, 0, stream>>>(
                    gbuf, ubuf, f_hi, f_lo, T_LEN * F_DIM / 4);
                {   // d-proj split-K x4 (K=4096)
                    const ushort_t* bh = Whi[6] + l * DF;
                    const ushort_t* bl = Wlo[6] + l * DF;
                    GemmJob ja = {bh, bl, p0, nullptr, nullptr, 0, 1024};
                    GemmJob jb = {bh, bl, p1, nullptr, nullptr, 1024, 2048};
                    GemmJob jc = {bh, bl, p2, nullptr, nullptr, 2048, 3072};
                    GemmJob jd = {bh, bl, p3, nullptr, nullptr, 3072, 4096};
                    gemm_mfma2_kernel<<<dim3(16, 16, 4), 256, 0, stream>>>(
                        f_hi, f_lo, F_DIM, D_DIM, ja, jb, jc, jd);
                    add4_kernel<<<(n4 + 255) / 256, 256, 0, stream>>>(x, p0, p1, p2, p3, n4);
                }
            }
            head_kernel<<<T_LEN, 256, 0, stream>>>(x, lnf, E, packed, soft);
        }
        argmax_kernel<<<(T_LEN + 255) / 256, 256, 0, stream>>>(soft, (int*)d_out);
        return;
    }

    // -------- fallback: fp32 path --------
    float* ws = (float*)d_ws;
    size_t off = 0;
    float* soft = ws + off; off += (size_t)T_LEN * V_DIM;
    float* x    = ws + off; off += (size_t)T_LEN * D_DIM;
    float* h    = ws + off; off += (size_t)T_LEN * D_DIM;
    float* qb   = ws + off; off += (size_t)T_LEN * D_DIM;
    float* kb   = ws + off; off += (size_t)T_LEN * D_DIM;
    float* vb   = ws + off; off += (size_t)T_LEN * D_DIM;
    float* cb   = ws + off; off += (size_t)T_LEN * D_DIM;
    float* gb   = ws + off; off += (size_t)T_LEN * F_DIM;
    float* ubf  = ws + off; off += (size_t)T_LEN * F_DIM;
    float* tmp  = ws + off; off += (size_t)T_LEN * R_LORA;

    init_soft_kernel<<<(T_LEN * V_DIM + 255) / 256, 256, 0, stream>>>(soft);
    for (int step = 0; step < N_STEPS; step++) {
        embed_kernel<<<T_LEN, 256, 0, stream>>>(soft, E, x);
        for (int l = 0; l < N_LAYERS; l++) {
            const float* ln1_l = ln1 + (size_t)l * D_DIM;
            const float* ln2_l = ln2 + (size_t)l * D_DIM;
            rms_kernel<<<T_LEN, 256, 0, stream>>>(x, ln1_l, h);
            launch_gemm(h, Asrc[0] + (size_t)l * D_DIM * R_LORA, tmp, T_LEN, R_LORA, D_DIM, 1.0f, 0, stream);
            launch_gemm(h, Wsrc[0] + (size_t)l * DD, qb, T_LEN, D_DIM, D_DIM, 1.0f, 0, stream);
            launch_gemm(tmp, Bsrc[0] + (size_t)l * R_LORA * D_DIM, qb, T_LEN, D_DIM, R_LORA, LORA_SCALE, 1, stream);
            launch_gemm(h, Asrc[1] + (size_t)l * D_DIM * R_LORA, tmp, T_LEN, R_LORA, D_DIM, 1.0f, 0, stream);
            launch_gemm(h, Wsrc[1] + (size_t)l * DD, kb, T_LEN, D_DIM, D_DIM, 1.0f, 0, stream);
            launch_gemm(tmp, Bsrc[1] + (size_t)l * R_LORA * D_DIM, kb, T_LEN, D_DIM, R_LORA, LORA_SCALE, 1, stream);
            launch_gemm(h, Asrc[2] + (size_t)l * D_DIM * R_LORA, tmp, T_LEN, R_LORA, D_DIM, 1.0f, 0, stream);
            launch_gemm(h, Wsrc[2] + (size_t)l * DD, vb, T_LEN, D_DIM, D_DIM, 1.0f, 0, stream);
            launch_gemm(tmp, Bsrc[2] + (size_t)l * R_LORA * D_DIM, vb, T_LEN, D_DIM, R_LORA, LORA_SCALE, 1, stream);
            attn_kernel<<<dim3(T_LEN, H_NUM), 256, 0, stream>>>(qb, kb, vb, cb);
            launch_gemm(cb, Asrc[3] + (size_t)l * D_DIM * R_LORA, tmp, T_LEN, R_LORA, D_DIM, 1.0f, 0, stream);
            launch_gemm(cb, Wsrc[3] + (size_t)l * DD, x, T_LEN, D_DIM, D_DIM, 1.0f, 1, stream);
            launch_gemm(tmp, Bsrc[3] + (size_t)l * R_LORA * D_DIM, x, T_LEN, D_DIM, R_LORA, LORA_SCALE, 1, stream);
            rms_kernel<<<T_LEN, 256, 0, stream>>>(x, ln2_l, h);
            launch_gemm(h, Asrc[4] + (size_t)l * D_DIM * R_LORA, tmp, T_LEN, R_LORA, D_DIM, 1.0f, 0, stream);
            launch_gemm(h, Wsrc[4] + (size_t)l * DF, gb, T_LEN, F_DIM, D_DIM, 1.0f, 0, stream);
            launch_gemm(tmp, Bsrc[4] + (size_t)l * R_LORA * F_DIM, gb, T_LEN, F_DIM, R_LORA, LORA_SCALE, 1, stream);
            launch_gemm(h, Asrc[5] + (size_t)l * D_DIM * R_LORA, tmp, T_LEN, R_LORA, D_DIM, 1.0f, 0, stream);
            launch_gemm(h, Wsrc[5] + (size_t)l * DF, ubf, T_LEN, F_DIM, D_DIM, 1.0f, 0, stream);
            launch_gemm(tmp, Bsrc[5] + (size_t)l * R_LORA * F_DIM, ubf, T_LEN, F_DIM, R_LORA, LORA_SCALE, 1, stream);
            silu_mul_kernel<<<(T_LEN * F_DIM + 255) / 256, 256, 0, stream>>>(gb, ubf, gb, T_LEN * F_DIM);
            launch_gemm(gb, Asrc[6] + (size_t)l * F_DIM * R_LORA, tmp, T_LEN, R_LORA, F_DIM, 1.0f, 0, stream);
            launch_gemm(gb, Wsrc[6] + (size_t)l * DF, x, T_LEN, D_DIM, F_DIM, 1.0f, 1, stream);
            launch_gemm(tmp, Bsrc[6] + (size_t)l * R_LORA * D_DIM, x, T_LEN, D_DIM, R_LORA, LORA_SCALE, 1, stream);
        }
        head_kernel<<<T_LEN, 256, 0, stream>>>(x, lnf, E, packed, soft);
    }
    argmax_kernel<<<(T_LEN + 255) / 256, 256, 0, stream>>>(soft, (int*)d_out);
}

// Round 4
// 1246.754 us; speedup vs baseline: 9.8805x; 1.0334x over previous
//
#include <hip/hip_runtime.h>
#include <hip/hip_bf16.h>

#define T_LEN 1024
#define D_DIM 1024
#define V_DIM 17
#define H_NUM 16
#define DH_DIM 64
#define F_DIM 4096
#define R_LORA 32
#define N_LAYERS 2
#define N_STEPS 2
#define MASK_ID 16
#define LORA_SCALE 2.0f

typedef __attribute__((ext_vector_type(8))) short bfx8;   // 8 bf16 in 4 VGPRs
typedef __attribute__((ext_vector_type(4))) float f32x4;

typedef unsigned short ushort_t;
typedef unsigned int uint_t;

#define AS1 __attribute__((address_space(1)))
#define AS3 __attribute__((address_space(3)))

__device__ __forceinline__ void gload16(const ushort_t* g, ushort_t* l) {
    __builtin_amdgcn_global_load_lds((const AS1 void*)(const void*)g,
                                     (AS3 void*)(void*)l, 16, 0, 0);
}

__device__ __forceinline__ ushort_t f2bf(float v) {
    __hip_bfloat16 h = __float2bfloat16(v);
    return __builtin_bit_cast(unsigned short, h);
}
__device__ __forceinline__ float bf2f(ushort_t u) {
    return __uint_as_float(((uint_t)u) << 16);
}
__device__ __forceinline__ void split4_store(float y0, float y1, float y2, float y3,
                                             ushort_t* __restrict__ hi, ushort_t* __restrict__ lo,
                                             size_t idx) {
    ushort_t h0 = f2bf(y0), h1 = f2bf(y1), h2 = f2bf(y2), h3 = f2bf(y3);
    ushort_t l0 = f2bf(y0 - bf2f(h0));
    ushort_t l1 = f2bf(y1 - bf2f(h1));
    ushort_t l2 = f2bf(y2 - bf2f(h2));
    ushort_t l3 = f2bf(y3 - bf2f(h3));
    uint2 hv, lv;
    hv.x = (uint_t)h0 | ((uint_t)h1 << 16);
    hv.y = (uint_t)h2 | ((uint_t)h3 << 16);
    lv.x = (uint_t)l0 | ((uint_t)l1 << 16);
    lv.y = (uint_t)l2 | ((uint_t)l3 << 16);
    *(uint2*)(hi + idx) = hv;
    *(uint2*)(lo + idx) = lv;
}

// ---------------- init soft ----------------
__global__ void init_soft_kernel(float* __restrict__ soft) {
    int idx = blockIdx.x * blockDim.x + threadIdx.x;
    if (idx < T_LEN * V_DIM) {
        soft[idx] = ((idx % V_DIM) == MASK_ID) ? 1.0f : 0.0f;
    }
}

// ---------------- embed: x = soft @ E ----------------
__global__ __launch_bounds__(256) void embed_kernel(const float* __restrict__ soft,
                                                    const float* __restrict__ E,
                                                    float* __restrict__ x) {
    int t = blockIdx.x;
    __shared__ float srow[V_DIM];
    if (threadIdx.x < V_DIM) srow[threadIdx.x] = soft[t * V_DIM + threadIdx.x];
    __syncthreads();
    for (int d = threadIdx.x; d < D_DIM; d += 256) {
        float acc = 0.f;
        #pragma unroll
        for (int v = 0; v < V_DIM; v++) acc += srow[v] * E[v * D_DIM + d];
        x[(size_t)t * D_DIM + d] = acc;
    }
}

// ---------------- fold (batched over layers via z): out^T = split(W + 2*A@B) ----------------
__global__ __launch_bounds__(256) void fold_kernel(
    const float* __restrict__ W,   // [L,K,N]
    const float* __restrict__ A,   // [L,K,R]
    const float* __restrict__ Bm,  // [L,R,N]
    ushort_t* __restrict__ oHi,    // [L,N,K]
    ushort_t* __restrict__ oLo,
    int K, int N)
{
    const int l = blockIdx.z;
    W   += (size_t)l * K * N;
    A   += (size_t)l * K * R_LORA;
    Bm  += (size_t)l * R_LORA * N;
    oHi += (size_t)l * K * N;
    oLo += (size_t)l * K * N;
    __shared__ uint_t tile[64][65];
    const int tid = threadIdx.x;
    const int n0 = blockIdx.x * 64, k0 = blockIdx.y * 64;
    {
        const int nl = tid & 63, kq = tid >> 6;
        float breg[R_LORA];
        #pragma unroll
        for (int r = 0; r < R_LORA; r++) breg[r] = Bm[(size_t)r * N + n0 + nl];
        for (int i = 0; i < 16; i++) {
            const int kl = kq * 16 + i;
            const size_t kgl = (size_t)(k0 + kl);
            const float* arow = A + kgl * R_LORA;
            float acc = 0.f;
            #pragma unroll
            for (int r = 0; r < R_LORA; r++) acc = fmaf(arow[r], breg[r], acc);
            float val = W[kgl * N + n0 + nl] + LORA_SCALE * acc;
            ushort_t h = f2bf(val);
            ushort_t l2 = f2bf(val - bf2f(h));
            tile[kl][nl] = ((uint_t)h << 16) | (uint_t)l2;
        }
    }
    __syncthreads();
    {
        const int kl = tid & 63, nb = tid >> 6;
        for (int i = 0; i < 16; i++) {
            const int nl = nb * 16 + i;
            uint_t pk = tile[kl][nl];
            size_t idx = (size_t)(n0 + nl) * K + k0 + kl;
            oHi[idx] = (ushort_t)(pk >> 16);
            oLo[idx] = (ushort_t)(pk & 0xffffu);
        }
    }
}

// ---------------- rms + bf16-split ----------------
__global__ __launch_bounds__(256) void rms_split_kernel(
    const float* __restrict__ x, const float* __restrict__ w,
    ushort_t* __restrict__ hi, ushort_t* __restrict__ lo)
{
    const int t = blockIdx.x, tid = threadIdx.x;
    const float* xr = x + (size_t)t * D_DIM;
    float4 xv = *(const float4*)(xr + tid * 4);
    float ss = xv.x * xv.x + xv.y * xv.y + xv.z * xv.z + xv.w * xv.w;
    __shared__ float red[4];
    const int lane = tid & 63, wv = tid >> 6;
    #pragma unroll
    for (int off = 32; off > 0; off >>= 1) ss += __shfl_xor(ss, off);
    if (lane == 0) red[wv] = ss;
    __syncthreads();
    ss = red[0] + red[1] + red[2] + red[3];
    const float r = 1.0f / sqrtf(ss * (1.0f / D_DIM) + 1e-6f);
    const float4 wv4 = *(const float4*)(w + tid * 4);
    size_t base = (size_t)t * D_DIM + tid * 4;
    split4_store(xv.x * r * wv4.x, xv.y * r * wv4.y, xv.z * r * wv4.z, xv.w * r * wv4.w,
                 hi, lo, base);
}

// ---------------- 128x128 MFMA split-bf16 GEMM, m97-structure ----------------
// A=[M,K] hi/lo (activations), B=[N,K] hi/lo (folded weights, K-contiguous).
// global_load_lds staging, XOR-swizzled source (rule #21), 48 MFMA / barrier-pair / wave.
struct GemmJob {
    const ushort_t* Bh;
    const ushort_t* Bl;
    float* Cf;        // if non-null: f32 plain store
    ushort_t* Ch;     // else split store
    ushort_t* Cl;
    int k0, k1;
};

__global__ __launch_bounds__(256) void gemm128_kernel(
    const ushort_t* __restrict__ Ahi, const ushort_t* __restrict__ Alo,
    int K, int N, GemmJob j0, GemmJob j1, GemmJob j2, GemmJob j3)
{
    GemmJob jb = (blockIdx.z == 0) ? j0 : (blockIdx.z == 1) ? j1 : (blockIdx.z == 2) ? j2 : j3;
    __shared__ ushort_t Ash[128][32];
    __shared__ ushort_t Asl[128][32];
    __shared__ ushort_t Bsh[128][32];
    __shared__ ushort_t Bsl[128][32];

    const int tid = threadIdx.x, lane = tid & 63, w = tid >> 6;
    const int l15 = lane & 15, lg = lane >> 4;
    const int m0 = blockIdx.y * 128, n0 = blockIdx.x * 128;
    const int wm = (w >> 1) * 64, wn = (w & 1) * 64;

    // staging geometry: wave w fills rows [w*32, w*32+32) of each tile.
    // lane -> (row = r0 + (lane>>2) [+16 for 2nd inst], colslot = lane&3)
    // global colslot pre-swizzled by row&3 so that swizzled reads see G[row][lg].
    const int r0 = w * 32;
    const int rsub = lane >> 2;
    const int cs = lane & 3;
    const int csl = (cs ^ (rsub & 3)) * 8;          // pre-swizzled source col (shorts)
    const int rsl = (lg ^ (l15 & 3)) * 8;           // swizzled read col (shorts)

    f32x4 acc[4][4];
    #pragma unroll
    for (int i = 0; i < 4; i++)
        #pragma unroll
        for (int j = 0; j < 4; j++) acc[i][j] = f32x4{0.f, 0.f, 0.f, 0.f};

    const size_t rowA = (size_t)(m0 + r0 + rsub) * K;
    const size_t rowB = (size_t)(n0 + r0 + rsub) * K;
    const size_t rstep = (size_t)16 * K;

    for (int kk = jb.k0; kk < jb.k1; kk += 32) {
        {
            const ushort_t* a0 = Ahi + rowA + kk + csl;
            const ushort_t* a1 = Alo + rowA + kk + csl;
            const ushort_t* b0 = jb.Bh + rowB + kk + csl;
            const ushort_t* b1 = jb.Bl + rowB + kk + csl;
            gload16(a0,         &Ash[r0][0]);
            gload16(a0 + rstep, &Ash[r0 + 16][0]);
            gload16(a1,         &Asl[r0][0]);
            gload16(a1 + rstep, &Asl[r0 + 16][0]);
            gload16(b0,         &Bsh[r0][0]);
            gload16(b0 + rstep, &Bsh[r0 + 16][0]);
            gload16(b1,         &Bsl[r0][0]);
            gload16(b1 + rstep, &Bsl[r0 + 16][0]);
        }
        __syncthreads();   // drains vmcnt: staged data visible to all waves
        bfx8 bh[4], bl[4];
        #pragma unroll
        for (int ni = 0; ni < 4; ni++) {
            bh[ni] = *(const bfx8*)&Bsh[wn + ni * 16 + l15][rsl];
            bl[ni] = *(const bfx8*)&Bsl[wn + ni * 16 + l15][rsl];
        }
        #pragma unroll
        for (int mi = 0; mi < 4; mi++) {
            bfx8 ah = *(const bfx8*)&Ash[wm + mi * 16 + l15][rsl];
            bfx8 al = *(const bfx8*)&Asl[wm + mi * 16 + l15][rsl];
            #pragma unroll
            for (int ni = 0; ni < 4; ni++) {
                acc[mi][ni] = __builtin_amdgcn_mfma_f32_16x16x32_bf16(ah, bh[ni], acc[mi][ni], 0, 0, 0);
                acc[mi][ni] = __builtin_amdgcn_mfma_f32_16x16x32_bf16(ah, bl[ni], acc[mi][ni], 0, 0, 0);
                acc[mi][ni] = __builtin_amdgcn_mfma_f32_16x16x32_bf16(al, bh[ni], acc[mi][ni], 0, 0, 0);
            }
        }
        __syncthreads();   // all reads done before next stage overwrites
    }

    if (jb.Cf) {
        #pragma unroll
        for (int mi = 0; mi < 4; mi++)
            #pragma unroll
            for (int ni = 0; ni < 4; ni++) {
                int col = n0 + wn + ni * 16 + l15;
                #pragma unroll
                for (int i = 0; i < 4; i++) {
                    int row = m0 + wm + mi * 16 + lg * 4 + i;
                    jb.Cf[(size_t)row * N + col] = acc[mi][ni][i];
                }
            }
    } else {
        #pragma unroll
        for (int mi = 0; mi < 4; mi++)
            #pragma unroll
            for (int ni = 0; ni < 4; ni++) {
                int col = n0 + wn + ni * 16 + l15;
                #pragma unroll
                for (int i = 0; i < 4; i++) {
                    int row = m0 + wm + mi * 16 + lg * 4 + i;
                    size_t idx = (size_t)row * N + col;
                    float v = acc[mi][ni][i];
                    ushort_t h = f2bf(v);
                    jb.Ch[idx] = h;
                    jb.Cl[idx] = f2bf(v - bf2f(h));
                }
            }
    }
}

// ---------------- add2 / add4: x += sum(partials) ----------------
__global__ void add2_kernel(float* __restrict__ x, const float* __restrict__ p0,
                            const float* __restrict__ p1, int n4) {
    int i = blockIdx.x * blockDim.x + threadIdx.x;
    if (i < n4) {
        float4 xv = *(const float4*)(x + (size_t)i * 4);
        float4 a = *(const float4*)(p0 + (size_t)i * 4);
        float4 b = *(const float4*)(p1 + (size_t)i * 4);
        xv.x += a.x + b.x; xv.y += a.y + b.y; xv.z += a.z + b.z; xv.w += a.w + b.w;
        *(float4*)(x + (size_t)i * 4) = xv;
    }
}
__global__ void add4_kernel(float* __restrict__ x, const float* __restrict__ p0,
                            const float* __restrict__ p1, const float* __restrict__ p2,
                            const float* __restrict__ p3, int n4) {
    int i = blockIdx.x * blockDim.x + threadIdx.x;
    if (i < n4) {
        float4 xv = *(const float4*)(x + (size_t)i * 4);
        float4 a = *(const float4*)(p0 + (size_t)i * 4);
        float4 b = *(const float4*)(p1 + (size_t)i * 4);
        float4 c = *(const float4*)(p2 + (size_t)i * 4);
        float4 d = *(const float4*)(p3 + (size_t)i * 4);
        xv.x += a.x + b.x + c.x + d.x;
        xv.y += a.y + b.y + c.y + d.y;
        xv.z += a.z + b.z + c.z + d.z;
        xv.w += a.w + b.w + c.w + d.w;
        *(float4*)(x + (size_t)i * 4) = xv;
    }
}

// ---------------- MFMA flash attention ----------------
#define KS_PAD 72
#define P_PAD 72
__global__ __launch_bounds__(256, 1) void attn_mfma_kernel(
    const ushort_t* __restrict__ qh, const ushort_t* __restrict__ ql,
    const ushort_t* __restrict__ kh, const ushort_t* __restrict__ kl,
    const ushort_t* __restrict__ vh, const ushort_t* __restrict__ vl,
    ushort_t* __restrict__ chi, ushort_t* __restrict__ clo)
{
    __shared__ ushort_t Ksh[64][KS_PAD];
    __shared__ ushort_t Ksl[64][KS_PAD];
    __shared__ ushort_t VTh[64][KS_PAD];   // transposed V: [d][k]
    __shared__ ushort_t VTl[64][KS_PAD];
    __shared__ ushort_t Ph[4][16][P_PAD];  // per-wave P strips
    __shared__ ushort_t Pl[4][16][P_PAD];

    const int qt = blockIdx.x, hh = blockIdx.y;
    const int tid = threadIdx.x, w = tid >> 6, lane = tid & 63;
    const int l15 = lane & 15, lg = lane >> 4;
    const int q0 = qt * 64;
    const int hcol = hh * DH_DIM;

    bfx8 qa_h[2], qa_l[2];
    {
        size_t qrow = (size_t)(q0 + w * 16 + l15) * D_DIM + hcol;
        #pragma unroll
        for (int ks = 0; ks < 2; ks++) {
            qa_h[ks] = *(const bfx8*)(qh + qrow + ks * 32 + lg * 8);
            qa_l[ks] = *(const bfx8*)(ql + qrow + ks * 32 + lg * 8);
        }
    }

    f32x4 o[4];
    #pragma unroll
    for (int ni = 0; ni < 4; ni++) o[ni] = f32x4{0.f, 0.f, 0.f, 0.f};
    float mrun[4], lrun[4];
    #pragma unroll
    for (int i = 0; i < 4; i++) { mrun[i] = -3.0e38f; lrun[i] = 0.f; }

    const int srow = tid >> 2;
    const int sseg = (tid & 3) * 16;
    const int vp = tid & 31;
    const int vd0 = (tid >> 5) * 8;

    for (int kt = 0; kt <= qt; kt++) {
        __syncthreads();
        {
            size_t src = (size_t)(kt * 64 + srow) * D_DIM + hcol + sseg;
            *(uint4*)&Ksh[srow][sseg]     = *(const uint4*)(kh + src);
            *(uint4*)&Ksh[srow][sseg + 8] = *(const uint4*)(kh + src + 8);
            *(uint4*)&Ksl[srow][sseg]     = *(const uint4*)(kl + src);
            *(uint4*)&Ksl[srow][sseg + 8] = *(const uint4*)(kl + src + 8);
        }
        {
            size_t s0 = (size_t)(kt * 64 + 2 * vp) * D_DIM + hcol + vd0;
            uint4 h0 = *(const uint4*)(vh + s0);
            uint4 h1 = *(const uint4*)(vh + s0 + D_DIM);
            uint4 l0 = *(const uint4*)(vl + s0);
            uint4 l1 = *(const uint4*)(vl + s0 + D_DIM);
            const ushort_t* a = (const ushort_t*)&h0;
            const ushort_t* b = (const ushort_t*)&h1;
            const ushort_t* c = (const ushort_t*)&l0;
            const ushort_t* d = (const ushort_t*)&l1;
            #pragma unroll
            for (int j = 0; j < 8; j++) {
                *(uint_t*)&VTh[vd0 + j][2 * vp] = (uint_t)a[j] | ((uint_t)b[j] << 16);
                *(uint_t*)&VTl[vd0 + j][2 * vp] = (uint_t)c[j] | ((uint_t)d[j] << 16);
            }
        }
        __syncthreads();

        f32x4 s[4];
        #pragma unroll
        for (int ni = 0; ni < 4; ni++) s[ni] = f32x4{0.f, 0.f, 0.f, 0.f};
        #pragma unroll
        for (int ks = 0; ks < 2; ks++) {
            #pragma unroll
            for (int ni = 0; ni < 4; ni++) {
                bfx8 bh = *(const bfx8*)&Ksh[ni * 16 + l15][ks * 32 + lg * 8];
                bfx8 bl = *(const bfx8*)&Ksl[ni * 16 + l15][ks * 32 + lg * 8];
                s[ni] = __builtin_amdgcn_mfma_f32_16x16x32_bf16(qa_h[ks], bh, s[ni], 0, 0, 0);
                s[ni] = __builtin_amdgcn_mfma_f32_16x16x32_bf16(qa_h[ks], bl, s[ni], 0, 0, 0);
                s[ni] = __builtin_amdgcn_mfma_f32_16x16x32_bf16(qa_l[ks], bh, s[ni], 0, 0, 0);
            }
        }

        const int kbase = kt * 64;
        float rmax[4];
        #pragma unroll
        for (int i = 0; i < 4; i++) rmax[i] = -3.0e38f;
        #pragma unroll
        for (int ni = 0; ni < 4; ni++) {
            int kc = kbase + ni * 16 + l15;
            #pragma unroll
            for (int i = 0; i < 4; i++) {
                int qrow = q0 + w * 16 + lg * 4 + i;
                float v = s[ni][i] * 0.125f;
                v = (kc <= qrow) ? v : -3.0e38f;
                s[ni][i] = v;
                rmax[i] = fmaxf(rmax[i], v);
            }
        }
        #pragma unroll
        for (int off = 1; off < 16; off <<= 1) {
            #pragma unroll
            for (int i = 0; i < 4; i++) rmax[i] = fmaxf(rmax[i], __shfl_xor(rmax[i], off));
        }
        float psum[4];
        #pragma unroll
        for (int i = 0; i < 4; i++) {
            float nm = fmaxf(mrun[i], rmax[i]);
            float sc = __expf(mrun[i] - nm);
            lrun[i] *= sc;
            #pragma unroll
            for (int ni = 0; ni < 4; ni++) o[ni][i] *= sc;
            mrun[i] = nm;
            psum[i] = 0.f;
        }
        #pragma unroll
        for (int ni = 0; ni < 4; ni++) {
            #pragma unroll
            for (int i = 0; i < 4; i++) {
                float e = __expf(s[ni][i] - mrun[i]);
                s[ni][i] = e;
                psum[i] += e;
            }
        }
        #pragma unroll
        for (int off = 1; off < 16; off <<= 1) {
            #pragma unroll
            for (int i = 0; i < 4; i++) psum[i] += __shfl_xor(psum[i], off);
        }
        #pragma unroll
        for (int i = 0; i < 4; i++) lrun[i] += psum[i];

        #pragma unroll
        for (int ni = 0; ni < 4; ni++) {
            #pragma unroll
            for (int i = 0; i < 4; i++) {
                float e = s[ni][i];
                ushort_t hp = f2bf(e);
                Ph[w][lg * 4 + i][ni * 16 + l15] = hp;
                Pl[w][lg * 4 + i][ni * 16 + l15] = f2bf(e - bf2f(hp));
            }
        }
        #pragma unroll
        for (int ks = 0; ks < 2; ks++) {
            bfx8 ah = *(const bfx8*)&Ph[w][l15][ks * 32 + lg * 8];
            bfx8 al = *(const bfx8*)&Pl[w][l15][ks * 32 + lg * 8];
            #pragma unroll
            for (int ni = 0; ni < 4; ni++) {
                bfx8 bh = *(const bfx8*)&VTh[ni * 16 + l15][ks * 32 + lg * 8];
                bfx8 bl = *(const bfx8*)&VTl[ni * 16 + l15][ks * 32 + lg * 8];
                o[ni] = __builtin_amdgcn_mfma_f32_16x16x32_bf16(ah, bh, o[ni], 0, 0, 0);
                o[ni] = __builtin_amdgcn_mfma_f32_16x16x32_bf16(ah, bl, o[ni], 0, 0, 0);
                o[ni] = __builtin_amdgcn_mfma_f32_16x16x32_bf16(al, bh, o[ni], 0, 0, 0);
            }
        }
    }

    #pragma unroll
    for (int i = 0; i < 4; i++) {
        float inv = 1.0f / lrun[i];
        #pragma unroll
        for (int ni = 0; ni < 4; ni++) o[ni][i] *= inv;
    }
    #pragma unroll
    for (int ni = 0; ni < 4; ni++) {
        int col = hcol + ni * 16 + l15;
        #pragma unroll
        for (int i = 0; i < 4; i++) {
            int row = q0 + w * 16 + lg * 4 + i;
            size_t idx = (size_t)row * D_DIM + col;
            float v = o[ni][i];
            ushort_t hp = f2bf(v);
            chi[idx] = hp;
            clo[idx] = f2bf(v - bf2f(hp));
        }
    }
}

// ---------------- silu(g)*u -> split ----------------
__global__ void silu_split_kernel(const float* __restrict__ g, const float* __restrict__ u,
                                  ushort_t* __restrict__ hi, ushort_t* __restrict__ lo, int n4) {
    int i = blockIdx.x * blockDim.x + threadIdx.x;
    if (i < n4) {
        float4 gv = *(const float4*)(g + (size_t)i * 4);
        float4 uv = *(const float4*)(u + (size_t)i * 4);
        float y0 = gv.x / (1.f + expf(-gv.x)) * uv.x;
        float y1 = gv.y / (1.f + expf(-gv.y)) * uv.y;
        float y2 = gv.z / (1.f + expf(-gv.z)) * uv.z;
        float y3 = gv.w / (1.f + expf(-gv.w)) * uv.w;
        split4_store(y0, y1, y2, y3, hi, lo, (size_t)i * 4);
    }
}

// ---------------- head ----------------
__global__ __launch_bounds__(256) void head_kernel(const float* __restrict__ x,
                                                   const float* __restrict__ lnf,
                                                   const float* __restrict__ E,
                                                   const int* __restrict__ tok,
                                                   float* __restrict__ soft) {
    int t = blockIdx.x;
    int tid = threadIdx.x;
    __shared__ float y[D_DIM];
    __shared__ float red[4];
    __shared__ float logits[V_DIM];
    const float* xr = x + (size_t)t * D_DIM;
    float ss = 0.f;
    for (int d = tid; d < D_DIM; d += 256) { float v = xr[d]; ss += v * v; }
    int lane = tid & 63, wave = tid >> 6;
    for (int off = 32; off > 0; off >>= 1) ss += __shfl_xor(ss, off);
    if (lane == 0) red[wave] = ss;
    __syncthreads();
    ss = red[0] + red[1] + red[2] + red[3];
    float r = 1.0f / sqrtf(ss * (1.0f / D_DIM) + 1e-6f);
    for (int d = tid; d < D_DIM; d += 256) y[d] = xr[d] * r * lnf[d];
    __syncthreads();
    for (int vv = wave; vv < V_DIM; vv += 4) {
        float p = 0.f;
        for (int d = lane; d < D_DIM; d += 64) p += y[d] * E[vv * D_DIM + d];
        for (int off = 32; off > 0; off >>= 1) p += __shfl_xor(p, off);
        if (lane == 0) logits[vv] = p;
    }
    __syncthreads();
    if (tid == 0) {
        int tk = tok[t];
        if (tk != MASK_ID) {
            for (int vv = 0; vv < V_DIM; vv++) soft[t * V_DIM + vv] = (vv == tk) ? 1.f : 0.f;
        } else {
            float mx = -1e30f;
            for (int vv = 0; vv < V_DIM; vv++) mx = fmaxf(mx, logits[vv]);
            float sm = 0.f;
            float e[V_DIM];
            for (int vv = 0; vv < V_DIM; vv++) { e[vv] = expf(logits[vv] - mx); sm += e[vv]; }
            float invs = 1.0f / sm;
            for (int vv = 0; vv < V_DIM; vv++) soft[t * V_DIM + vv] = e[vv] * invs;
        }
    }
}

// ---------------- argmax ----------------
__global__ void argmax_kernel(const float* __restrict__ soft, int* __restrict__ out) {
    int t = blockIdx.x * blockDim.x + threadIdx.x;
    if (t < T_LEN) {
        const float* s = soft + t * V_DIM;
        int best = 0;
        float bv = s[0];
        #pragma unroll
        for (int vv = 1; vv < V_DIM; vv++) {
            float v = s[vv];
            if (v > bv) { bv = v; best = vv; }
        }
        out[t] = best;
    }
}

// ================= fallback kernels (fp32, if ws too small) =================
__global__ __launch_bounds__(256) void rms_kernel(const float* __restrict__ x,
                                                  const float* __restrict__ w,
                                                  float* __restrict__ out) {
    int t = blockIdx.x;
    const float* xr = x + (size_t)t * D_DIM;
    float ss = 0.f;
    for (int d = threadIdx.x; d < D_DIM; d += 256) { float v = xr[d]; ss += v * v; }
    __shared__ float red[4];
    int lane = threadIdx.x & 63, wave = threadIdx.x >> 6;
    for (int off = 32; off > 0; off >>= 1) ss += __shfl_xor(ss, off);
    if (lane == 0) red[wave] = ss;
    __syncthreads();
    ss = red[0] + red[1] + red[2] + red[3];
    float r = 1.0f / sqrtf(ss * (1.0f / D_DIM) + 1e-6f);
    for (int d = threadIdx.x; d < D_DIM; d += 256) out[(size_t)t * D_DIM + d] = xr[d] * r * w[d];
}

__global__ __launch_bounds__(256) void gemm_kernel(const float* __restrict__ A,
                                                   const float* __restrict__ B,
                                                   float* __restrict__ C,
                                                   int M, int N, int K,
                                                   float alpha, int accumulate) {
    const int BM = 64, BN = 64, BK = 16;
    __shared__ float As[BK][BM];
    __shared__ float Bsh[BK][BN];
    int tid = threadIdx.x;
    int tx = tid % 16, ty = tid / 16;
    int row0 = blockIdx.y * BM, col0 = blockIdx.x * BN;
    float acc[4][4] = {};
    for (int k0 = 0; k0 < K; k0 += BK) {
        #pragma unroll
        for (int i = 0; i < 4; i++) {
            int e = tid * 4 + i;
            int m = e / BK, kk = e % BK;
            int gr = row0 + m, gk = k0 + kk;
            As[kk][m] = (gr < M && gk < K) ? A[(size_t)gr * K + gk] : 0.f;
        }
        #pragma unroll
        for (int i = 0; i < 4; i++) {
            int e = tid * 4 + i;
            int kk = e / BN, n = e % BN;
            int gk = k0 + kk, gc = col0 + n;
            Bsh[kk][n] = (gk < K && gc < N) ? B[(size_t)gk * N + gc] : 0.f;
        }
        __syncthreads();
        #pragma unroll
        for (int kk = 0; kk < BK; kk++) {
            float a[4], b[4];
            #pragma unroll
            for (int i = 0; i < 4; i++) a[i] = As[kk][ty * 4 + i];
            #pragma unroll
            for (int j = 0; j < 4; j++) b[j] = Bsh[kk][tx * 4 + j];
            #pragma unroll
            for (int i = 0; i < 4; i++)
                #pragma unroll
                for (int j = 0; j < 4; j++)
                    acc[i][j] += a[i] * b[j];
        }
        __syncthreads();
    }
    #pragma unroll
    for (int i = 0; i < 4; i++) {
        int r = row0 + ty * 4 + i;
        if (r >= M) continue;
        #pragma unroll
        for (int j = 0; j < 4; j++) {
            int c = col0 + tx * 4 + j;
            if (c >= N) continue;
            size_t idx = (size_t)r * N + c;
            float val = alpha * acc[i][j];
            if (accumulate) val += C[idx];
            C[idx] = val;
        }
    }
}

__global__ __launch_bounds__(256) void attn_kernel(const float* __restrict__ q,
                                                   const float* __restrict__ k,
                                                   const float* __restrict__ v,
                                                   float* __restrict__ ctx) {
    int qi = blockIdx.x;
    int hh = blockIdx.y;
    __shared__ float sc[T_LEN];
    __shared__ float qrow[DH_DIM];
    __shared__ float red[8];
    __shared__ float part[4][DH_DIM];
    int tid = threadIdx.x;
    int lane = tid & 63, wave = tid >> 6;
    const float* qp = q + (size_t)qi * D_DIM + hh * DH_DIM;
    if (tid < DH_DIM) qrow[tid] = qp[tid];
    __syncthreads();
    const float scale = 0.125f;
    for (int j = wave; j <= qi; j += 4) {
        const float* kp = k + (size_t)j * D_DIM + hh * DH_DIM;
        float p = qrow[lane] * kp[lane];
        for (int off = 32; off > 0; off >>= 1) p += __shfl_xor(p, off);
        if (lane == 0) sc[j] = p * scale;
    }
    __syncthreads();
    int n = qi + 1;
    float m = -1e30f;
    for (int j = tid; j < n; j += 256) m = fmaxf(m, sc[j]);
    for (int off = 32; off > 0; off >>= 1) m = fmaxf(m, __shfl_xor(m, off));
    if (lane == 0) red[wave] = m;
    __syncthreads();
    m = fmaxf(fmaxf(red[0], red[1]), fmaxf(red[2], red[3]));
    float s = 0.f;
    for (int j = tid; j < n; j += 256) { float e = expf(sc[j] - m); sc[j] = e; s += e; }
    for (int off = 32; off > 0; off >>= 1) s += __shfl_xor(s, off);
    if (lane == 0) red[4 + wave] = s;
    __syncthreads();
    s = red[4] + red[5] + red[6] + red[7];
    float inv = 1.0f / s;
    float acc = 0.f;
    for (int j = wave; j < n; j += 4) {
        acc += sc[j] * v[(size_t)j * D_DIM + hh * DH_DIM + lane];
    }
    part[wave][lane] = acc;
    __syncthreads();
    if (tid < DH_DIM) {
        float r = (part[0][tid] + part[1][tid] + part[2][tid] + part[3][tid]) * inv;
        ctx[(size_t)qi * D_DIM + hh * DH_DIM + tid] = r;
    }
}

__global__ void silu_mul_kernel(const float* __restrict__ g, const float* __restrict__ u,
                                float* __restrict__ out, int nelem) {
    int i = blockIdx.x * blockDim.x + threadIdx.x;
    if (i < nelem) {
        float gv = g[i];
        float sg = 1.0f / (1.0f + expf(-gv));
        out[i] = gv * sg * u[i];
    }
}

static inline void launch_gemm(const float* A, const float* B, float* C,
                               int M, int N, int K, float alpha, int accumulate,
                               hipStream_t stream) {
    dim3 grid((N + 63) / 64, (M + 63) / 64);
    gemm_kernel<<<grid, 256, 0, stream>>>(A, B, C, M, N, K, alpha, accumulate);
}

// =====================================================================================
extern "C" void kernel_launch(void* const* d_in, const int* in_sizes, int n_in,
                              void* d_out, int out_size, void* d_ws, size_t ws_size,
                              hipStream_t stream) {
    const int* packed = (const int*)d_in[0];
    const float* E  = (const float*)d_in[6];
    const float* Wsrc[7] = {(const float*)d_in[7],  (const float*)d_in[10], (const float*)d_in[13],
                            (const float*)d_in[16], (const float*)d_in[19], (const float*)d_in[22],
                            (const float*)d_in[25]};
    const float* Asrc[7] = {(const float*)d_in[8],  (const float*)d_in[11], (const float*)d_in[14],
                            (const float*)d_in[17], (const float*)d_in[20], (const float*)d_in[23],
                            (const float*)d_in[26]};
    const float* Bsrc[7] = {(const float*)d_in[9],  (const float*)d_in[12], (const float*)d_in[15],
                            (const float*)d_in[18], (const float*)d_in[21], (const float*)d_in[24],
                            (const float*)d_in[27]};
    const float* ln1 = (const float*)d_in[28];
    const float* ln2 = (const float*)d_in[29];
    const float* lnf = (const float*)d_in[30];

    const size_t DD = (size_t)D_DIM * D_DIM;     // 1M
    const size_t DF = (size_t)D_DIM * F_DIM;     // 4M
    const size_t wsizes[7] = {DD, DD, DD, DD, DF, DF, DF};
    const int Kdim[7] = {D_DIM, D_DIM, D_DIM, D_DIM, D_DIM, D_DIM, F_DIM};
    const int Ndim[7] = {D_DIM, D_DIM, D_DIM, D_DIM, F_DIM, F_DIM, D_DIM};

    // fast-path workspace requirement
    size_t u16_elems = 0;
    for (int p = 0; p < 7; p++) u16_elems += 2ull * N_LAYERS * wsizes[p];  // folded hi/lo
    u16_elems += 2ull * DD;            // h hi/lo
    u16_elems += 2ull * DD;            // ctx hi/lo
    u16_elems += 2ull * DF;            // ff hi/lo
    u16_elems += 6ull * DD;            // q,k,v hi/lo
    size_t f32_elems = (size_t)T_LEN * V_DIM + DD /*x*/ + 2 * DF /*g,u (p0..3 alias)*/;
    size_t need = u16_elems * 2 + f32_elems * 4 + 256;

    if (ws_size >= need) {
        // -------- fast path --------
        ushort_t* ub = (ushort_t*)d_ws;
        size_t uo = 0;
        ushort_t *Whi[7], *Wlo[7];
        for (int p = 0; p < 7; p++) {
            Whi[p] = ub + uo; uo += (size_t)N_LAYERS * wsizes[p];
            Wlo[p] = ub + uo; uo += (size_t)N_LAYERS * wsizes[p];
        }
        ushort_t* h_hi = ub + uo; uo += DD;
        ushort_t* h_lo = ub + uo; uo += DD;
        ushort_t* c_hi = ub + uo; uo += DD;
        ushort_t* c_lo = ub + uo; uo += DD;
        ushort_t* f_hi = ub + uo; uo += DF;
        ushort_t* f_lo = ub + uo; uo += DF;
        ushort_t* qbh = ub + uo; uo += DD;
        ushort_t* qbl = ub + uo; uo += DD;
        ushort_t* kbh = ub + uo; uo += DD;
        ushort_t* kbl = ub + uo; uo += DD;
        ushort_t* vbh = ub + uo; uo += DD;
        ushort_t* vbl = ub + uo; uo += DD;
        float* fb = (float*)(ub + uo);
        size_t fo = 0;
        float* soft = fb + fo; fo += (size_t)T_LEN * V_DIM;
        float* x    = fb + fo; fo += DD;
        float* gbuf = fb + fo; fo += DF;
        float* ubuf = fb + fo; fo += DF;
        // split-K partial buffers alias gbuf (different live ranges)
        float* p0 = gbuf;
        float* p1 = gbuf + DD;
        float* p2 = gbuf + 2 * DD;
        float* p3 = gbuf + 3 * DD;

        // fold weights (batched over layers)
        for (int p = 0; p < 7; p++) {
            dim3 grid(Ndim[p] / 64, Kdim[p] / 64, N_LAYERS);
            fold_kernel<<<grid, 256, 0, stream>>>(Wsrc[p], Asrc[p], Bsrc[p],
                                                  Whi[p], Wlo[p], Kdim[p], Ndim[p]);
        }

        init_soft_kernel<<<(T_LEN * V_DIM + 255) / 256, 256, 0, stream>>>(soft);

        const int n4 = (int)(DD / 4);
        for (int step = 0; step < N_STEPS; step++) {
            embed_kernel<<<T_LEN, 256, 0, stream>>>(soft, E, x);
            for (int l = 0; l < N_LAYERS; l++) {
                rms_split_kernel<<<T_LEN, 256, 0, stream>>>(x, ln1 + (size_t)l * D_DIM, h_hi, h_lo);
                {   // fused QKV: 3 jobs, 128^2 tiles
                    GemmJob jq = {Whi[0] + l * DD, Wlo[0] + l * DD, nullptr, qbh, qbl, 0, D_DIM};
                    GemmJob jk = {Whi[1] + l * DD, Wlo[1] + l * DD, nullptr, kbh, kbl, 0, D_DIM};
                    GemmJob jv = {Whi[2] + l * DD, Wlo[2] + l * DD, nullptr, vbh, vbl, 0, D_DIM};
                    gemm128_kernel<<<dim3(8, 8, 3), 256, 0, stream>>>(
                        h_hi, h_lo, D_DIM, D_DIM, jq, jk, jv, jq);
                }
                attn_mfma_kernel<<<dim3(T_LEN / 64, H_NUM), 256, 0, stream>>>(
                    qbh, qbl, kbh, kbl, vbh, vbl, c_hi, c_lo);
                {   // o-proj split-K x4
                    const ushort_t* bh = Whi[3] + l * DD;
                    const ushort_t* bl = Wlo[3] + l * DD;
                    GemmJob ja = {bh, bl, p0, nullptr, nullptr, 0, 256};
                    GemmJob jb = {bh, bl, p1, nullptr, nullptr, 256, 512};
                    GemmJob jc = {bh, bl, p2, nullptr, nullptr, 512, 768};
                    GemmJob jd = {bh, bl, p3, nullptr, nullptr, 768, 1024};
                    gemm128_kernel<<<dim3(8, 8, 4), 256, 0, stream>>>(
                        c_hi, c_lo, D_DIM, D_DIM, ja, jb, jc, jd);
                    add4_kernel<<<(n4 + 255) / 256, 256, 0, stream>>>(x, p0, p1, p2, p3, n4);
                }
                rms_split_kernel<<<T_LEN, 256, 0, stream>>>(x, ln2 + (size_t)l * D_DIM, h_hi, h_lo);
                {   // fused G,U
                    GemmJob jg = {Whi[4] + l * DF, Wlo[4] + l * DF, gbuf, nullptr, nullptr, 0, D_DIM};
                    GemmJob ju = {Whi[5] + l * DF, Wlo[5] + l * DF, ubuf, nullptr, nullptr, 0, D_DIM};
                    gemm128_kernel<<<dim3(32, 8, 2), 256, 0, stream>>>(
                        h_hi, h_lo, D_DIM, F_DIM, jg, ju, jg, jg);
                }
                silu_split_kernel<<<(T_LEN * F_DIM / 4 + 255) / 256, 256, 0, stream>>>(
                    gbuf, ubuf, f_hi, f_lo, T_LEN * F_DIM / 4);
                {   // d-proj split-K x4 (K=4096)
                    const ushort_t* bh = Whi[6] + l * DF;
                    const ushort_t* bl = Wlo[6] + l * DF;
                    GemmJob ja = {bh, bl, p0, nullptr, nullptr, 0, 1024};
                    GemmJob jb = {bh, bl, p1, nullptr, nullptr, 1024, 2048};
                    GemmJob jc = {bh, bl, p2, nullptr, nullptr, 2048, 3072};
                    GemmJob jd = {bh, bl, p3, nullptr, nullptr, 3072, 4096};
                    gemm128_kernel<<<dim3(8, 8, 4), 256, 0, stream>>>(
                        f_hi, f_lo, F_DIM, D_DIM, ja, jb, jc, jd);
                    add4_kernel<<<(n4 + 255) / 256, 256, 0, stream>>>(x, p0, p1, p2, p3, n4);
                }
            }
            head_kernel<<<T_LEN, 256, 0, stream>>>(x, lnf, E, packed, soft);
        }
        argmax_kernel<<<(T_LEN + 255) / 256, 256, 0, stream>>>(soft, (int*)d_out);
        return;
    }

    // -------- fallback: fp32 path --------
    float* ws = (float*)d_ws;
    size_t off = 0;
    float* soft = ws + off; off += (size_t)T_LEN * V_DIM;
    float* x    = ws + off; off += (size_t)T_LEN * D_DIM;
    float* h    = ws + off; off += (size_t)T_LEN * D_DIM;
    float* qb   = ws + off; off += (size_t)T_LEN * D_DIM;
    float* kb   = ws + off; off += (size_t)T_LEN * D_DIM;
    float* vb   = ws + off; off += (size_t)T_LEN * D_DIM;
    float* cb   = ws + off; off += (size_t)T_LEN * D_DIM;
    float* gb   = ws + off; off += (size_t)T_LEN * F_DIM;
    float* ubf  = ws + off; off += (size_t)T_LEN * F_DIM;
    float* tmp  = ws + off; off += (size_t)T_LEN * R_LORA;

    init_soft_kernel<<<(T_LEN * V_DIM + 255) / 256, 256, 0, stream>>>(soft);
    for (int step = 0; step < N_STEPS; step++) {
        embed_kernel<<<T_LEN, 256, 0, stream>>>(soft, E, x);
        for (int l = 0; l < N_LAYERS; l++) {
            const float* ln1_l = ln1 + (size_t)l * D_DIM;
            const float* ln2_l = ln2 + (size_t)l * D_DIM;
            rms_kernel<<<T_LEN, 256, 0, stream>>>(x, ln1_l, h);
            launch_gemm(h, Asrc[0] + (size_t)l * D_DIM * R_LORA, tmp, T_LEN, R_LORA, D_DIM, 1.0f, 0, stream);
            launch_gemm(h, Wsrc[0] + (size_t)l * DD, qb, T_LEN, D_DIM, D_DIM, 1.0f, 0, stream);
            launch_gemm(tmp, Bsrc[0] + (size_t)l * R_LORA * D_DIM, qb, T_LEN, D_DIM, R_LORA, LORA_SCALE, 1, stream);
            launch_gemm(h, Asrc[1] + (size_t)l * D_DIM * R_LORA, tmp, T_LEN, R_LORA, D_DIM, 1.0f, 0, stream);
            launch_gemm(h, Wsrc[1] + (size_t)l * DD, kb, T_LEN, D_DIM, D_DIM, 1.0f, 0, stream);
            launch_gemm(tmp, Bsrc[1] + (size_t)l * R_LORA * D_DIM, kb, T_LEN, D_DIM, R_LORA, LORA_SCALE, 1, stream);
            launch_gemm(h, Asrc[2] + (size_t)l * D_DIM * R_LORA, tmp, T_LEN, R_LORA, D_DIM, 1.0f, 0, stream);
            launch_gemm(h, Wsrc[2] + (size_t)l * DD, vb, T_LEN, D_DIM, D_DIM, 1.0f, 0, stream);
            launch_gemm(tmp, Bsrc[2] + (size_t)l * R_LORA * D_DIM, vb, T_LEN, D_DIM, R_LORA, LORA_SCALE, 1, stream);
            attn_kernel<<<dim3(T_LEN, H_NUM), 256, 0, stream>>>(qb, kb, vb, cb);
            launch_gemm(cb, Asrc[3] + (size_t)l * D_DIM * R_LORA, tmp, T_LEN, R_LORA, D_DIM, 1.0f, 0, stream);
            launch_gemm(cb, Wsrc[3] + (size_t)l * DD, x, T_LEN, D_DIM, D_DIM, 1.0f, 1, stream);
            launch_gemm(tmp, Bsrc[3] + (size_t)l * R_LORA * D_DIM, x, T_LEN, D_DIM, R_LORA, LORA_SCALE, 1, stream);
            rms_kernel<<<T_LEN, 256, 0, stream>>>(x, ln2_l, h);
            launch_gemm(h, Asrc[4] + (size_t)l * D_DIM * R_LORA, tmp, T_LEN, R_LORA, D_DIM, 1.0f, 0, stream);
            launch_gemm(h, Wsrc[4] + (size_t)l * DF, gb, T_LEN, F_DIM, D_DIM, 1.0f, 0, stream);
            launch_gemm(tmp, Bsrc[4] + (size_t)l * R_LORA * F_DIM, gb, T_LEN, F_DIM, R_LORA, LORA_SCALE, 1, stream);
            launch_gemm(h, Asrc[5] + (size_t)l * D_DIM * R_LORA, tmp, T_LEN, R_LORA, D_DIM, 1.0f, 0, stream);
            launch_gemm(h, Wsrc[5] + (size_t)l * DF, ubf, T_LEN, F_DIM, D_DIM, 1.0f, 0, stream);
            launch_gemm(tmp, Bsrc[5] + (size_t)l * R_LORA * F_DIM, ubf, T_LEN, F_DIM, R_LORA, LORA_SCALE, 1, stream);
            silu_mul_kernel<<<(T_LEN * F_DIM + 255) / 256, 256, 0, stream>>>(gb, ubf, gb, T_LEN * F_DIM);
            launch_gemm(gb, Asrc[6] + (size_t)l * F_DIM * R_LORA, tmp, T_LEN, R_LORA, F_DIM, 1.0f, 0, stream);
            launch_gemm(gb, Wsrc[6] + (size_t)l * DF, x, T_LEN, D_DIM, F_DIM, 1.0f, 1, stream);
            launch_gemm(tmp, Bsrc[6] + (size_t)l * R_LORA * D_DIM, x, T_LEN, D_DIM, R_LORA, LORA_SCALE, 1, stream);
        }
        head_kernel<<<T_LEN, 256, 0, stream>>>(x, lnf, E, packed, soft);
    }
    argmax_kernel<<<(T_LEN + 255) / 256, 256, 0, stream>>>(soft, (int*)d_out);
}

// Round 5
// 1229.369 us; speedup vs baseline: 10.0203x; 1.0141x over previous
//
#include <hip/hip_runtime.h>
#include <hip/hip_bf16.h>

#define T_LEN 1024
#define D_DIM 1024
#define V_DIM 17
#define H_NUM 16
#define DH_DIM 64
#define F_DIM 4096
#define R_LORA 32
#define N_LAYERS 2
#define N_STEPS 2
#define MASK_ID 16
#define LORA_SCALE 2.0f

typedef __attribute__((ext_vector_type(8))) short bfx8;   // 8 bf16 in 4 VGPRs
typedef __attribute__((ext_vector_type(4))) float f32x4;

typedef unsigned short ushort_t;
typedef unsigned int uint_t;

#define AS1 __attribute__((address_space(1)))
#define AS3 __attribute__((address_space(3)))

__device__ __forceinline__ void gload16(const ushort_t* g, ushort_t* l) {
    __builtin_amdgcn_global_load_lds((const AS1 void*)(const void*)g,
                                     (AS3 void*)(void*)l, 16, 0, 0);
}

__device__ __forceinline__ ushort_t f2bf(float v) {
    __hip_bfloat16 h = __float2bfloat16(v);
    return __builtin_bit_cast(unsigned short, h);
}
__device__ __forceinline__ float bf2f(ushort_t u) {
    return __uint_as_float(((uint_t)u) << 16);
}
__device__ __forceinline__ void split4_store(float y0, float y1, float y2, float y3,
                                             ushort_t* __restrict__ hi, ushort_t* __restrict__ lo,
                                             size_t idx) {
    ushort_t h0 = f2bf(y0), h1 = f2bf(y1), h2 = f2bf(y2), h3 = f2bf(y3);
    ushort_t l0 = f2bf(y0 - bf2f(h0));
    ushort_t l1 = f2bf(y1 - bf2f(h1));
    ushort_t l2 = f2bf(y2 - bf2f(h2));
    ushort_t l3 = f2bf(y3 - bf2f(h3));
    uint2 hv, lv;
    hv.x = (uint_t)h0 | ((uint_t)h1 << 16);
    hv.y = (uint_t)h2 | ((uint_t)h3 << 16);
    lv.x = (uint_t)l0 | ((uint_t)l1 << 16);
    lv.y = (uint_t)l2 | ((uint_t)l3 << 16);
    *(uint2*)(hi + idx) = hv;
    *(uint2*)(lo + idx) = lv;
}

// ---------------- init soft ----------------
__global__ void init_soft_kernel(float* __restrict__ soft) {
    int idx = blockIdx.x * blockDim.x + threadIdx.x;
    if (idx < T_LEN * V_DIM) {
        soft[idx] = ((idx % V_DIM) == MASK_ID) ? 1.0f : 0.0f;
    }
}

// ---------------- embed: x = soft @ E ----------------
__global__ __launch_bounds__(256) void embed_kernel(const float* __restrict__ soft,
                                                    const float* __restrict__ E,
                                                    float* __restrict__ x) {
    int t = blockIdx.x;
    __shared__ float srow[V_DIM];
    if (threadIdx.x < V_DIM) srow[threadIdx.x] = soft[t * V_DIM + threadIdx.x];
    __syncthreads();
    for (int d = threadIdx.x; d < D_DIM; d += 256) {
        float acc = 0.f;
        #pragma unroll
        for (int v = 0; v < V_DIM; v++) acc += srow[v] * E[v * D_DIM + d];
        x[(size_t)t * D_DIM + d] = acc;
    }
}

// ---------------- fold (batched over layers via z): out^T = split(W + 2*A@B) ----------------
// vectorized: float4 A-row loads, uint4 transposed stores
__global__ __launch_bounds__(256) void fold_kernel(
    const float* __restrict__ W,   // [L,K,N]
    const float* __restrict__ A,   // [L,K,R]
    const float* __restrict__ Bm,  // [L,R,N]
    ushort_t* __restrict__ oHi,    // [L,N,K]
    ushort_t* __restrict__ oLo,
    int K, int N)
{
    const int l = blockIdx.z;
    W   += (size_t)l * K * N;
    A   += (size_t)l * K * R_LORA;
    Bm  += (size_t)l * R_LORA * N;
    oHi += (size_t)l * K * N;
    oLo += (size_t)l * K * N;
    __shared__ uint_t tile[64][65];
    const int tid = threadIdx.x;
    const int n0 = blockIdx.x * 64, k0 = blockIdx.y * 64;
    {
        const int nl = tid & 63, kq = tid >> 6;
        float breg[R_LORA];
        #pragma unroll
        for (int r = 0; r < R_LORA; r++) breg[r] = Bm[(size_t)r * N + n0 + nl];
        for (int i = 0; i < 16; i++) {
            const int kl = kq * 16 + i;
            const size_t kgl = (size_t)(k0 + kl);
            const float4* arow4 = (const float4*)(A + kgl * R_LORA);
            float acc = 0.f;
            #pragma unroll
            for (int r4 = 0; r4 < 8; r4++) {
                float4 a = arow4[r4];
                acc = fmaf(a.x, breg[r4 * 4 + 0], acc);
                acc = fmaf(a.y, breg[r4 * 4 + 1], acc);
                acc = fmaf(a.z, breg[r4 * 4 + 2], acc);
                acc = fmaf(a.w, breg[r4 * 4 + 3], acc);
            }
            float val = W[kgl * N + n0 + nl] + LORA_SCALE * acc;
            ushort_t h = f2bf(val);
            ushort_t l2 = f2bf(val - bf2f(h));
            tile[kl][nl] = ((uint_t)h << 16) | (uint_t)l2;
        }
    }
    __syncthreads();
    {
        const int nl = tid >> 2;            // 0..63 output row (n)
        const int kc0 = (tid & 3) * 16;     // 16 consecutive k per thread
        ushort_t hb[16], lb[16];
        #pragma unroll
        for (int i = 0; i < 16; i++) {
            uint_t pk = tile[kc0 + i][nl];
            hb[i] = (ushort_t)(pk >> 16);
            lb[i] = (ushort_t)(pk & 0xffffu);
        }
        size_t idx = (size_t)(n0 + nl) * K + k0 + kc0;
        *(uint4*)(oHi + idx)     = *(uint4*)&hb[0];
        *(uint4*)(oHi + idx + 8) = *(uint4*)&hb[8];
        *(uint4*)(oLo + idx)     = *(uint4*)&lb[0];
        *(uint4*)(oLo + idx + 8) = *(uint4*)&lb[8];
    }
}

// ---------------- rms + bf16-split ----------------
__global__ __launch_bounds__(256) void rms_split_kernel(
    const float* __restrict__ x, const float* __restrict__ w,
    ushort_t* __restrict__ hi, ushort_t* __restrict__ lo)
{
    const int t = blockIdx.x, tid = threadIdx.x;
    const float* xr = x + (size_t)t * D_DIM;
    float4 xv = *(const float4*)(xr + tid * 4);
    float ss = xv.x * xv.x + xv.y * xv.y + xv.z * xv.z + xv.w * xv.w;
    __shared__ float red[4];
    const int lane = tid & 63, wv = tid >> 6;
    #pragma unroll
    for (int off = 32; off > 0; off >>= 1) ss += __shfl_xor(ss, off);
    if (lane == 0) red[wv] = ss;
    __syncthreads();
    ss = red[0] + red[1] + red[2] + red[3];
    const float r = 1.0f / sqrtf(ss * (1.0f / D_DIM) + 1e-6f);
    const float4 wv4 = *(const float4*)(w + tid * 4);
    size_t base = (size_t)t * D_DIM + tid * 4;
    split4_store(xv.x * r * wv4.x, xv.y * r * wv4.y, xv.z * r * wv4.z, xv.w * r * wv4.w,
                 hi, lo, base);
}

// ---------------- fused: x += p0+p1+p2+p3; h = split(rms(x,w)) ----------------
__global__ __launch_bounds__(256) void add4_rms_split_kernel(
    float* __restrict__ x, const float* __restrict__ p0, const float* __restrict__ p1,
    const float* __restrict__ p2, const float* __restrict__ p3,
    const float* __restrict__ w, ushort_t* __restrict__ hi, ushort_t* __restrict__ lo)
{
    const int t = blockIdx.x, tid = threadIdx.x;
    size_t base = (size_t)t * D_DIM + tid * 4;
    float4 xv = *(const float4*)(x + base);
    float4 a = *(const float4*)(p0 + base);
    float4 b = *(const float4*)(p1 + base);
    float4 c = *(const float4*)(p2 + base);
    float4 d = *(const float4*)(p3 + base);
    xv.x += a.x + b.x + c.x + d.x;
    xv.y += a.y + b.y + c.y + d.y;
    xv.z += a.z + b.z + c.z + d.z;
    xv.w += a.w + b.w + c.w + d.w;
    *(float4*)(x + base) = xv;
    float ss = xv.x * xv.x + xv.y * xv.y + xv.z * xv.z + xv.w * xv.w;
    __shared__ float red[4];
    const int lane = tid & 63, wv = tid >> 6;
    #pragma unroll
    for (int off = 32; off > 0; off >>= 1) ss += __shfl_xor(ss, off);
    if (lane == 0) red[wv] = ss;
    __syncthreads();
    ss = red[0] + red[1] + red[2] + red[3];
    const float r = 1.0f / sqrtf(ss * (1.0f / D_DIM) + 1e-6f);
    const float4 wv4 = *(const float4*)(w + tid * 4);
    split4_store(xv.x * r * wv4.x, xv.y * r * wv4.y, xv.z * r * wv4.z, xv.w * r * wv4.w,
                 hi, lo, base);
}

// ---------------- 128x128 MFMA split-bf16 GEMM, m97-structure ----------------
// swizzle: physical slot = logical slot ^ ((row>>1)&3)  (8 distinct 16B slots per
// 8-lane read group -> conflict-free ds_read_b128); source pre-swizzled to match.
struct GemmJob {
    const ushort_t* Bh;
    const ushort_t* Bl;
    float* Cf;        // if non-null: f32 plain store
    ushort_t* Ch;     // else split store
    ushort_t* Cl;
    int k0, k1;
};

__global__ __launch_bounds__(256) void gemm128_kernel(
    const ushort_t* __restrict__ Ahi, const ushort_t* __restrict__ Alo,
    int K, int N, GemmJob j0, GemmJob j1, GemmJob j2, GemmJob j3)
{
    GemmJob jb = (blockIdx.z == 0) ? j0 : (blockIdx.z == 1) ? j1 : (blockIdx.z == 2) ? j2 : j3;
    __shared__ ushort_t Ash[128][32];
    __shared__ ushort_t Asl[128][32];
    __shared__ ushort_t Bsh[128][32];
    __shared__ ushort_t Bsl[128][32];

    const int tid = threadIdx.x, lane = tid & 63, w = tid >> 6;
    const int l15 = lane & 15, lg = lane >> 4;
    const int m0 = blockIdx.y * 128, n0 = blockIdx.x * 128;
    const int wm = (w >> 1) * 64, wn = (w & 1) * 64;

    const int r0 = w * 32;
    const int rsub = lane >> 2;
    const int cs = lane & 3;
    const int csl = (cs ^ ((rsub >> 1) & 3)) * 8;   // pre-swizzled source col (shorts)
    const int rsl = (lg ^ ((l15 >> 1) & 3)) * 8;    // swizzled read col (shorts)

    f32x4 acc[4][4];
    #pragma unroll
    for (int i = 0; i < 4; i++)
        #pragma unroll
        for (int j = 0; j < 4; j++) acc[i][j] = f32x4{0.f, 0.f, 0.f, 0.f};

    const size_t rowA = (size_t)(m0 + r0 + rsub) * K;
    const size_t rowB = (size_t)(n0 + r0 + rsub) * K;
    const size_t rstep = (size_t)16 * K;

    for (int kk = jb.k0; kk < jb.k1; kk += 32) {
        {
            const ushort_t* a0 = Ahi + rowA + kk + csl;
            const ushort_t* a1 = Alo + rowA + kk + csl;
            const ushort_t* b0 = jb.Bh + rowB + kk + csl;
            const ushort_t* b1 = jb.Bl + rowB + kk + csl;
            gload16(a0,         &Ash[r0][0]);
            gload16(a0 + rstep, &Ash[r0 + 16][0]);
            gload16(a1,         &Asl[r0][0]);
            gload16(a1 + rstep, &Asl[r0 + 16][0]);
            gload16(b0,         &Bsh[r0][0]);
            gload16(b0 + rstep, &Bsh[r0 + 16][0]);
            gload16(b1,         &Bsl[r0][0]);
            gload16(b1 + rstep, &Bsl[r0 + 16][0]);
        }
        __syncthreads();   // drains vmcnt: staged data visible to all waves
        bfx8 bh[4], bl[4];
        #pragma unroll
        for (int ni = 0; ni < 4; ni++) {
            bh[ni] = *(const bfx8*)&Bsh[wn + ni * 16 + l15][rsl];
            bl[ni] = *(const bfx8*)&Bsl[wn + ni * 16 + l15][rsl];
        }
        #pragma unroll
        for (int mi = 0; mi < 4; mi++) {
            bfx8 ah = *(const bfx8*)&Ash[wm + mi * 16 + l15][rsl];
            bfx8 al = *(const bfx8*)&Asl[wm + mi * 16 + l15][rsl];
            #pragma unroll
            for (int ni = 0; ni < 4; ni++) {
                acc[mi][ni] = __builtin_amdgcn_mfma_f32_16x16x32_bf16(ah, bh[ni], acc[mi][ni], 0, 0, 0);
                acc[mi][ni] = __builtin_amdgcn_mfma_f32_16x16x32_bf16(ah, bl[ni], acc[mi][ni], 0, 0, 0);
                acc[mi][ni] = __builtin_amdgcn_mfma_f32_16x16x32_bf16(al, bh[ni], acc[mi][ni], 0, 0, 0);
            }
        }
        __syncthreads();   // all reads done before next stage overwrites
    }

    if (jb.Cf) {
        #pragma unroll
        for (int mi = 0; mi < 4; mi++)
            #pragma unroll
            for (int ni = 0; ni < 4; ni++) {
                int col = n0 + wn + ni * 16 + l15;
                #pragma unroll
                for (int i = 0; i < 4; i++) {
                    int row = m0 + wm + mi * 16 + lg * 4 + i;
                    jb.Cf[(size_t)row * N + col] = acc[mi][ni][i];
                }
            }
    } else {
        #pragma unroll
        for (int mi = 0; mi < 4; mi++)
            #pragma unroll
            for (int ni = 0; ni < 4; ni++) {
                int col = n0 + wn + ni * 16 + l15;
                #pragma unroll
                for (int i = 0; i < 4; i++) {
                    int row = m0 + wm + mi * 16 + lg * 4 + i;
                    size_t idx = (size_t)row * N + col;
                    float v = acc[mi][ni][i];
                    ushort_t h = f2bf(v);
                    jb.Ch[idx] = h;
                    jb.Cl[idx] = f2bf(v - bf2f(h));
                }
            }
    }
}

// ---------------- add4: x += sum(partials) ----------------
__global__ void add4_kernel(float* __restrict__ x, const float* __restrict__ p0,
                            const float* __restrict__ p1, const float* __restrict__ p2,
                            const float* __restrict__ p3, int n4) {
    int i = blockIdx.x * blockDim.x + threadIdx.x;
    if (i < n4) {
        float4 xv = *(const float4*)(x + (size_t)i * 4);
        float4 a = *(const float4*)(p0 + (size_t)i * 4);
        float4 b = *(const float4*)(p1 + (size_t)i * 4);
        float4 c = *(const float4*)(p2 + (size_t)i * 4);
        float4 d = *(const float4*)(p3 + (size_t)i * 4);
        xv.x += a.x + b.x + c.x + d.x;
        xv.y += a.y + b.y + c.y + d.y;
        xv.z += a.z + b.z + c.z + d.z;
        xv.w += a.w + b.w + c.w + d.w;
        *(float4*)(x + (size_t)i * 4) = xv;
    }
}

// ---------------- MFMA flash attention ----------------
#define KS_PAD 72
#define P_PAD 72
__global__ __launch_bounds__(256, 1) void attn_mfma_kernel(
    const ushort_t* __restrict__ qh, const ushort_t* __restrict__ ql,
    const ushort_t* __restrict__ kh, const ushort_t* __restrict__ kl,
    const ushort_t* __restrict__ vh, const ushort_t* __restrict__ vl,
    ushort_t* __restrict__ chi, ushort_t* __restrict__ clo)
{
    __shared__ ushort_t Ksh[64][KS_PAD];
    __shared__ ushort_t Ksl[64][KS_PAD];
    __shared__ ushort_t VTh[64][KS_PAD];   // transposed V: [d][k]
    __shared__ ushort_t VTl[64][KS_PAD];
    __shared__ ushort_t Ph[4][16][P_PAD];  // per-wave P strips
    __shared__ ushort_t Pl[4][16][P_PAD];

    const int qt = blockIdx.x, hh = blockIdx.y;
    const int tid = threadIdx.x, w = tid >> 6, lane = tid & 63;
    const int l15 = lane & 15, lg = lane >> 4;
    const int q0 = qt * 64;
    const int hcol = hh * DH_DIM;

    bfx8 qa_h[2], qa_l[2];
    {
        size_t qrow = (size_t)(q0 + w * 16 + l15) * D_DIM + hcol;
        #pragma unroll
        for (int ks = 0; ks < 2; ks++) {
            qa_h[ks] = *(const bfx8*)(qh + qrow + ks * 32 + lg * 8);
            qa_l[ks] = *(const bfx8*)(ql + qrow + ks * 32 + lg * 8);
        }
    }

    f32x4 o[4];
    #pragma unroll
    for (int ni = 0; ni < 4; ni++) o[ni] = f32x4{0.f, 0.f, 0.f, 0.f};
    float mrun[4], lrun[4];
    #pragma unroll
    for (int i = 0; i < 4; i++) { mrun[i] = -3.0e38f; lrun[i] = 0.f; }

    const int srow = tid >> 2;
    const int sseg = (tid & 3) * 16;
    const int vp = tid & 31;
    const int vd0 = (tid >> 5) * 8;

    for (int kt = 0; kt <= qt; kt++) {
        __syncthreads();
        {
            size_t src = (size_t)(kt * 64 + srow) * D_DIM + hcol + sseg;
            *(uint4*)&Ksh[srow][sseg]     = *(const uint4*)(kh + src);
            *(uint4*)&Ksh[srow][sseg + 8] = *(const uint4*)(kh + src + 8);
            *(uint4*)&Ksl[srow][sseg]     = *(const uint4*)(kl + src);
            *(uint4*)&Ksl[srow][sseg + 8] = *(const uint4*)(kl + src + 8);
        }
        {
            size_t s0 = (size_t)(kt * 64 + 2 * vp) * D_DIM + hcol + vd0;
            uint4 h0 = *(const uint4*)(vh + s0);
            uint4 h1 = *(const uint4*)(vh + s0 + D_DIM);
            uint4 l0 = *(const uint4*)(vl + s0);
            uint4 l1 = *(const uint4*)(vl + s0 + D_DIM);
            const ushort_t* a = (const ushort_t*)&h0;
            const ushort_t* b = (const ushort_t*)&h1;
            const ushort_t* c = (const ushort_t*)&l0;
            const ushort_t* d = (const ushort_t*)&l1;
            #pragma unroll
            for (int j = 0; j < 8; j++) {
                *(uint_t*)&VTh[vd0 + j][2 * vp] = (uint_t)a[j] | ((uint_t)b[j] << 16);
                *(uint_t*)&VTl[vd0 + j][2 * vp] = (uint_t)c[j] | ((uint_t)d[j] << 16);
            }
        }
        __syncthreads();

        f32x4 s[4];
        #pragma unroll
        for (int ni = 0; ni < 4; ni++) s[ni] = f32x4{0.f, 0.f, 0.f, 0.f};
        #pragma unroll
        for (int ks = 0; ks < 2; ks++) {
            #pragma unroll
            for (int ni = 0; ni < 4; ni++) {
                bfx8 bh = *(const bfx8*)&Ksh[ni * 16 + l15][ks * 32 + lg * 8];
                bfx8 bl = *(const bfx8*)&Ksl[ni * 16 + l15][ks * 32 + lg * 8];
                s[ni] = __builtin_amdgcn_mfma_f32_16x16x32_bf16(qa_h[ks], bh, s[ni], 0, 0, 0);
                s[ni] = __builtin_amdgcn_mfma_f32_16x16x32_bf16(qa_h[ks], bl, s[ni], 0, 0, 0);
                s[ni] = __builtin_amdgcn_mfma_f32_16x16x32_bf16(qa_l[ks], bh, s[ni], 0, 0, 0);
            }
        }

        const int kbase = kt * 64;
        float rmax[4];
        #pragma unroll
        for (int i = 0; i < 4; i++) rmax[i] = -3.0e38f;
        #pragma unroll
        for (int ni = 0; ni < 4; ni++) {
            int kc = kbase + ni * 16 + l15;
            #pragma unroll
            for (int i = 0; i < 4; i++) {
                int qrow = q0 + w * 16 + lg * 4 + i;
                float v = s[ni][i] * 0.125f;
                v = (kc <= qrow) ? v : -3.0e38f;
                s[ni][i] = v;
                rmax[i] = fmaxf(rmax[i], v);
            }
        }
        #pragma unroll
        for (int off = 1; off < 16; off <<= 1) {
            #pragma unroll
            for (int i = 0; i < 4; i++) rmax[i] = fmaxf(rmax[i], __shfl_xor(rmax[i], off));
        }
        float psum[4];
        #pragma unroll
        for (int i = 0; i < 4; i++) {
            float nm = fmaxf(mrun[i], rmax[i]);
            float sc = __expf(mrun[i] - nm);
            lrun[i] *= sc;
            #pragma unroll
            for (int ni = 0; ni < 4; ni++) o[ni][i] *= sc;
            mrun[i] = nm;
            psum[i] = 0.f;
        }
        #pragma unroll
        for (int ni = 0; ni < 4; ni++) {
            #pragma unroll
            for (int i = 0; i < 4; i++) {
                float e = __expf(s[ni][i] - mrun[i]);
                s[ni][i] = e;
                psum[i] += e;
            }
        }
        #pragma unroll
        for (int off = 1; off < 16; off <<= 1) {
            #pragma unroll
            for (int i = 0; i < 4; i++) psum[i] += __shfl_xor(psum[i], off);
        }
        #pragma unroll
        for (int i = 0; i < 4; i++) lrun[i] += psum[i];

        #pragma unroll
        for (int ni = 0; ni < 4; ni++) {
            #pragma unroll
            for (int i = 0; i < 4; i++) {
                float e = s[ni][i];
                ushort_t hp = f2bf(e);
                Ph[w][lg * 4 + i][ni * 16 + l15] = hp;
                Pl[w][lg * 4 + i][ni * 16 + l15] = f2bf(e - bf2f(hp));
            }
        }
        #pragma unroll
        for (int ks = 0; ks < 2; ks++) {
            bfx8 ah = *(const bfx8*)&Ph[w][l15][ks * 32 + lg * 8];
            bfx8 al = *(const bfx8*)&Pl[w][l15][ks * 32 + lg * 8];
            #pragma unroll
            for (int ni = 0; ni < 4; ni++) {
                bfx8 bh = *(const bfx8*)&VTh[ni * 16 + l15][ks * 32 + lg * 8];
                bfx8 bl = *(const bfx8*)&VTl[ni * 16 + l15][ks * 32 + lg * 8];
                o[ni] = __builtin_amdgcn_mfma_f32_16x16x32_bf16(ah, bh, o[ni], 0, 0, 0);
                o[ni] = __builtin_amdgcn_mfma_f32_16x16x32_bf16(ah, bl, o[ni], 0, 0, 0);
                o[ni] = __builtin_amdgcn_mfma_f32_16x16x32_bf16(al, bh, o[ni], 0, 0, 0);
            }
        }
    }

    #pragma unroll
    for (int i = 0; i < 4; i++) {
        float inv = 1.0f / lrun[i];
        #pragma unroll
        for (int ni = 0; ni < 4; ni++) o[ni][i] *= inv;
    }
    #pragma unroll
    for (int ni = 0; ni < 4; ni++) {
        int col = hcol + ni * 16 + l15;
        #pragma unroll
        for (int i = 0; i < 4; i++) {
            int row = q0 + w * 16 + lg * 4 + i;
            size_t idx = (size_t)row * D_DIM + col;
            float v = o[ni][i];
            ushort_t hp = f2bf(v);
            chi[idx] = hp;
            clo[idx] = f2bf(v - bf2f(hp));
        }
    }
}

// ---------------- silu(g)*u -> split ----------------
__global__ void silu_split_kernel(const float* __restrict__ g, const float* __restrict__ u,
                                  ushort_t* __restrict__ hi, ushort_t* __restrict__ lo, int n4) {
    int i = blockIdx.x * blockDim.x + threadIdx.x;
    if (i < n4) {
        float4 gv = *(const float4*)(g + (size_t)i * 4);
        float4 uv = *(const float4*)(u + (size_t)i * 4);
        float y0 = gv.x / (1.f + expf(-gv.x)) * uv.x;
        float y1 = gv.y / (1.f + expf(-gv.y)) * uv.y;
        float y2 = gv.z / (1.f + expf(-gv.z)) * uv.z;
        float y3 = gv.w / (1.f + expf(-gv.w)) * uv.w;
        split4_store(y0, y1, y2, y3, hi, lo, (size_t)i * 4);
    }
}

// ---------------- head ----------------
__global__ __launch_bounds__(256) void head_kernel(const float* __restrict__ x,
                                                   const float* __restrict__ lnf,
                                                   const float* __restrict__ E,
                                                   const int* __restrict__ tok,
                                                   float* __restrict__ soft) {
    int t = blockIdx.x;
    int tid = threadIdx.x;
    __shared__ float y[D_DIM];
    __shared__ float red[4];
    __shared__ float logits[V_DIM];
    const float* xr = x + (size_t)t * D_DIM;
    float ss = 0.f;
    for (int d = tid; d < D_DIM; d += 256) { float v = xr[d]; ss += v * v; }
    int lane = tid & 63, wave = tid >> 6;
    for (int off = 32; off > 0; off >>= 1) ss += __shfl_xor(ss, off);
    if (lane == 0) red[wave] = ss;
    __syncthreads();
    ss = red[0] + red[1] + red[2] + red[3];
    float r = 1.0f / sqrtf(ss * (1.0f / D_DIM) + 1e-6f);
    for (int d = tid; d < D_DIM; d += 256) y[d] = xr[d] * r * lnf[d];
    __syncthreads();
    for (int vv = wave; vv < V_DIM; vv += 4) {
        float p = 0.f;
        for (int d = lane; d < D_DIM; d += 64) p += y[d] * E[vv * D_DIM + d];
        for (int off = 32; off > 0; off >>= 1) p += __shfl_xor(p, off);
        if (lane == 0) logits[vv] = p;
    }
    __syncthreads();
    if (tid == 0) {
        int tk = tok[t];
        if (tk != MASK_ID) {
            for (int vv = 0; vv < V_DIM; vv++) soft[t * V_DIM + vv] = (vv == tk) ? 1.f : 0.f;
        } else {
            float mx = -1e30f;
            for (int vv = 0; vv < V_DIM; vv++) mx = fmaxf(mx, logits[vv]);
            float sm = 0.f;
            float e[V_DIM];
            for (int vv = 0; vv < V_DIM; vv++) { e[vv] = expf(logits[vv] - mx); sm += e[vv]; }
            float invs = 1.0f / sm;
            for (int vv = 0; vv < V_DIM; vv++) soft[t * V_DIM + vv] = e[vv] * invs;
        }
    }
}

// ---------------- argmax ----------------
__global__ void argmax_kernel(const float* __restrict__ soft, int* __restrict__ out) {
    int t = blockIdx.x * blockDim.x + threadIdx.x;
    if (t < T_LEN) {
        const float* s = soft + t * V_DIM;
        int best = 0;
        float bv = s[0];
        #pragma unroll
        for (int vv = 1; vv < V_DIM; vv++) {
            float v = s[vv];
            if (v > bv) { bv = v; best = vv; }
        }
        out[t] = best;
    }
}

// ================= fallback kernels (fp32, if ws too small) =================
__global__ __launch_bounds__(256) void rms_kernel(const float* __restrict__ x,
                                                  const float* __restrict__ w,
                                                  float* __restrict__ out) {
    int t = blockIdx.x;
    const float* xr = x + (size_t)t * D_DIM;
    float ss = 0.f;
    for (int d = threadIdx.x; d < D_DIM; d += 256) { float v = xr[d]; ss += v * v; }
    __shared__ float red[4];
    int lane = threadIdx.x & 63, wave = threadIdx.x >> 6;
    for (int off = 32; off > 0; off >>= 1) ss += __shfl_xor(ss, off);
    if (lane == 0) red[wave] = ss;
    __syncthreads();
    ss = red[0] + red[1] + red[2] + red[3];
    float r = 1.0f / sqrtf(ss * (1.0f / D_DIM) + 1e-6f);
    for (int d = threadIdx.x; d < D_DIM; d += 256) out[(size_t)t * D_DIM + d] = xr[d] * r * w[d];
}

__global__ __launch_bounds__(256) void gemm_kernel(const float* __restrict__ A,
                                                   const float* __restrict__ B,
                                                   float* __restrict__ C,
                                                   int M, int N, int K,
                                                   float alpha, int accumulate) {
    const int BM = 64, BN = 64, BK = 16;
    __shared__ float As[BK][BM];
    __shared__ float Bsh[BK][BN];
    int tid = threadIdx.x;
    int tx = tid % 16, ty = tid / 16;
    int row0 = blockIdx.y * BM, col0 = blockIdx.x * BN;
    float acc[4][4] = {};
    for (int k0 = 0; k0 < K; k0 += BK) {
        #pragma unroll
        for (int i = 0; i < 4; i++) {
            int e = tid * 4 + i;
            int m = e / BK, kk = e % BK;
            int gr = row0 + m, gk = k0 + kk;
            As[kk][m] = (gr < M && gk < K) ? A[(size_t)gr * K + gk] : 0.f;
        }
        #pragma unroll
        for (int i = 0; i < 4; i++) {
            int e = tid * 4 + i;
            int kk = e / BN, n = e % BN;
            int gk = k0 + kk, gc = col0 + n;
            Bsh[kk][n] = (gk < K && gc < N) ? B[(size_t)gk * N + gc] : 0.f;
        }
        __syncthreads();
        #pragma unroll
        for (int kk = 0; kk < BK; kk++) {
            float a[4], b[4];
            #pragma unroll
            for (int i = 0; i < 4; i++) a[i] = As[kk][ty * 4 + i];
            #pragma unroll
            for (int j = 0; j < 4; j++) b[j] = Bsh[kk][tx * 4 + j];
            #pragma unroll
            for (int i = 0; i < 4; i++)
                #pragma unroll
                for (int j = 0; j < 4; j++)
                    acc[i][j] += a[i] * b[j];
        }
        __syncthreads();
    }
    #pragma unroll
    for (int i = 0; i < 4; i++) {
        int r = row0 + ty * 4 + i;
        if (r >= M) continue;
        #pragma unroll
        for (int j = 0; j < 4; j++) {
            int c = col0 + tx * 4 + j;
            if (c >= N) continue;
            size_t idx = (size_t)r * N + c;
            float val = alpha * acc[i][j];
            if (accumulate) val += C[idx];
            C[idx] = val;
        }
    }
}

__global__ __launch_bounds__(256) void attn_kernel(const float* __restrict__ q,
                                                   const float* __restrict__ k,
                                                   const float* __restrict__ v,
                                                   float* __restrict__ ctx) {
    int qi = blockIdx.x;
    int hh = blockIdx.y;
    __shared__ float sc[T_LEN];
    __shared__ float qrow[DH_DIM];
    __shared__ float red[8];
    __shared__ float part[4][DH_DIM];
    int tid = threadIdx.x;
    int lane = tid & 63, wave = tid >> 6;
    const float* qp = q + (size_t)qi * D_DIM + hh * DH_DIM;
    if (tid < DH_DIM) qrow[tid] = qp[tid];
    __syncthreads();
    const float scale = 0.125f;
    for (int j = wave; j <= qi; j += 4) {
        const float* kp = k + (size_t)j * D_DIM + hh * DH_DIM;
        float p = qrow[lane] * kp[lane];
        for (int off = 32; off > 0; off >>= 1) p += __shfl_xor(p, off);
        if (lane == 0) sc[j] = p * scale;
    }
    __syncthreads();
    int n = qi + 1;
    float m = -1e30f;
    for (int j = tid; j < n; j += 256) m = fmaxf(m, sc[j]);
    for (int off = 32; off > 0; off >>= 1) m = fmaxf(m, __shfl_xor(m, off));
    if (lane == 0) red[wave] = m;
    __syncthreads();
    m = fmaxf(fmaxf(red[0], red[1]), fmaxf(red[2], red[3]));
    float s = 0.f;
    for (int j = tid; j < n; j += 256) { float e = expf(sc[j] - m); sc[j] = e; s += e; }
    for (int off = 32; off > 0; off >>= 1) s += __shfl_xor(s, off);
    if (lane == 0) red[4 + wave] = s;
    __syncthreads();
    s = red[4] + red[5] + red[6] + red[7];
    float inv = 1.0f / s;
    float acc = 0.f;
    for (int j = wave; j < n; j += 4) {
        acc += sc[j] * v[(size_t)j * D_DIM + hh * DH_DIM + lane];
    }
    part[wave][lane] = acc;
    __syncthreads();
    if (tid < DH_DIM) {
        float r = (part[0][tid] + part[1][tid] + part[2][tid] + part[3][tid]) * inv;
        ctx[(size_t)qi * D_DIM + hh * DH_DIM + tid] = r;
    }
}

__global__ void silu_mul_kernel(const float* __restrict__ g, const float* __restrict__ u,
                                float* __restrict__ out, int nelem) {
    int i = blockIdx.x * blockDim.x + threadIdx.x;
    if (i < nelem) {
        float gv = g[i];
        float sg = 1.0f / (1.0f + expf(-gv));
        out[i] = gv * sg * u[i];
    }
}

static inline void launch_gemm(const float* A, const float* B, float* C,
                               int M, int N, int K, float alpha, int accumulate,
                               hipStream_t stream) {
    dim3 grid((N + 63) / 64, (M + 63) / 64);
    gemm_kernel<<<grid, 256, 0, stream>>>(A, B, C, M, N, K, alpha, accumulate);
}

// =====================================================================================
extern "C" void kernel_launch(void* const* d_in, const int* in_sizes, int n_in,
                              void* d_out, int out_size, void* d_ws, size_t ws_size,
                              hipStream_t stream) {
    const int* packed = (const int*)d_in[0];
    const float* E  = (const float*)d_in[6];
    const float* Wsrc[7] = {(const float*)d_in[7],  (const float*)d_in[10], (const float*)d_in[13],
                            (const float*)d_in[16], (const float*)d_in[19], (const float*)d_in[22],
                            (const float*)d_in[25]};
    const float* Asrc[7] = {(const float*)d_in[8],  (const float*)d_in[11], (const float*)d_in[14],
                            (const float*)d_in[17], (const float*)d_in[20], (const float*)d_in[23],
                            (const float*)d_in[26]};
    const float* Bsrc[7] = {(const float*)d_in[9],  (const float*)d_in[12], (const float*)d_in[15],
                            (const float*)d_in[18], (const float*)d_in[21], (const float*)d_in[24],
                            (const float*)d_in[27]};
    const float* ln1 = (const float*)d_in[28];
    const float* ln2 = (const float*)d_in[29];
    const float* lnf = (const float*)d_in[30];

    const size_t DD = (size_t)D_DIM * D_DIM;     // 1M
    const size_t DF = (size_t)D_DIM * F_DIM;     // 4M
    const size_t wsizes[7] = {DD, DD, DD, DD, DF, DF, DF};
    const int Kdim[7] = {D_DIM, D_DIM, D_DIM, D_DIM, D_DIM, D_DIM, F_DIM};
    const int Ndim[7] = {D_DIM, D_DIM, D_DIM, D_DIM, F_DIM, F_DIM, D_DIM};

    // fast-path workspace requirement
    size_t u16_elems = 0;
    for (int p = 0; p < 7; p++) u16_elems += 2ull * N_LAYERS * wsizes[p];  // folded hi/lo
    u16_elems += 2ull * DD;            // h hi/lo
    u16_elems += 2ull * DD;            // ctx hi/lo
    u16_elems += 2ull * DF;            // ff hi/lo
    u16_elems += 6ull * DD;            // q,k,v hi/lo
    size_t f32_elems = (size_t)T_LEN * V_DIM + DD /*x*/ + 2 * DF /*g,u (p0..3 alias)*/;
    size_t need = u16_elems * 2 + f32_elems * 4 + 256;

    if (ws_size >= need) {
        // -------- fast path --------
        ushort_t* ub = (ushort_t*)d_ws;
        size_t uo = 0;
        ushort_t *Whi[7], *Wlo[7];
        for (int p = 0; p < 7; p++) {
            Whi[p] = ub + uo; uo += (size_t)N_LAYERS * wsizes[p];
            Wlo[p] = ub + uo; uo += (size_t)N_LAYERS * wsizes[p];
        }
        ushort_t* h_hi = ub + uo; uo += DD;
        ushort_t* h_lo = ub + uo; uo += DD;
        ushort_t* c_hi = ub + uo; uo += DD;
        ushort_t* c_lo = ub + uo; uo += DD;
        ushort_t* f_hi = ub + uo; uo += DF;
        ushort_t* f_lo = ub + uo; uo += DF;
        ushort_t* qbh = ub + uo; uo += DD;
        ushort_t* qbl = ub + uo; uo += DD;
        ushort_t* kbh = ub + uo; uo += DD;
        ushort_t* kbl = ub + uo; uo += DD;
        ushort_t* vbh = ub + uo; uo += DD;
        ushort_t* vbl = ub + uo; uo += DD;
        float* fb = (float*)(ub + uo);
        size_t fo = 0;
        float* soft = fb + fo; fo += (size_t)T_LEN * V_DIM;
        float* x    = fb + fo; fo += DD;
        float* gbuf = fb + fo; fo += DF;
        float* ubuf = fb + fo; fo += DF;
        // split-K partial buffers alias gbuf (different live ranges)
        float* p0 = gbuf;
        float* p1 = gbuf + DD;
        float* p2 = gbuf + 2 * DD;
        float* p3 = gbuf + 3 * DD;

        // fold weights (batched over layers)
        for (int p = 0; p < 7; p++) {
            dim3 grid(Ndim[p] / 64, Kdim[p] / 64, N_LAYERS);
            fold_kernel<<<grid, 256, 0, stream>>>(Wsrc[p], Asrc[p], Bsrc[p],
                                                  Whi[p], Wlo[p], Kdim[p], Ndim[p]);
        }

        init_soft_kernel<<<(T_LEN * V_DIM + 255) / 256, 256, 0, stream>>>(soft);

        const int n4 = (int)(DD / 4);
        for (int step = 0; step < N_STEPS; step++) {
            embed_kernel<<<T_LEN, 256, 0, stream>>>(soft, E, x);
            // h = split(rms(x, ln1[0])) for layer 0; later layers get h from fused add+rms
            rms_split_kernel<<<T_LEN, 256, 0, stream>>>(x, ln1, h_hi, h_lo);
            for (int l = 0; l < N_LAYERS; l++) {
                {   // fused QKV: 3 jobs, 128^2 tiles
                    GemmJob jq = {Whi[0] + l * DD, Wlo[0] + l * DD, nullptr, qbh, qbl, 0, D_DIM};
                    GemmJob jk = {Whi[1] + l * DD, Wlo[1] + l * DD, nullptr, kbh, kbl, 0, D_DIM};
                    GemmJob jv = {Whi[2] + l * DD, Wlo[2] + l * DD, nullptr, vbh, vbl, 0, D_DIM};
                    gemm128_kernel<<<dim3(8, 8, 3), 256, 0, stream>>>(
                        h_hi, h_lo, D_DIM, D_DIM, jq, jk, jv, jq);
                }
                attn_mfma_kernel<<<dim3(T_LEN / 64, H_NUM), 256, 0, stream>>>(
                    qbh, qbl, kbh, kbl, vbh, vbl, c_hi, c_lo);
                {   // o-proj split-K x4 + fused add + rms(ln2[l]) -> h
                    const ushort_t* bh = Whi[3] + l * DD;
                    const ushort_t* bl = Wlo[3] + l * DD;
                    GemmJob ja = {bh, bl, p0, nullptr, nullptr, 0, 256};
                    GemmJob jb = {bh, bl, p1, nullptr, nullptr, 256, 512};
                    GemmJob jc = {bh, bl, p2, nullptr, nullptr, 512, 768};
                    GemmJob jd = {bh, bl, p3, nullptr, nullptr, 768, 1024};
                    gemm128_kernel<<<dim3(8, 8, 4), 256, 0, stream>>>(
                        c_hi, c_lo, D_DIM, D_DIM, ja, jb, jc, jd);
                    add4_rms_split_kernel<<<T_LEN, 256, 0, stream>>>(
                        x, p0, p1, p2, p3, ln2 + (size_t)l * D_DIM, h_hi, h_lo);
                }
                {   // fused G,U
                    GemmJob jg = {Whi[4] + l * DF, Wlo[4] + l * DF, gbuf, nullptr, nullptr, 0, D_DIM};
                    GemmJob ju = {Whi[5] + l * DF, Wlo[5] + l * DF, ubuf, nullptr, nullptr, 0, D_DIM};
                    gemm128_kernel<<<dim3(32, 8, 2), 256, 0, stream>>>(
                        h_hi, h_lo, D_DIM, F_DIM, jg, ju, jg, jg);
                }
                silu_split_kernel<<<(T_LEN * F_DIM / 4 + 255) / 256, 256, 0, stream>>>(
                    gbuf, ubuf, f_hi, f_lo, T_LEN * F_DIM / 4);
                {   // d-proj split-K x4 (K=4096)
                    const ushort_t* bh = Whi[6] + l * DF;
                    const ushort_t* bl = Wlo[6] + l * DF;
                    GemmJob ja = {bh, bl, p0, nullptr, nullptr, 0, 1024};
                    GemmJob jb = {bh, bl, p1, nullptr, nullptr, 1024, 2048};
                    GemmJob jc = {bh, bl, p2, nullptr, nullptr, 2048, 3072};
                    GemmJob jd = {bh, bl, p3, nullptr, nullptr, 3072, 4096};
                    gemm128_kernel<<<dim3(8, 8, 4), 256, 0, stream>>>(
                        f_hi, f_lo, F_DIM, D_DIM, ja, jb, jc, jd);
                    if (l + 1 < N_LAYERS) {
                        // fused add + rms(ln1[l+1]) -> h for next layer
                        add4_rms_split_kernel<<<T_LEN, 256, 0, stream>>>(
                            x, p0, p1, p2, p3, ln1 + (size_t)(l + 1) * D_DIM, h_hi, h_lo);
                    } else {
                        add4_kernel<<<(n4 + 255) / 256, 256, 0, stream>>>(x, p0, p1, p2, p3, n4);
                    }
                }
            }
            head_kernel<<<T_LEN, 256, 0, stream>>>(x, lnf, E, packed, soft);
        }
        argmax_kernel<<<(T_LEN + 255) / 256, 256, 0, stream>>>(soft, (int*)d_out);
        return;
    }

    // -------- fallback: fp32 path --------
    float* ws = (float*)d_ws;
    size_t off = 0;
    float* soft = ws + off; off += (size_t)T_LEN * V_DIM;
    float* x    = ws + off; off += (size_t)T_LEN * D_DIM;
    float* h    = ws + off; off += (size_t)T_LEN * D_DIM;
    float* qb   = ws + off; off += (size_t)T_LEN * D_DIM;
    float* kb   = ws + off; off += (size_t)T_LEN * D_DIM;
    float* vb   = ws + off; off += (size_t)T_LEN * D_DIM;
    float* cb   = ws + off; off += (size_t)T_LEN * D_DIM;
    float* gb   = ws + off; off += (size_t)T_LEN * F_DIM;
    float* ubf  = ws + off; off += (size_t)T_LEN * F_DIM;
    float* tmp  = ws + off; off += (size_t)T_LEN * R_LORA;

    init_soft_kernel<<<(T_LEN * V_DIM + 255) / 256, 256, 0, stream>>>(soft);
    for (int step = 0; step < N_STEPS; step++) {
        embed_kernel<<<T_LEN, 256, 0, stream>>>(soft, E, x);
        for (int l = 0; l < N_LAYERS; l++) {
            const float* ln1_l = ln1 + (size_t)l * D_DIM;
            const float* ln2_l = ln2 + (size_t)l * D_DIM;
            rms_kernel<<<T_LEN, 256, 0, stream>>>(x, ln1_l, h);
            launch_gemm(h, Asrc[0] + (size_t)l * D_DIM * R_LORA, tmp, T_LEN, R_LORA, D_DIM, 1.0f, 0, stream);
            launch_gemm(h, Wsrc[0] + (size_t)l * DD, qb, T_LEN, D_DIM, D_DIM, 1.0f, 0, stream);
            launch_gemm(tmp, Bsrc[0] + (size_t)l * R_LORA * D_DIM, qb, T_LEN, D_DIM, R_LORA, LORA_SCALE, 1, stream);
            launch_gemm(h, Asrc[1] + (size_t)l * D_DIM * R_LORA, tmp, T_LEN, R_LORA, D_DIM, 1.0f, 0, stream);
            launch_gemm(h, Wsrc[1] + (size_t)l * DD, kb, T_LEN, D_DIM, D_DIM, 1.0f, 0, stream);
            launch_gemm(tmp, Bsrc[1] + (size_t)l * R_LORA * D_DIM, kb, T_LEN, D_DIM, R_LORA, LORA_SCALE, 1, stream);
            launch_gemm(h, Asrc[2] + (size_t)l * D_DIM * R_LORA, tmp, T_LEN, R_LORA, D_DIM, 1.0f, 0, stream);
            launch_gemm(h, Wsrc[2] + (size_t)l * DD, vb, T_LEN, D_DIM, D_DIM, 1.0f, 0, stream);
            launch_gemm(tmp, Bsrc[2] + (size_t)l * R_LORA * D_DIM, vb, T_LEN, D_DIM, R_LORA, LORA_SCALE, 1, stream);
            attn_kernel<<<dim3(T_LEN, H_NUM), 256, 0, stream>>>(qb, kb, vb, cb);
            launch_gemm(cb, Asrc[3] + (size_t)l * D_DIM * R_LORA, tmp, T_LEN, R_LORA, D_DIM, 1.0f, 0, stream);
            launch_gemm(cb, Wsrc[3] + (size_t)l * DD, x, T_LEN, D_DIM, D_DIM, 1.0f, 1, stream);
            launch_gemm(tmp, Bsrc[3] + (size_t)l * R_LORA * D_DIM, x, T_LEN, D_DIM, R_LORA, LORA_SCALE, 1, stream);
            rms_kernel<<<T_LEN, 256, 0, stream>>>(x, ln2_l, h);
            launch_gemm(h, Asrc[4] + (size_t)l * D_DIM * R_LORA, tmp, T_LEN, R_LORA, D_DIM, 1.0f, 0, stream);
            launch_gemm(h, Wsrc[4] + (size_t)l * DF, gb, T_LEN, F_DIM, D_DIM, 1.0f, 0, stream);
            launch_gemm(tmp, Bsrc[4] + (size_t)l * R_LORA * F_DIM, gb, T_LEN, F_DIM, R_LORA, LORA_SCALE, 1, stream);
            launch_gemm(h, Asrc[5] + (size_t)l * D_DIM * R_LORA, tmp, T_LEN, R_LORA, D_DIM, 1.0f, 0, stream);
            launch_gemm(h, Wsrc[5] + (size_t)l * DF, ubf, T_LEN, F_DIM, D_DIM, 1.0f, 0, stream);
            launch_gemm(tmp, Bsrc[5] + (size_t)l * R_LORA * F_DIM, ubf, T_LEN, F_DIM, R_LORA, LORA_SCALE, 1, stream);
            silu_mul_kernel<<<(T_LEN * F_DIM + 255) / 256, 256, 0, stream>>>(gb, ubf, gb, T_LEN * F_DIM);
            launch_gemm(gb, Asrc[6] + (size_t)l * F_DIM * R_LORA, tmp, T_LEN, R_LORA, F_DIM, 1.0f, 0, stream);
            launch_gemm(gb, Wsrc[6] + (size_t)l * DF, x, T_LEN, D_DIM, F_DIM, 1.0f, 1, stream);
            launch_gemm(tmp, Bsrc[6] + (size_t)l * R_LORA * D_DIM, x, T_LEN, D_DIM, R_LORA, LORA_SCALE, 1, stream);
        }
        head_kernel<<<T_LEN, 256, 0, stream>>>(x, lnf, E, packed, soft);
    }
    argmax_kernel<<<(T_LEN + 255) / 256, 256, 0, stream>>>(soft, (int*)d_out);
}

// Round 6
// 1083.436 us; speedup vs baseline: 11.3699x; 1.1347x over previous
//
#include <hip/hip_runtime.h>
#include <hip/hip_bf16.h>

#define T_LEN 1024
#define D_DIM 1024
#define V_DIM 17
#define H_NUM 16
#define DH_DIM 64
#define F_DIM 4096
#define R_LORA 32
#define N_LAYERS 2
#define N_STEPS 2
#define MASK_ID 16
#define LORA_SCALE 2.0f

typedef __attribute__((ext_vector_type(8))) short bfx8;   // 8 bf16 in 4 VGPRs
typedef __attribute__((ext_vector_type(4))) float f32x4;

typedef unsigned short ushort_t;
typedef unsigned int uint_t;

#define AS1 __attribute__((address_space(1)))
#define AS3 __attribute__((address_space(3)))

__device__ __forceinline__ void gload16(const ushort_t* g, ushort_t* l) {
    __builtin_amdgcn_global_load_lds((const AS1 void*)(const void*)g,
                                     (AS3 void*)(void*)l, 16, 0, 0);
}

__device__ __forceinline__ ushort_t f2bf(float v) {
    __hip_bfloat16 h = __float2bfloat16(v);
    return __builtin_bit_cast(unsigned short, h);
}
__device__ __forceinline__ float bf2f(ushort_t u) {
    return __uint_as_float(((uint_t)u) << 16);
}
__device__ __forceinline__ void split4_store(float y0, float y1, float y2, float y3,
                                             ushort_t* __restrict__ hi, ushort_t* __restrict__ lo,
                                             size_t idx) {
    ushort_t h0 = f2bf(y0), h1 = f2bf(y1), h2 = f2bf(y2), h3 = f2bf(y3);
    ushort_t l0 = f2bf(y0 - bf2f(h0));
    ushort_t l1 = f2bf(y1 - bf2f(h1));
    ushort_t l2 = f2bf(y2 - bf2f(h2));
    ushort_t l3 = f2bf(y3 - bf2f(h3));
    uint2 hv, lv;
    hv.x = (uint_t)h0 | ((uint_t)h1 << 16);
    hv.y = (uint_t)h2 | ((uint_t)h3 << 16);
    lv.x = (uint_t)l0 | ((uint_t)l1 << 16);
    lv.y = (uint_t)l2 | ((uint_t)l3 << 16);
    *(uint2*)(hi + idx) = hv;
    *(uint2*)(lo + idx) = lv;
}

// ---------------- init soft ----------------
__global__ void init_soft_kernel(float* __restrict__ soft) {
    int idx = blockIdx.x * blockDim.x + threadIdx.x;
    if (idx < T_LEN * V_DIM) {
        soft[idx] = ((idx % V_DIM) == MASK_ID) ? 1.0f : 0.0f;
    }
}

// ---------------- fused embed + rms + split: x = soft@E; h = split(rms(x,w)) ----------------
__global__ __launch_bounds__(256) void embed_rms_split_kernel(
    const float* __restrict__ soft, const float* __restrict__ E,
    const float* __restrict__ w, float* __restrict__ x,
    ushort_t* __restrict__ hi, ushort_t* __restrict__ lo)
{
    const int t = blockIdx.x, tid = threadIdx.x;
    __shared__ float srow[V_DIM];
    __shared__ float red[4];
    if (tid < V_DIM) srow[tid] = soft[t * V_DIM + tid];
    __syncthreads();
    const int d0 = tid * 4;
    float4 acc = {0.f, 0.f, 0.f, 0.f};
    #pragma unroll
    for (int v = 0; v < V_DIM; v++) {
        float s = srow[v];
        float4 e = *(const float4*)(E + (size_t)v * D_DIM + d0);
        acc.x = fmaf(s, e.x, acc.x);
        acc.y = fmaf(s, e.y, acc.y);
        acc.z = fmaf(s, e.z, acc.z);
        acc.w = fmaf(s, e.w, acc.w);
    }
    size_t base = (size_t)t * D_DIM + d0;
    *(float4*)(x + base) = acc;
    float ss = acc.x * acc.x + acc.y * acc.y + acc.z * acc.z + acc.w * acc.w;
    const int lane = tid & 63, wv = tid >> 6;
    #pragma unroll
    for (int off = 32; off > 0; off >>= 1) ss += __shfl_xor(ss, off);
    if (lane == 0) red[wv] = ss;
    __syncthreads();
    ss = red[0] + red[1] + red[2] + red[3];
    const float r = 1.0f / sqrtf(ss * (1.0f / D_DIM) + 1e-6f);
    const float4 wv4 = *(const float4*)(w + d0);
    split4_store(acc.x * r * wv4.x, acc.y * r * wv4.y, acc.z * r * wv4.z, acc.w * r * wv4.w,
                 hi, lo, base);
}

// ---------------- fold v3: out^T = split(W + 2*A@B), latency-optimized ----------------
__global__ __launch_bounds__(256) void fold_kernel(
    const float* __restrict__ W,   // [L,K,N]
    const float* __restrict__ A,   // [L,K,R]
    const float* __restrict__ Bm,  // [L,R,N]
    ushort_t* __restrict__ oHi,    // [L,N,K]
    ushort_t* __restrict__ oLo,
    int K, int N)
{
    const int l = blockIdx.z;
    W   += (size_t)l * K * N;
    A   += (size_t)l * K * R_LORA;
    Bm  += (size_t)l * R_LORA * N;
    oHi += (size_t)l * K * N;
    oLo += (size_t)l * K * N;
    __shared__ float Als[64][R_LORA + 1];
    __shared__ uint_t tile[64][65];
    const int tid = threadIdx.x;
    const int n0 = blockIdx.x * 64, k0 = blockIdx.y * 64;

    {   // stage A tile [64 k][32 r]; scalar writes (pad+1 -> 2-way max)
        const int row = tid >> 2, c0 = (tid & 3) * 8;
        const float* src = A + (size_t)(k0 + row) * R_LORA + c0;
        float4 a0 = *(const float4*)(src);
        float4 a1 = *(const float4*)(src + 4);
        Als[row][c0 + 0] = a0.x; Als[row][c0 + 1] = a0.y;
        Als[row][c0 + 2] = a0.z; Als[row][c0 + 3] = a0.w;
        Als[row][c0 + 4] = a1.x; Als[row][c0 + 5] = a1.y;
        Als[row][c0 + 6] = a1.z; Als[row][c0 + 7] = a1.w;
    }
    const int nl = tid & 63, kq = tid >> 6;
    float wreg[16];
    #pragma unroll
    for (int i = 0; i < 16; i++)
        wreg[i] = W[(size_t)(k0 + kq * 16 + i) * N + n0 + nl];
    float breg[R_LORA];
    #pragma unroll
    for (int r = 0; r < R_LORA; r++) breg[r] = Bm[(size_t)r * N + n0 + nl];
    __syncthreads();
    #pragma unroll
    for (int i = 0; i < 16; i++) {
        const int kl = kq * 16 + i;
        float acc = 0.f;
        #pragma unroll
        for (int r = 0; r < R_LORA; r++) acc = fmaf(Als[kl][r], breg[r], acc);
        float val = wreg[i] + LORA_SCALE * acc;
        ushort_t h = f2bf(val);
        tile[kl][nl] = ((uint_t)h << 16) | (uint_t)f2bf(val - bf2f(h));
    }
    __syncthreads();
    {   // transposed vectorized store
        const int nl2 = tid >> 2;
        const int kc0 = (tid & 3) * 16;
        ushort_t hb[16], lb[16];
        #pragma unroll
        for (int i = 0; i < 16; i++) {
            uint_t pk = tile[kc0 + i][nl2];
            hb[i] = (ushort_t)(pk >> 16);
            lb[i] = (ushort_t)(pk & 0xffffu);
        }
        size_t idx = (size_t)(n0 + nl2) * K + k0 + kc0;
        *(uint4*)(oHi + idx)     = *(uint4*)&hb[0];
        *(uint4*)(oHi + idx + 8) = *(uint4*)&hb[8];
        *(uint4*)(oLo + idx)     = *(uint4*)&lb[0];
        *(uint4*)(oLo + idx + 8) = *(uint4*)&lb[8];
    }
}

// ---------------- 128x128 MFMA split-bf16 GEMM (m97-structure), up to 8 jobs ----------------
struct GemmJob {
    const ushort_t* Bh;
    const ushort_t* Bl;
    float* Cf;        // if non-null: f32 plain store
    ushort_t* Ch;     // else split store
    ushort_t* Cl;
    int k0, k1;
};

__global__ __launch_bounds__(256) void gemm128_kernel(
    const ushort_t* __restrict__ Ahi, const ushort_t* __restrict__ Alo,
    int K, int N,
    GemmJob j0, GemmJob j1, GemmJob j2, GemmJob j3,
    GemmJob j4, GemmJob j5, GemmJob j6, GemmJob j7)
{
    GemmJob jb;
    {
        const int z = blockIdx.z;
        if      (z == 0) jb = j0; else if (z == 1) jb = j1;
        else if (z == 2) jb = j2; else if (z == 3) jb = j3;
        else if (z == 4) jb = j4; else if (z == 5) jb = j5;
        else if (z == 6) jb = j6; else jb = j7;
    }
    __shared__ ushort_t Ash[128][32];
    __shared__ ushort_t Asl[128][32];
    __shared__ ushort_t Bsh[128][32];
    __shared__ ushort_t Bsl[128][32];

    const int tid = threadIdx.x, lane = tid & 63, w = tid >> 6;
    const int l15 = lane & 15, lg = lane >> 4;
    const int m0 = blockIdx.y * 128, n0 = blockIdx.x * 128;
    const int wm = (w >> 1) * 64, wn = (w & 1) * 64;

    const int r0 = w * 32;
    const int rsub = lane >> 2;
    const int cs = lane & 3;
    const int csl = (cs ^ ((rsub >> 1) & 3)) * 8;   // pre-swizzled source col (shorts)
    const int rsl = (lg ^ ((l15 >> 1) & 3)) * 8;    // swizzled read col (shorts)

    f32x4 acc[4][4];
    #pragma unroll
    for (int i = 0; i < 4; i++)
        #pragma unroll
        for (int j = 0; j < 4; j++) acc[i][j] = f32x4{0.f, 0.f, 0.f, 0.f};

    const size_t rowA = (size_t)(m0 + r0 + rsub) * K;
    const size_t rowB = (size_t)(n0 + r0 + rsub) * K;
    const size_t rstep = (size_t)16 * K;

    for (int kk = jb.k0; kk < jb.k1; kk += 32) {
        {
            const ushort_t* a0 = Ahi + rowA + kk + csl;
            const ushort_t* a1 = Alo + rowA + kk + csl;
            const ushort_t* b0 = jb.Bh + rowB + kk + csl;
            const ushort_t* b1 = jb.Bl + rowB + kk + csl;
            gload16(a0,         &Ash[r0][0]);
            gload16(a0 + rstep, &Ash[r0 + 16][0]);
            gload16(a1,         &Asl[r0][0]);
            gload16(a1 + rstep, &Asl[r0 + 16][0]);
            gload16(b0,         &Bsh[r0][0]);
            gload16(b0 + rstep, &Bsh[r0 + 16][0]);
            gload16(b1,         &Bsl[r0][0]);
            gload16(b1 + rstep, &Bsl[r0 + 16][0]);
        }
        __syncthreads();   // drains vmcnt: staged data visible to all waves
        bfx8 bh[4], bl[4];
        #pragma unroll
        for (int ni = 0; ni < 4; ni++) {
            bh[ni] = *(const bfx8*)&Bsh[wn + ni * 16 + l15][rsl];
            bl[ni] = *(const bfx8*)&Bsl[wn + ni * 16 + l15][rsl];
        }
        #pragma unroll
        for (int mi = 0; mi < 4; mi++) {
            bfx8 ah = *(const bfx8*)&Ash[wm + mi * 16 + l15][rsl];
            bfx8 al = *(const bfx8*)&Asl[wm + mi * 16 + l15][rsl];
            #pragma unroll
            for (int ni = 0; ni < 4; ni++) {
                acc[mi][ni] = __builtin_amdgcn_mfma_f32_16x16x32_bf16(ah, bh[ni], acc[mi][ni], 0, 0, 0);
                acc[mi][ni] = __builtin_amdgcn_mfma_f32_16x16x32_bf16(ah, bl[ni], acc[mi][ni], 0, 0, 0);
                acc[mi][ni] = __builtin_amdgcn_mfma_f32_16x16x32_bf16(al, bh[ni], acc[mi][ni], 0, 0, 0);
            }
        }
        __syncthreads();   // all reads done before next stage overwrites
    }

    if (jb.Cf) {
        #pragma unroll
        for (int mi = 0; mi < 4; mi++)
            #pragma unroll
            for (int ni = 0; ni < 4; ni++) {
                int col = n0 + wn + ni * 16 + l15;
                #pragma unroll
                for (int i = 0; i < 4; i++) {
                    int row = m0 + wm + mi * 16 + lg * 4 + i;
                    jb.Cf[(size_t)row * N + col] = acc[mi][ni][i];
                }
            }
    } else {
        #pragma unroll
        for (int mi = 0; mi < 4; mi++)
            #pragma unroll
            for (int ni = 0; ni < 4; ni++) {
                int col = n0 + wn + ni * 16 + l15;
                #pragma unroll
                for (int i = 0; i < 4; i++) {
                    int row = m0 + wm + mi * 16 + lg * 4 + i;
                    size_t idx = (size_t)row * N + col;
                    float v = acc[mi][ni][i];
                    ushort_t h = f2bf(v);
                    jb.Ch[idx] = h;
                    jb.Cl[idx] = f2bf(v - bf2f(h));
                }
            }
    }
}

// ---------------- qkv epilogue: q/k/v = split(partial0+partial1) ----------------
__global__ __launch_bounds__(256) void qkv2_split_kernel(
    const float* __restrict__ pb,
    ushort_t* __restrict__ qbh, ushort_t* __restrict__ qbl,
    ushort_t* __restrict__ kbh, ushort_t* __restrict__ kbl,
    ushort_t* __restrict__ vbh, ushort_t* __restrict__ vbl)
{
    const size_t DD1 = (size_t)T_LEN * D_DIM;
    size_t e = ((size_t)blockIdx.x * 256 + threadIdx.x) * 4;
    float4 a, b;
    a = *(const float4*)(pb + e);
    b = *(const float4*)(pb + DD1 + e);
    split4_store(a.x + b.x, a.y + b.y, a.z + b.z, a.w + b.w, qbh, qbl, e);
    a = *(const float4*)(pb + 2 * DD1 + e);
    b = *(const float4*)(pb + 3 * DD1 + e);
    split4_store(a.x + b.x, a.y + b.y, a.z + b.z, a.w + b.w, kbh, kbl, e);
    a = *(const float4*)(pb + 4 * DD1 + e);
    b = *(const float4*)(pb + 5 * DD1 + e);
    split4_store(a.x + b.x, a.y + b.y, a.z + b.z, a.w + b.w, vbh, vbl, e);
}

// ---------------- x += sum of 8 contiguous partials ----------------
__global__ void add8_kernel(float* __restrict__ x, const float* __restrict__ pb, int n4) {
    int i = blockIdx.x * blockDim.x + threadIdx.x;
    if (i < n4) {
        const size_t DD1 = (size_t)T_LEN * D_DIM;
        size_t e = (size_t)i * 4;
        float4 xv = *(const float4*)(x + e);
        #pragma unroll
        for (int j = 0; j < 8; j++) {
            float4 p = *(const float4*)(pb + j * DD1 + e);
            xv.x += p.x; xv.y += p.y; xv.z += p.z; xv.w += p.w;
        }
        *(float4*)(x + e) = xv;
    }
}

// ---------------- fused: x += sum8; h = split(rms(x,w)) ----------------
__global__ __launch_bounds__(256) void add8_rms_split_kernel(
    float* __restrict__ x, const float* __restrict__ pb,
    const float* __restrict__ w, ushort_t* __restrict__ hi, ushort_t* __restrict__ lo)
{
    const int t = blockIdx.x, tid = threadIdx.x;
    const size_t DD1 = (size_t)T_LEN * D_DIM;
    size_t base = (size_t)t * D_DIM + tid * 4;
    float4 xv = *(const float4*)(x + base);
    #pragma unroll
    for (int j = 0; j < 8; j++) {
        float4 p = *(const float4*)(pb + j * DD1 + base);
        xv.x += p.x; xv.y += p.y; xv.z += p.z; xv.w += p.w;
    }
    *(float4*)(x + base) = xv;
    float ss = xv.x * xv.x + xv.y * xv.y + xv.z * xv.z + xv.w * xv.w;
    __shared__ float red[4];
    const int lane = tid & 63, wv = tid >> 6;
    #pragma unroll
    for (int off = 32; off > 0; off >>= 1) ss += __shfl_xor(ss, off);
    if (lane == 0) red[wv] = ss;
    __syncthreads();
    ss = red[0] + red[1] + red[2] + red[3];
    const float r = 1.0f / sqrtf(ss * (1.0f / D_DIM) + 1e-6f);
    const float4 wv4 = *(const float4*)(w + tid * 4);
    split4_store(xv.x * r * wv4.x, xv.y * r * wv4.y, xv.z * r * wv4.z, xv.w * r * wv4.w,
                 hi, lo, base);
}

// ---------------- MFMA flash attention ----------------
#define KS_PAD 72
#define P_PAD 72
__global__ __launch_bounds__(256, 1) void attn_mfma_kernel(
    const ushort_t* __restrict__ qh, const ushort_t* __restrict__ ql,
    const ushort_t* __restrict__ kh, const ushort_t* __restrict__ kl,
    const ushort_t* __restrict__ vh, const ushort_t* __restrict__ vl,
    ushort_t* __restrict__ chi, ushort_t* __restrict__ clo)
{
    __shared__ ushort_t Ksh[64][KS_PAD];
    __shared__ ushort_t Ksl[64][KS_PAD];
    __shared__ ushort_t VTh[64][KS_PAD];   // transposed V: [d][k]
    __shared__ ushort_t VTl[64][KS_PAD];
    __shared__ ushort_t Ph[4][16][P_PAD];  // per-wave P strips
    __shared__ ushort_t Pl[4][16][P_PAD];

    const int qt = blockIdx.x, hh = blockIdx.y;
    const int tid = threadIdx.x, w = tid >> 6, lane = tid & 63;
    const int l15 = lane & 15, lg = lane >> 4;
    const int q0 = qt * 64;
    const int hcol = hh * DH_DIM;

    bfx8 qa_h[2], qa_l[2];
    {
        size_t qrow = (size_t)(q0 + w * 16 + l15) * D_DIM + hcol;
        #pragma unroll
        for (int ks = 0; ks < 2; ks++) {
            qa_h[ks] = *(const bfx8*)(qh + qrow + ks * 32 + lg * 8);
            qa_l[ks] = *(const bfx8*)(ql + qrow + ks * 32 + lg * 8);
        }
    }

    f32x4 o[4];
    #pragma unroll
    for (int ni = 0; ni < 4; ni++) o[ni] = f32x4{0.f, 0.f, 0.f, 0.f};
    float mrun[4], lrun[4];
    #pragma unroll
    for (int i = 0; i < 4; i++) { mrun[i] = -3.0e38f; lrun[i] = 0.f; }

    const int srow = tid >> 2;
    const int sseg = (tid & 3) * 16;
    const int vp = tid & 31;
    const int vd0 = (tid >> 5) * 8;

    for (int kt = 0; kt <= qt; kt++) {
        __syncthreads();
        {
            size_t src = (size_t)(kt * 64 + srow) * D_DIM + hcol + sseg;
            *(uint4*)&Ksh[srow][sseg]     = *(const uint4*)(kh + src);
            *(uint4*)&Ksh[srow][sseg + 8] = *(const uint4*)(kh + src + 8);
            *(uint4*)&Ksl[srow][sseg]     = *(const uint4*)(kl + src);
            *(uint4*)&Ksl[srow][sseg + 8] = *(const uint4*)(kl + src + 8);
        }
        {
            size_t s0 = (size_t)(kt * 64 + 2 * vp) * D_DIM + hcol + vd0;
            uint4 h0 = *(const uint4*)(vh + s0);
            uint4 h1 = *(const uint4*)(vh + s0 + D_DIM);
            uint4 l0 = *(const uint4*)(vl + s0);
            uint4 l1 = *(const uint4*)(vl + s0 + D_DIM);
            const ushort_t* a = (const ushort_t*)&h0;
            const ushort_t* b = (const ushort_t*)&h1;
            const ushort_t* c = (const ushort_t*)&l0;
            const ushort_t* d = (const ushort_t*)&l1;
            #pragma unroll
            for (int j = 0; j < 8; j++) {
                *(uint_t*)&VTh[vd0 + j][2 * vp] = (uint_t)a[j] | ((uint_t)b[j] << 16);
                *(uint_t*)&VTl[vd0 + j][2 * vp] = (uint_t)c[j] | ((uint_t)d[j] << 16);
            }
        }
        __syncthreads();

        f32x4 s[4];
        #pragma unroll
        for (int ni = 0; ni < 4; ni++) s[ni] = f32x4{0.f, 0.f, 0.f, 0.f};
        #pragma unroll
        for (int ks = 0; ks < 2; ks++) {
            #pragma unroll
            for (int ni = 0; ni < 4; ni++) {
                bfx8 bh = *(const bfx8*)&Ksh[ni * 16 + l15][ks * 32 + lg * 8];
                bfx8 bl = *(const bfx8*)&Ksl[ni * 16 + l15][ks * 32 + lg * 8];
                s[ni] = __builtin_amdgcn_mfma_f32_16x16x32_bf16(qa_h[ks], bh, s[ni], 0, 0, 0);
                s[ni] = __builtin_amdgcn_mfma_f32_16x16x32_bf16(qa_h[ks], bl, s[ni], 0, 0, 0);
                s[ni] = __builtin_amdgcn_mfma_f32_16x16x32_bf16(qa_l[ks], bh, s[ni], 0, 0, 0);
            }
        }

        const int kbase = kt * 64;
        float rmax[4];
        #pragma unroll
        for (int i = 0; i < 4; i++) rmax[i] = -3.0e38f;
        #pragma unroll
        for (int ni = 0; ni < 4; ni++) {
            int kc = kbase + ni * 16 + l15;
            #pragma unroll
            for (int i = 0; i < 4; i++) {
                int qrow = q0 + w * 16 + lg * 4 + i;
                float v = s[ni][i] * 0.125f;
                v = (kc <= qrow) ? v : -3.0e38f;
                s[ni][i] = v;
                rmax[i] = fmaxf(rmax[i], v);
            }
        }
        #pragma unroll
        for (int off = 1; off < 16; off <<= 1) {
            #pragma unroll
            for (int i = 0; i < 4; i++) rmax[i] = fmaxf(rmax[i], __shfl_xor(rmax[i], off));
        }
        float psum[4];
        #pragma unroll
        for (int i = 0; i < 4; i++) {
            float nm = fmaxf(mrun[i], rmax[i]);
            float sc = __expf(mrun[i] - nm);
            lrun[i] *= sc;
            #pragma unroll
            for (int ni = 0; ni < 4; ni++) o[ni][i] *= sc;
            mrun[i] = nm;
            psum[i] = 0.f;
        }
        #pragma unroll
        for (int ni = 0; ni < 4; ni++) {
            #pragma unroll
            for (int i = 0; i < 4; i++) {
                float e = __expf(s[ni][i] - mrun[i]);
                s[ni][i] = e;
                psum[i] += e;
            }
        }
        #pragma unroll
        for (int off = 1; off < 16; off <<= 1) {
            #pragma unroll
            for (int i = 0; i < 4; i++) psum[i] += __shfl_xor(psum[i], off);
        }
        #pragma unroll
        for (int i = 0; i < 4; i++) lrun[i] += psum[i];

        #pragma unroll
        for (int ni = 0; ni < 4; ni++) {
            #pragma unroll
            for (int i = 0; i < 4; i++) {
                float e = s[ni][i];
                ushort_t hp = f2bf(e);
                Ph[w][lg * 4 + i][ni * 16 + l15] = hp;
                Pl[w][lg * 4 + i][ni * 16 + l15] = f2bf(e - bf2f(hp));
            }
        }
        #pragma unroll
        for (int ks = 0; ks < 2; ks++) {
            bfx8 ah = *(const bfx8*)&Ph[w][l15][ks * 32 + lg * 8];
            bfx8 al = *(const bfx8*)&Pl[w][l15][ks * 32 + lg * 8];
            #pragma unroll
            for (int ni = 0; ni < 4; ni++) {
                bfx8 bh = *(const bfx8*)&VTh[ni * 16 + l15][ks * 32 + lg * 8];
                bfx8 bl = *(const bfx8*)&VTl[ni * 16 + l15][ks * 32 + lg * 8];
                o[ni] = __builtin_amdgcn_mfma_f32_16x16x32_bf16(ah, bh, o[ni], 0, 0, 0);
                o[ni] = __builtin_amdgcn_mfma_f32_16x16x32_bf16(ah, bl, o[ni], 0, 0, 0);
                o[ni] = __builtin_amdgcn_mfma_f32_16x16x32_bf16(al, bh, o[ni], 0, 0, 0);
            }
        }
    }

    #pragma unroll
    for (int i = 0; i < 4; i++) {
        float inv = 1.0f / lrun[i];
        #pragma unroll
        for (int ni = 0; ni < 4; ni++) o[ni][i] *= inv;
    }
    #pragma unroll
    for (int ni = 0; ni < 4; ni++) {
        int col = hcol + ni * 16 + l15;
        #pragma unroll
        for (int i = 0; i < 4; i++) {
            int row = q0 + w * 16 + lg * 4 + i;
            size_t idx = (size_t)row * D_DIM + col;
            float v = o[ni][i];
            ushort_t hp = f2bf(v);
            chi[idx] = hp;
            clo[idx] = f2bf(v - bf2f(hp));
        }
    }
}

// ---------------- silu(g)*u -> split ----------------
__global__ void silu_split_kernel(const float* __restrict__ g, const float* __restrict__ u,
                                  ushort_t* __restrict__ hi, ushort_t* __restrict__ lo, int n4) {
    int i = blockIdx.x * blockDim.x + threadIdx.x;
    if (i < n4) {
        float4 gv = *(const float4*)(g + (size_t)i * 4);
        float4 uv = *(const float4*)(u + (size_t)i * 4);
        float y0 = gv.x / (1.f + expf(-gv.x)) * uv.x;
        float y1 = gv.y / (1.f + expf(-gv.y)) * uv.y;
        float y2 = gv.z / (1.f + expf(-gv.z)) * uv.z;
        float y3 = gv.w / (1.f + expf(-gv.w)) * uv.w;
        split4_store(y0, y1, y2, y3, hi, lo, (size_t)i * 4);
    }
}

// ---------------- head ----------------
__global__ __launch_bounds__(256) void head_kernel(const float* __restrict__ x,
                                                   const float* __restrict__ lnf,
                                                   const float* __restrict__ E,
                                                   const int* __restrict__ tok,
                                                   float* __restrict__ soft) {
    int t = blockIdx.x;
    int tid = threadIdx.x;
    __shared__ float y[D_DIM];
    __shared__ float red[4];
    __shared__ float logits[V_DIM];
    const float* xr = x + (size_t)t * D_DIM;
    float ss = 0.f;
    for (int d = tid; d < D_DIM; d += 256) { float v = xr[d]; ss += v * v; }
    int lane = tid & 63, wave = tid >> 6;
    for (int off = 32; off > 0; off >>= 1) ss += __shfl_xor(ss, off);
    if (lane == 0) red[wave] = ss;
    __syncthreads();
    ss = red[0] + red[1] + red[2] + red[3];
    float r = 1.0f / sqrtf(ss * (1.0f / D_DIM) + 1e-6f);
    for (int d = tid; d < D_DIM; d += 256) y[d] = xr[d] * r * lnf[d];
    __syncthreads();
    for (int vv = wave; vv < V_DIM; vv += 4) {
        float p = 0.f;
        for (int d = lane; d < D_DIM; d += 64) p += y[d] * E[vv * D_DIM + d];
        for (int off = 32; off > 0; off >>= 1) p += __shfl_xor(p, off);
        if (lane == 0) logits[vv] = p;
    }
    __syncthreads();
    if (tid == 0) {
        int tk = tok[t];
        if (tk != MASK_ID) {
            for (int vv = 0; vv < V_DIM; vv++) soft[t * V_DIM + vv] = (vv == tk) ? 1.f : 0.f;
        } else {
            float mx = -1e30f;
            for (int vv = 0; vv < V_DIM; vv++) mx = fmaxf(mx, logits[vv]);
            float sm = 0.f;
            float e[V_DIM];
            for (int vv = 0; vv < V_DIM; vv++) { e[vv] = expf(logits[vv] - mx); sm += e[vv]; }
            float invs = 1.0f / sm;
            for (int vv = 0; vv < V_DIM; vv++) soft[t * V_DIM + vv] = e[vv] * invs;
        }
    }
}

// ---------------- argmax ----------------
__global__ void argmax_kernel(const float* __restrict__ soft, int* __restrict__ out) {
    int t = blockIdx.x * blockDim.x + threadIdx.x;
    if (t < T_LEN) {
        const float* s = soft + t * V_DIM;
        int best = 0;
        float bv = s[0];
        #pragma unroll
        for (int vv = 1; vv < V_DIM; vv++) {
            float v = s[vv];
            if (v > bv) { bv = v; best = vv; }
        }
        out[t] = best;
    }
}

// ================= fallback kernels (fp32, if ws too small) =================
__global__ __launch_bounds__(256) void rms_kernel(const float* __restrict__ x,
                                                  const float* __restrict__ w,
                                                  float* __restrict__ out) {
    int t = blockIdx.x;
    const float* xr = x + (size_t)t * D_DIM;
    float ss = 0.f;
    for (int d = threadIdx.x; d < D_DIM; d += 256) { float v = xr[d]; ss += v * v; }
    __shared__ float red[4];
    int lane = threadIdx.x & 63, wave = threadIdx.x >> 6;
    for (int off = 32; off > 0; off >>= 1) ss += __shfl_xor(ss, off);
    if (lane == 0) red[wave] = ss;
    __syncthreads();
    ss = red[0] + red[1] + red[2] + red[3];
    float r = 1.0f / sqrtf(ss * (1.0f / D_DIM) + 1e-6f);
    for (int d = threadIdx.x; d < D_DIM; d += 256) out[(size_t)t * D_DIM + d] = xr[d] * r * w[d];
}

__global__ __launch_bounds__(256) void embed_kernel(const float* __restrict__ soft,
                                                    const float* __restrict__ E,
                                                    float* __restrict__ x) {
    int t = blockIdx.x;
    __shared__ float srow[V_DIM];
    if (threadIdx.x < V_DIM) srow[threadIdx.x] = soft[t * V_DIM + threadIdx.x];
    __syncthreads();
    for (int d = threadIdx.x; d < D_DIM; d += 256) {
        float acc = 0.f;
        #pragma unroll
        for (int v = 0; v < V_DIM; v++) acc += srow[v] * E[v * D_DIM + d];
        x[(size_t)t * D_DIM + d] = acc;
    }
}

__global__ __launch_bounds__(256) void gemm_kernel(const float* __restrict__ A,
                                                   const float* __restrict__ B,
                                                   float* __restrict__ C,
                                                   int M, int N, int K,
                                                   float alpha, int accumulate) {
    const int BM = 64, BN = 64, BK = 16;
    __shared__ float As[BK][BM];
    __shared__ float Bsh[BK][BN];
    int tid = threadIdx.x;
    int tx = tid % 16, ty = tid / 16;
    int row0 = blockIdx.y * BM, col0 = blockIdx.x * BN;
    float acc[4][4] = {};
    for (int k0 = 0; k0 < K; k0 += BK) {
        #pragma unroll
        for (int i = 0; i < 4; i++) {
            int e = tid * 4 + i;
            int m = e / BK, kk = e % BK;
            int gr = row0 + m, gk = k0 + kk;
            As[kk][m] = (gr < M && gk < K) ? A[(size_t)gr * K + gk] : 0.f;
        }
        #pragma unroll
        for (int i = 0; i < 4; i++) {
            int e = tid * 4 + i;
            int kk = e / BN, n = e % BN;
            int gk = k0 + kk, gc = col0 + n;
            Bsh[kk][n] = (gk < K && gc < N) ? B[(size_t)gk * N + gc] : 0.f;
        }
        __syncthreads();
        #pragma unroll
        for (int kk = 0; kk < BK; kk++) {
            float a[4], b[4];
            #pragma unroll
            for (int i = 0; i < 4; i++) a[i] = As[kk][ty * 4 + i];
            #pragma unroll
            for (int j = 0; j < 4; j++) b[j] = Bsh[kk][tx * 4 + j];
            #pragma unroll
            for (int i = 0; i < 4; i++)
                #pragma unroll
                for (int j = 0; j < 4; j++)
                    acc[i][j] += a[i] * b[j];
        }
        __syncthreads();
    }
    #pragma unroll
    for (int i = 0; i < 4; i++) {
        int r = row0 + ty * 4 + i;
        if (r >= M) continue;
        #pragma unroll
        for (int j = 0; j < 4; j++) {
            int c = col0 + tx * 4 + j;
            if (c >= N) continue;
            size_t idx = (size_t)r * N + c;
            float val = alpha * acc[i][j];
            if (accumulate) val += C[idx];
            C[idx] = val;
        }
    }
}

__global__ __launch_bounds__(256) void attn_kernel(const float* __restrict__ q,
                                                   const float* __restrict__ k,
                                                   const float* __restrict__ v,
                                                   float* __restrict__ ctx) {
    int qi = blockIdx.x;
    int hh = blockIdx.y;
    __shared__ float sc[T_LEN];
    __shared__ float qrow[DH_DIM];
    __shared__ float red[8];
    __shared__ float part[4][DH_DIM];
    int tid = threadIdx.x;
    int lane = tid & 63, wave = tid >> 6;
    const float* qp = q + (size_t)qi * D_DIM + hh * DH_DIM;
    if (tid < DH_DIM) qrow[tid] = qp[tid];
    __syncthreads();
    const float scale = 0.125f;
    for (int j = wave; j <= qi; j += 4) {
        const float* kp = k + (size_t)j * D_DIM + hh * DH_DIM;
        float p = qrow[lane] * kp[lane];
        for (int off = 32; off > 0; off >>= 1) p += __shfl_xor(p, off);
        if (lane == 0) sc[j] = p * scale;
    }
    __syncthreads();
    int n = qi + 1;
    float m = -1e30f;
    for (int j = tid; j < n; j += 256) m = fmaxf(m, sc[j]);
    for (int off = 32; off > 0; off >>= 1) m = fmaxf(m, __shfl_xor(m, off));
    if (lane == 0) red[wave] = m;
    __syncthreads();
    m = fmaxf(fmaxf(red[0], red[1]), fmaxf(red[2], red[3]));
    float s = 0.f;
    for (int j = tid; j < n; j += 256) { float e = expf(sc[j] - m); sc[j] = e; s += e; }
    for (int off = 32; off > 0; off >>= 1) s += __shfl_xor(s, off);
    if (lane == 0) red[4 + wave] = s;
    __syncthreads();
    s = red[4] + red[5] + red[6] + red[7];
    float inv = 1.0f / s;
    float acc = 0.f;
    for (int j = wave; j < n; j += 4) {
        acc += sc[j] * v[(size_t)j * D_DIM + hh * DH_DIM + lane];
    }
    part[wave][lane] = acc;
    __syncthreads();
    if (tid < DH_DIM) {
        float r = (part[0][tid] + part[1][tid] + part[2][tid] + part[3][tid]) * inv;
        ctx[(size_t)qi * D_DIM + hh * DH_DIM + tid] = r;
    }
}

__global__ void silu_mul_kernel(const float* __restrict__ g, const float* __restrict__ u,
                                float* __restrict__ out, int nelem) {
    int i = blockIdx.x * blockDim.x + threadIdx.x;
    if (i < nelem) {
        float gv = g[i];
        float sg = 1.0f / (1.0f + expf(-gv));
        out[i] = gv * sg * u[i];
    }
}

static inline void launch_gemm(const float* A, const float* B, float* C,
                               int M, int N, int K, float alpha, int accumulate,
                               hipStream_t stream) {
    dim3 grid((N + 63) / 64, (M + 63) / 64);
    gemm_kernel<<<grid, 256, 0, stream>>>(A, B, C, M, N, K, alpha, accumulate);
}

// =====================================================================================
extern "C" void kernel_launch(void* const* d_in, const int* in_sizes, int n_in,
                              void* d_out, int out_size, void* d_ws, size_t ws_size,
                              hipStream_t stream) {
    const int* packed = (const int*)d_in[0];
    const float* E  = (const float*)d_in[6];
    const float* Wsrc[7] = {(const float*)d_in[7],  (const float*)d_in[10], (const float*)d_in[13],
                            (const float*)d_in[16], (const float*)d_in[19], (const float*)d_in[22],
                            (const float*)d_in[25]};
    const float* Asrc[7] = {(const float*)d_in[8],  (const float*)d_in[11], (const float*)d_in[14],
                            (const float*)d_in[17], (const float*)d_in[20], (const float*)d_in[23],
                            (const float*)d_in[26]};
    const float* Bsrc[7] = {(const float*)d_in[9],  (const float*)d_in[12], (const float*)d_in[15],
                            (const float*)d_in[18], (const float*)d_in[21], (const float*)d_in[24],
                            (const float*)d_in[27]};
    const float* ln1 = (const float*)d_in[28];
    const float* ln2 = (const float*)d_in[29];
    const float* lnf = (const float*)d_in[30];

    const size_t DD = (size_t)D_DIM * D_DIM;     // 1M
    const size_t DF = (size_t)D_DIM * F_DIM;     // 4M
    const size_t wsizes[7] = {DD, DD, DD, DD, DF, DF, DF};
    const int Kdim[7] = {D_DIM, D_DIM, D_DIM, D_DIM, D_DIM, D_DIM, F_DIM};
    const int Ndim[7] = {D_DIM, D_DIM, D_DIM, D_DIM, F_DIM, F_DIM, D_DIM};

    // fast-path workspace requirement (same layout as prior rounds)
    size_t u16_elems = 0;
    for (int p = 0; p < 7; p++) u16_elems += 2ull * N_LAYERS * wsizes[p];  // folded hi/lo
    u16_elems += 2ull * DD;            // h hi/lo
    u16_elems += 2ull * DD;            // ctx hi/lo
    u16_elems += 2ull * DF;            // ff hi/lo
    u16_elems += 6ull * DD;            // q,k,v hi/lo
    size_t f32_elems = (size_t)T_LEN * V_DIM + DD /*x*/ + 2 * DF /*g,u (partials alias)*/;
    size_t need = u16_elems * 2 + f32_elems * 4 + 256;

    if (ws_size >= need) {
        // -------- fast path --------
        ushort_t* ub = (ushort_t*)d_ws;
        size_t uo = 0;
        ushort_t *Whi[7], *Wlo[7];
        for (int p = 0; p < 7; p++) {
            Whi[p] = ub + uo; uo += (size_t)N_LAYERS * wsizes[p];
            Wlo[p] = ub + uo; uo += (size_t)N_LAYERS * wsizes[p];
        }
        ushort_t* h_hi = ub + uo; uo += DD;
        ushort_t* h_lo = ub + uo; uo += DD;
        ushort_t* c_hi = ub + uo; uo += DD;
        ushort_t* c_lo = ub + uo; uo += DD;
        ushort_t* f_hi = ub + uo; uo += DF;
        ushort_t* f_lo = ub + uo; uo += DF;
        ushort_t* qbh = ub + uo; uo += DD;
        ushort_t* qbl = ub + uo; uo += DD;
        ushort_t* kbh = ub + uo; uo += DD;
        ushort_t* kbl = ub + uo; uo += DD;
        ushort_t* vbh = ub + uo; uo += DD;
        ushort_t* vbl = ub + uo; uo += DD;
        float* fb = (float*)(ub + uo);
        size_t fo = 0;
        float* soft = fb + fo; fo += (size_t)T_LEN * V_DIM;
        float* x    = fb + fo; fo += DD;
        float* gbuf = fb + fo; fo += DF;
        float* ubuf = fb + fo; fo += DF;
        // contiguous 8-slot partial region = gbuf..gbuf+8*DD (spans gbuf+ubuf)
        float* pbase = gbuf;

        // fold weights (batched over layers)
        for (int p = 0; p < 7; p++) {
            dim3 grid(Ndim[p] / 64, Kdim[p] / 64, N_LAYERS);
            fold_kernel<<<grid, 256, 0, stream>>>(Wsrc[p], Asrc[p], Bsrc[p],
                                                  Whi[p], Wlo[p], Kdim[p], Ndim[p]);
        }

        init_soft_kernel<<<(T_LEN * V_DIM + 255) / 256, 256, 0, stream>>>(soft);

        const int n4 = (int)(DD / 4);
        for (int step = 0; step < N_STEPS; step++) {
            // x = soft@E ; h = split(rms(x, ln1[0]))
            embed_rms_split_kernel<<<T_LEN, 256, 0, stream>>>(soft, E, ln1, x, h_hi, h_lo);
            for (int l = 0; l < N_LAYERS; l++) {
                {   // fused QKV, split-K x2 (6 jobs -> 384 blocks)
                    GemmJob jq0 = {Whi[0] + l * DD, Wlo[0] + l * DD, pbase + 0 * DD, nullptr, nullptr, 0, 512};
                    GemmJob jq1 = {Whi[0] + l * DD, Wlo[0] + l * DD, pbase + 1 * DD, nullptr, nullptr, 512, 1024};
                    GemmJob jk0 = {Whi[1] + l * DD, Wlo[1] + l * DD, pbase + 2 * DD, nullptr, nullptr, 0, 512};
                    GemmJob jk1 = {Whi[1] + l * DD, Wlo[1] + l * DD, pbase + 3 * DD, nullptr, nullptr, 512, 1024};
                    GemmJob jv0 = {Whi[2] + l * DD, Wlo[2] + l * DD, pbase + 4 * DD, nullptr, nullptr, 0, 512};
                    GemmJob jv1 = {Whi[2] + l * DD, Wlo[2] + l * DD, pbase + 5 * DD, nullptr, nullptr, 512, 1024};
                    gemm128_kernel<<<dim3(8, 8, 6), 256, 0, stream>>>(
                        h_hi, h_lo, D_DIM, D_DIM, jq0, jq1, jk0, jk1, jv0, jv1, jq0, jq0);
                    qkv2_split_kernel<<<(int)(DD / 4 / 256), 256, 0, stream>>>(
                        pbase, qbh, qbl, kbh, kbl, vbh, vbl);
                }
                attn_mfma_kernel<<<dim3(T_LEN / 64, H_NUM), 256, 0, stream>>>(
                    qbh, qbl, kbh, kbl, vbh, vbl, c_hi, c_lo);
                {   // o-proj split-K x8 + fused add + rms(ln2[l]) -> h
                    const ushort_t* bh = Whi[3] + l * DD;
                    const ushort_t* bl = Wlo[3] + l * DD;
                    GemmJob j[8];
                    for (int i = 0; i < 8; i++)
                        j[i] = {bh, bl, pbase + i * DD, nullptr, nullptr, i * 128, (i + 1) * 128};
                    gemm128_kernel<<<dim3(8, 8, 8), 256, 0, stream>>>(
                        c_hi, c_lo, D_DIM, D_DIM, j[0], j[1], j[2], j[3], j[4], j[5], j[6], j[7]);
                    add8_rms_split_kernel<<<T_LEN, 256, 0, stream>>>(
                        x, pbase, ln2 + (size_t)l * D_DIM, h_hi, h_lo);
                }
                {   // fused G,U (512 blocks = 2/CU, at structure ceiling)
                    GemmJob jg = {Whi[4] + l * DF, Wlo[4] + l * DF, gbuf, nullptr, nullptr, 0, D_DIM};
                    GemmJob ju = {Whi[5] + l * DF, Wlo[5] + l * DF, ubuf, nullptr, nullptr, 0, D_DIM};
                    gemm128_kernel<<<dim3(32, 8, 2), 256, 0, stream>>>(
                        h_hi, h_lo, D_DIM, F_DIM, jg, ju, jg, jg, jg, jg, jg, jg);
                }
                silu_split_kernel<<<(T_LEN * F_DIM / 4 + 255) / 256, 256, 0, stream>>>(
                    gbuf, ubuf, f_hi, f_lo, T_LEN * F_DIM / 4);
                {   // d-proj split-K x8 (K=4096 -> 512/job, 512 blocks)
                    const ushort_t* bh = Whi[6] + l * DF;
                    const ushort_t* bl = Wlo[6] + l * DF;
                    GemmJob j[8];
                    for (int i = 0; i < 8; i++)
                        j[i] = {bh, bl, pbase + i * DD, nullptr, nullptr, i * 512, (i + 1) * 512};
                    gemm128_kernel<<<dim3(8, 8, 8), 256, 0, stream>>>(
                        f_hi, f_lo, F_DIM, D_DIM, j[0], j[1], j[2], j[3], j[4], j[5], j[6], j[7]);
                    if (l + 1 < N_LAYERS) {
                        add8_rms_split_kernel<<<T_LEN, 256, 0, stream>>>(
                            x, pbase, ln1 + (size_t)(l + 1) * D_DIM, h_hi, h_lo);
                    } else {
                        add8_kernel<<<(n4 + 255) / 256, 256, 0, stream>>>(x, pbase, n4);
                    }
                }
            }
            head_kernel<<<T_LEN, 256, 0, stream>>>(x, lnf, E, packed, soft);
        }
        argmax_kernel<<<(T_LEN + 255) / 256, 256, 0, stream>>>(soft, (int*)d_out);
        return;
    }

    // -------- fallback: fp32 path --------
    float* ws = (float*)d_ws;
    size_t off = 0;
    float* soft = ws + off; off += (size_t)T_LEN * V_DIM;
    float* x    = ws + off; off += (size_t)T_LEN * D_DIM;
    float* h    = ws + off; off += (size_t)T_LEN * D_DIM;
    float* qb   = ws + off; off += (size_t)T_LEN * D_DIM;
    float* kb   = ws + off; off += (size_t)T_LEN * D_DIM;
    float* vb   = ws + off; off += (size_t)T_LEN * D_DIM;
    float* cb   = ws + off; off += (size_t)T_LEN * D_DIM;
    float* gb   = ws + off; off += (size_t)T_LEN * F_DIM;
    float* ubf  = ws + off; off += (size_t)T_LEN * F_DIM;
    float* tmp  = ws + off; off += (size_t)T_LEN * R_LORA;

    init_soft_kernel<<<(T_LEN * V_DIM + 255) / 256, 256, 0, stream>>>(soft);
    for (int step = 0; step < N_STEPS; step++) {
        embed_kernel<<<T_LEN, 256, 0, stream>>>(soft, E, x);
        for (int l = 0; l < N_LAYERS; l++) {
            const float* ln1_l = ln1 + (size_t)l * D_DIM;
            const float* ln2_l = ln2 + (size_t)l * D_DIM;
            rms_kernel<<<T_LEN, 256, 0, stream>>>(x, ln1_l, h);
            launch_gemm(h, Asrc[0] + (size_t)l * D_DIM * R_LORA, tmp, T_LEN, R_LORA, D_DIM, 1.0f, 0, stream);
            launch_gemm(h, Wsrc[0] + (size_t)l * DD, qb, T_LEN, D_DIM, D_DIM, 1.0f, 0, stream);
            launch_gemm(tmp, Bsrc[0] + (size_t)l * R_LORA * D_DIM, qb, T_LEN, D_DIM, R_LORA, LORA_SCALE, 1, stream);
            launch_gemm(h, Asrc[1] + (size_t)l * D_DIM * R_LORA, tmp, T_LEN, R_LORA, D_DIM, 1.0f, 0, stream);
            launch_gemm(h, Wsrc[1] + (size_t)l * DD, kb, T_LEN, D_DIM, D_DIM, 1.0f, 0, stream);
            launch_gemm(tmp, Bsrc[1] + (size_t)l * R_LORA * D_DIM, kb, T_LEN, D_DIM, R_LORA, LORA_SCALE, 1, stream);
            launch_gemm(h, Asrc[2] + (size_t)l * D_DIM * R_LORA, tmp, T_LEN, R_LORA, D_DIM, 1.0f, 0, stream);
            launch_gemm(h, Wsrc[2] + (size_t)l * DD, vb, T_LEN, D_DIM, D_DIM, 1.0f, 0, stream);
            launch_gemm(tmp, Bsrc[2] + (size_t)l * R_LORA * D_DIM, vb, T_LEN, D_DIM, R_LORA, LORA_SCALE, 1, stream);
            attn_kernel<<<dim3(T_LEN, H_NUM), 256, 0, stream>>>(qb, kb, vb, cb);
            launch_gemm(cb, Asrc[3] + (size_t)l * D_DIM * R_LORA, tmp, T_LEN, R_LORA, D_DIM, 1.0f, 0, stream);
            launch_gemm(cb, Wsrc[3] + (size_t)l * DD, x, T_LEN, D_DIM, D_DIM, 1.0f, 1, stream);
            launch_gemm(tmp, Bsrc[3] + (size_t)l * R_LORA * D_DIM, x, T_LEN, D_DIM, R_LORA, LORA_SCALE, 1, stream);
            rms_kernel<<<T_LEN, 256, 0, stream>>>(x, ln2_l, h);
            launch_gemm(h, Asrc[4] + (size_t)l * D_DIM * R_LORA, tmp, T_LEN, R_LORA, D_DIM, 1.0f, 0, stream);
            launch_gemm(h, Wsrc[4] + (size_t)l * DF, gb, T_LEN, F_DIM, D_DIM, 1.0f, 0, stream);
            launch_gemm(tmp, Bsrc[4] + (size_t)l * R_LORA * F_DIM, gb, T_LEN, F_DIM, R_LORA, LORA_SCALE, 1, stream);
            launch_gemm(h, Asrc[5] + (size_t)l * D_DIM * R_LORA, tmp, T_LEN, R_LORA, D_DIM, 1.0f, 0, stream);
            launch_gemm(h, Wsrc[5] + (size_t)l * DF, ubf, T_LEN, F_DIM, D_DIM, 1.0f, 0, stream);
            launch_gemm(tmp, Bsrc[5] + (size_t)l * R_LORA * F_DIM, ubf, T_LEN, F_DIM, R_LORA, LORA_SCALE, 1, stream);
            silu_mul_kernel<<<(T_LEN * F_DIM + 255) / 256, 256, 0, stream>>>(gb, ubf, gb, T_LEN * F_DIM);
            launch_gemm(gb, Asrc[6] + (size_t)l * F_DIM * R_LORA, tmp, T_LEN, R_LORA, F_DIM, 1.0f, 0, stream);
            launch_gemm(gb, Wsrc[6] + (size_t)l * DF, x, T_LEN, D_DIM, F_DIM, 1.0f, 1, stream);
            launch_gemm(tmp, Bsrc[6] + (size_t)l * R_LORA * D_DIM, x, T_LEN, D_DIM, R_LORA, LORA_SCALE, 1, stream);
        }
        head_kernel<<<T_LEN, 256, 0, stream>>>(x, lnf, E, packed, soft);
    }
    argmax_kernel<<<(T_LEN + 255) / 256, 256, 0, stream>>>(soft, (int*)d_out);
}